// Round 9
// baseline (536.213 us; speedup 1.0000x reference)
//
#include <hip/hip_runtime.h>
#include <hip/hip_bf16.h>
#include <math.h>

#define N_NODES 10000
#define N_EDGES 160000
#define SO_BLK 157          // ceil(10000/64) s-GEMM blocks
#define VO_BLK 469          // ceil(30000/64) v-GEMM blocks

typedef __attribute__((ext_vector_type(8))) short short8x;
typedef __attribute__((ext_vector_type(4))) float floatx4;
typedef __attribute__((ext_vector_type(4))) unsigned int uint4x;
typedef __attribute__((ext_vector_type(2))) unsigned int uint2x;

union S8 { short8x v; unsigned short u[8]; uint4 q; uint4x qx; };

template<int N> struct ic { static constexpr int value = N; };

__device__ __forceinline__ unsigned short f2bf(float x) {
    unsigned int u = __float_as_uint(x);
    return (unsigned short)((u + 0x7fffu + ((u >> 16) & 1u)) >> 16);
}
__device__ __forceinline__ float bf2f(unsigned short u) {
    return __uint_as_float(((unsigned)u) << 16);
}
__device__ __forceinline__ float silu_c(float x) {
    return 1.679f * x / (1.0f + __expf(-x));
}

// ---------------- pack_all: all weight pre-packs in one launch ----------------
// blocks [0,192): b_pre; [192,208): w2a; [208,210): w1a; [210,226): b_lin
__global__ __launch_bounds__(256) void pack_all_kernel(
    const float* __restrict__ sc_ws, const float* __restrict__ lin2_ws,
    const float* __restrict__ sc_wv, const float* __restrict__ lin2_wv,
    const float* __restrict__ fc_w2, const float* __restrict__ fc_w1,
    const float* __restrict__ lin1_ws, const float* __restrict__ lin1_wv,
    unsigned short* __restrict__ b_pre, unsigned short* __restrict__ w2a,
    unsigned short* __restrict__ w1a, unsigned short* __restrict__ b_lin)
{
    const int bid = blockIdx.x;
    const int t = threadIdx.x;
    if (bid < 192) {
        int id = bid * 256 + t;                  // 0..49151
        int mat = id / 24576;
        int slot = id - mat * 24576;
        int ks = slot >> 9;
        int rr = slot & 511;
        int lane = rr & 63;
        int quad = lane >> 4;
        int n = ((rr >> 6) << 4) + (lane & 15);
        const float* sc  = mat ? sc_wv  : sc_ws;
        const float* lin = mat ? lin2_wv : lin2_ws;
        S8 pk;
        #pragma unroll
        for (int j = 0; j < 8; j++) {
            int k = ks * 32 + quad * 8 + j;
            float w;
            if (k < 1280) {
                int u = k & 127, v = k >> 7;
                w = sc[(u * 10 + v) * 128 + n];
            } else {
                w = lin[(k - 1280) * 128 + n];
            }
            pk.u[j] = f2bf(w);
        }
        *(uint4*)(b_pre + (size_t)id * 8) = pk.q;
    } else if (bid < 208) {
        int id = (bid - 192) * 256 + t;          // 0..4095
        int lane = id & 63;
        int mfg = (id >> 6) & 31;
        int ks = id >> 11;
        int col = mfg * 16 + (lane & 15);
        int k0 = ks * 32 + (lane >> 4) * 8;
        S8 pk;
        #pragma unroll
        for (int j = 0; j < 8; j++)
            pk.u[j] = f2bf(fc_w2[(k0 + j) * 512 + col] * 0.125f);
        *(uint4*)(w2a + (size_t)id * 8) = pk.q;
    } else if (bid < 210) {
        int id = (bid - 208) * 256 + t;          // 0..511
        int lane = id & 63;
        int mf = (id >> 6) & 3;
        int ks = id >> 8;
        int m = mf * 16 + (lane & 15);
        int k0 = ks * 32 + (lane >> 4) * 8;
        S8 pk;
        #pragma unroll
        for (int j = 0; j < 8; j++)
            pk.u[j] = f2bf(fc_w1[(k0 + j) * 64 + m] * 0.125f);
        *(uint4*)(w1a + (size_t)id * 8) = pk.q;
    } else {
        int id = (bid - 210) * 256 + t;          // 0..4095
        int mat = id >> 11;
        int slot = id & 2047;
        int ks = slot >> 9;
        int rr = slot & 511;
        int nf = rr >> 6;
        int lane = rr & 63;
        int n = nf * 16 + (lane & 15);
        int k0 = ks * 32 + (lane >> 4) * 8;
        const float* w = mat ? lin1_wv : lin1_ws;
        const float l1 = 0.0883883476483f;
        S8 pk;
        #pragma unroll
        for (int j = 0; j < 8; j++)
            pk.u[j] = f2bf(w[(k0 + j) * 128 + n] * l1);
        *(uint4*)(b_lin + (size_t)id * 8) = pk.q;
    }
}

// ---------------- Kernel A: lin1 via MFMA -> packed bf16 y + bf16 xvP ----------------
__global__ __launch_bounds__(256) void node_lin1_mfma(
    const float* __restrict__ node_feats,
    const unsigned short* __restrict__ b_lin,
    unsigned short* __restrict__ y_pk,
    unsigned short* __restrict__ xvP16)
{
    __shared__ __align__(16) unsigned char smem[32768];
    short8x* Al = (short8x*)smem;
    unsigned short* Yt = (unsigned short*)smem;

    const int blk = blockIdx.x;   // 313
    const int t = threadIdx.x;
    const int base = blk * 32;
    const int lane = t & 63;
    const int wv = t >> 6;
    const int m15 = lane & 15;
    const int k0q = (lane >> 4) * 8;

    #pragma unroll
    for (int it = 0; it < 8; it++) {
        int g = wv * 8 + it;
        int af = g >> 2;
        int ks = g & 3;
        int m = af * 16 + m15;
        int comp = m >> 5;
        int nloc = m & 31;
        int node = base + nloc;
        int valid = (node < N_NODES);
        if (!valid) node = N_NODES - 1;
        int k0 = ks * 32 + k0q;
        const float* row = node_feats + (size_t)node * 512;
        S8 pk;
        if (comp == 0) {
            float4 a = *(const float4*)&row[k0];
            float4 b = *(const float4*)&row[k0 + 4];
            pk.u[0] = f2bf(a.x); pk.u[1] = f2bf(a.y); pk.u[2] = f2bf(a.z); pk.u[3] = f2bf(a.w);
            pk.u[4] = f2bf(b.x); pk.u[5] = f2bf(b.y); pk.u[6] = f2bf(b.z); pk.u[7] = f2bf(b.w);
        } else {
            int c = comp - 1;
            #pragma unroll
            for (int j = 0; j < 8; j++)
                pk.u[j] = f2bf(row[128 + (k0 + j) * 3 + c]);
            if (valid)
                *(uint4*)&xvP16[((size_t)node * 3 + c) * 128 + k0] = pk.q;
        }
        Al[(ks * 8 + af) * 64 + lane] = pk.v;
    }
    __syncthreads();

    floatx4 c[8][2];
    #pragma unroll
    for (int af = 0; af < 8; af++) {
        c[af][0] = (floatx4){0.f, 0.f, 0.f, 0.f};
        c[af][1] = (floatx4){0.f, 0.f, 0.f, 0.f};
    }

    const uint4* bq = (const uint4*)b_lin;
    #pragma unroll
    for (int ks = 0; ks < 4; ks++) {
        S8 bs0, bs1, bv0, bv1;
        bs0.q = bq[       ks*512 + (wv*2+0)*64 + lane];
        bs1.q = bq[       ks*512 + (wv*2+1)*64 + lane];
        bv0.q = bq[2048 + ks*512 + (wv*2+0)*64 + lane];
        bv1.q = bq[2048 + ks*512 + (wv*2+1)*64 + lane];
        #pragma unroll
        for (int af = 0; af < 8; af++) {
            short8x a = Al[(ks*8 + af)*64 + lane];
            if (af < 2) {
                c[af][0] = __builtin_amdgcn_mfma_f32_16x16x32_bf16(a, bs0.v, c[af][0], 0, 0, 0);
                c[af][1] = __builtin_amdgcn_mfma_f32_16x16x32_bf16(a, bs1.v, c[af][1], 0, 0, 0);
            } else {
                c[af][0] = __builtin_amdgcn_mfma_f32_16x16x32_bf16(a, bv0.v, c[af][0], 0, 0, 0);
                c[af][1] = __builtin_amdgcn_mfma_f32_16x16x32_bf16(a, bv1.v, c[af][1], 0, 0, 0);
            }
        }
    }
    __syncthreads();

    {
        const int rq = (lane >> 4) * 4;
        #pragma unroll
        for (int af = 0; af < 8; af++) {
            #pragma unroll
            for (int nf = 0; nf < 2; nf++) {
                int u = wv * 32 + nf * 16 + m15;
                #pragma unroll
                for (int i = 0; i < 4; i++) {
                    int m = af * 16 + rq + i;
                    int comp = m >> 5, nloc = m & 31;
                    Yt[(nloc * 128 + u) * 4 + comp] = f2bf(c[af][nf][i]);
                }
            }
        }
    }
    __syncthreads();
    {
        unsigned short* dst = y_pk + (size_t)base * 512;
        int nrem = N_NODES - base;
        #pragma unroll
        for (int it = 0; it < 8; it++) {
            int idx = it * 256 + t;
            if ((idx >> 6) < nrem)
                *(uint4*)(dst + (size_t)idx * 8) = *(const uint4*)&Yt[idx * 8];
        }
    }
}

// ---------------- CSR build ----------------
__global__ __launch_bounds__(256) void hist_kernel(const int* __restrict__ edge_index,
                                                   int* __restrict__ deg) {
    int e = blockIdx.x * 256 + threadIdx.x;
    if (e < N_EDGES) atomicAdd(&deg[edge_index[e]], 1);
}

__global__ __launch_bounds__(1024) void scan_kernel(const int* __restrict__ deg,
                                                    int* __restrict__ row_start,
                                                    int* __restrict__ cursor) {
    __shared__ int wsum[16];
    __shared__ int carry_s;
    const int t = threadIdx.x;
    const int lane = t & 63, w = t >> 6;
    if (t == 0) carry_s = 0;
    __syncthreads();
    for (int chunk = 0; chunk < 10; chunk++) {
        int idx = chunk * 1024 + t;
        int v = (idx < N_NODES) ? deg[idx] : 0;
        int x = v;
        #pragma unroll
        for (int off = 1; off < 64; off <<= 1) {
            int yv = __shfl_up(x, off, 64);
            if (lane >= off) x += yv;
        }
        if (lane == 63) wsum[w] = x;
        __syncthreads();
        int wpre = 0;
        for (int i = 0; i < w; i++) wpre += wsum[i];
        int incl = x + wpre + carry_s;
        int excl = incl - v;
        if (idx < N_NODES) { row_start[idx] = excl; cursor[idx] = excl; }
        __syncthreads();
        if (t == 1023) carry_s = incl;
        __syncthreads();
    }
    if (t == 0) row_start[N_NODES] = carry_s;
}

__global__ __launch_bounds__(256) void scatter_kernel(const int* __restrict__ edge_index,
                                                      const float* __restrict__ edge_attrs,
                                                      int* __restrict__ cursor,
                                                      int* __restrict__ edge_list,
                                                      int* __restrict__ srcs,
                                                      float* __restrict__ ea_sorted) {
    int e = blockIdx.x * 256 + threadIdx.x;
    if (e < N_EDGES) {
        int pos = atomicAdd(&cursor[edge_index[e]], 1);
        edge_list[pos] = e;
        srcs[pos] = edge_index[N_EDGES + e];
        float4 ea = *(const float4*)(edge_attrs + (size_t)e * 4);
        *(float4*)(ea_sorted + (size_t)pos * 4) = ea;
    }
}

// ---------------- Fused edge MLP + gather (node-aligned, NO atomics) ----------------
// Block owns 8 consecutive nodes (grid 1250); processes their contiguous sorted
// edge range in tiles of 64. Each phase-3 pass leaves T=[64e][32u][4c] in LDS and
// is consumed in-block: thread (u_loc=t&31, nd=t>>5) walks ITS node's edges in
// the tile with a depth-2 y/T/ea pipeline into 32 statically-indexed VGPRs.
// Exclusive node ownership -> plain coalesced epilogue stores. w never hits DRAM.
// RACE FIX (R8): tile-top barrier BEFORE staging writes — prior tile's pass-3
// consume reads srcs_l/ea_l/T and must drain before they are overwritten.
__global__ __launch_bounds__(256) void edge_w_fused(
    const float* __restrict__ edge_feats,
    const int* __restrict__ edge_list,
    const int* __restrict__ srcs,
    const float* __restrict__ ea_sorted,
    const int* __restrict__ row_start,
    const float* __restrict__ fc_w0,
    const unsigned short* __restrict__ w1a,
    const unsigned short* __restrict__ w2a,
    const unsigned short* __restrict__ y_pk,
    float* __restrict__ accS,
    float* __restrict__ accV)
{
    __shared__ __align__(16) unsigned char smem[27712];
    float* ef = (float*)smem;                               // [0, 2304)
    unsigned short* h0b = (unsigned short*)(smem + 2304);   // [2304, 11520): 64 x 72
    unsigned short* T   = (unsigned short*)smem;            // [0, 16896): 64 x 132 (phase 3)
    unsigned short* h1b = (unsigned short*)(smem + 16896);  // [16896, 26112): 64 x 72
    int* eids   = (int*)(smem + 26112);                     // [26112, 26368)
    int* srcs_l = (int*)(smem + 26368);                     // [26368, 26624)
    float* ea_l = (float*)(smem + 26624);                   // [26624, 27648): 64 x 4
    int* rs_l   = (int*)(smem + 27648);                     // [27648, 27684): 9 ints

    const int b = blockIdx.x;        // 1250
    const int t = threadIdx.x;
    const int n0 = b * 8;
    const int lane = t & 63;
    const int wv = t >> 6;
    const int quad = lane >> 4;
    const int m15 = lane & 15;
    const int u_loc = t & 31;
    const int nd = t >> 5;           // 0..7

    if (t < 9) rs_l[t] = row_start[n0 + t];
    __syncthreads();
    const int eb = rs_l[0], ee = rs_l[8];
    const int nlo = rs_l[nd], nhi = rs_l[nd + 1];
    const int ntiles = (ee > eb) ? ((ee - eb + 63) >> 6) : 0;

    float acc[4][8];
    #pragma unroll
    for (int p = 0; p < 4; p++)
        #pragma unroll
        for (int k = 0; k < 8; k++) acc[p][k] = 0.f;

    auto consume1 = [&](float* a8, ushort4 w4, ushort4 y4, const float4& ea) {
        float wss = bf2f(w4.x), wsv = bf2f(w4.y);
        float wvs = bf2f(w4.z), wvv = bf2f(w4.w);
        float qs = bf2f(y4.x), q0 = bf2f(y4.y), q1 = bf2f(y4.z), q2 = bf2f(y4.w);
        a8[0] += wss * qs * ea.x;
        a8[1] += wvv * (q0*ea.y + q1*ea.z + q2*ea.w);
        float tsv = wsv * qs;
        a8[2] += tsv * ea.y; a8[3] += tsv * ea.z; a8[4] += tsv * ea.w;
        float tvs = wvs * ea.x;
        a8[5] += tvs * q0; a8[6] += tvs * q1; a8[7] += tvs * q2;
    };

    const uint4* w1aq = (const uint4*)w1a;
    const uint4* w2aq = (const uint4*)w2a;

    #pragma unroll 1
    for (int tile = 0; tile < ntiles; tile++) {
        const int tbeg = eb + (tile << 6);
        const int tend = (tbeg + 64 < ee) ? tbeg + 64 : ee;

        __syncthreads();   // RACE FIX: prior tile's consume (reads srcs_l/ea_l/T) must drain

        // ---- stage eids/srcs/ea for this tile (clamped) ----
        if (t < 64) {
            int pos = tbeg + t; if (pos >= ee) pos = ee - 1;
            eids[t]   = edge_list[pos];
            srcs_l[t] = srcs[pos];
        }
        {
            int el = t >> 2;
            int pos = tbeg + el; if (pos >= ee) pos = ee - 1;
            ea_l[el * 4 + (t & 3)] = ea_sorted[(size_t)pos * 4 + (t & 3)];
        }
        __syncthreads();

        #pragma unroll
        for (int r = 0; r < 2; r++) {
            int idx = r * 256 + t;
            int el = idx >> 3;
            int k = idx & 7;
            ef[el * 9 + k] = edge_feats[(size_t)eids[el] * 8 + k];
        }
        __syncthreads();

        // phase 1 (VALU, f32): h0 = silu_c(ef @ w0 / sqrt(8)) -> bf16
        {
            const int e_loc = t >> 2;
            const int c0 = (t & 3) * 16;
            float a0[16];
            #pragma unroll
            for (int i = 0; i < 16; i++) a0[i] = 0.f;
            const float* efr = &ef[e_loc * 9];
            #pragma unroll
            for (int k = 0; k < 8; k++) {
                float ek = efr[k];
                float w[16];
                #pragma unroll
                for (int q4 = 0; q4 < 4; q4++)
                    *(float4*)&w[q4*4] = *(const float4*)&fc_w0[k*64 + c0 + q4*4];
                #pragma unroll
                for (int i = 0; i < 16; i++) a0[i] += ek * w[i];
            }
            const float is8 = 0.35355339059f;
            S8 p0, p1;
            #pragma unroll
            for (int i = 0; i < 8; i++) {
                p0.u[i] = f2bf(silu_c(a0[i] * is8));
                p1.u[i] = f2bf(silu_c(a0[8 + i] * is8));
            }
            *(uint4*)&h0b[e_loc * 72 + c0]     = p0.q;
            *(uint4*)&h0b[e_loc * 72 + c0 + 8] = p1.q;
        }
        __syncthreads();

        // phase 2 (MFMA): h1 = silu_c(h0 @ w1 / 8)
        {
            floatx4 c2[4];
            #pragma unroll
            for (int ee2 = 0; ee2 < 4; ee2++) c2[ee2] = (floatx4){0.f, 0.f, 0.f, 0.f};
            #pragma unroll
            for (int ks = 0; ks < 2; ks++) {
                S8 afr;
                afr.q = w1aq[(ks*4 + wv)*64 + lane];
                #pragma unroll
                for (int ee2 = 0; ee2 < 4; ee2++) {
                    S8 bfr;
                    bfr.q = *(const uint4*)&h0b[(ee2*16 + m15) * 72 + ks*32 + quad*8];
                    c2[ee2] = __builtin_amdgcn_mfma_f32_16x16x32_bf16(afr.v, bfr.v, c2[ee2], 0, 0, 0);
                }
            }
            #pragma unroll
            for (int ee2 = 0; ee2 < 4; ee2++) {
                ushort4 pk = make_ushort4(f2bf(silu_c(c2[ee2][0])), f2bf(silu_c(c2[ee2][1])),
                                          f2bf(silu_c(c2[ee2][2])), f2bf(silu_c(c2[ee2][3])));
                *(ushort4*)&h1b[(ee2*16 + m15) * 72 + wv*16 + quad*4] = pk;
            }
        }
        __syncthreads();

        // ---- phase 3: 4 passes (fully unrolled; p is constexpr) ----
        auto do_pass = [&](auto pc) {
            constexpr int p = decltype(pc)::value;
            floatx4 c3[2][4];
            #pragma unroll
            for (int mf = 0; mf < 2; mf++)
                #pragma unroll
                for (int ee2 = 0; ee2 < 4; ee2++)
                    c3[mf][ee2] = (floatx4){0.f, 0.f, 0.f, 0.f};

            #pragma unroll
            for (int ks = 0; ks < 2; ks++) {
                S8 bfr[4];
                #pragma unroll
                for (int ee2 = 0; ee2 < 4; ee2++)
                    bfr[ee2].q = *(const uint4*)&h1b[(ee2*16 + m15) * 72 + ks*32 + quad*8];
                #pragma unroll
                for (int mf = 0; mf < 2; mf++) {
                    S8 afr;
                    afr.q = w2aq[(size_t)(ks*32 + wv*8 + p*2 + mf) * 64 + lane];
                    #pragma unroll
                    for (int ee2 = 0; ee2 < 4; ee2++)
                        c3[mf][ee2] = __builtin_amdgcn_mfma_f32_16x16x32_bf16(afr.v, bfr[ee2].v, c3[mf][ee2], 0, 0, 0);
                }
            }

            __syncthreads();   // prior consume done reading T
            #pragma unroll
            for (int mf = 0; mf < 2; mf++) {
                #pragma unroll
                for (int ee2 = 0; ee2 < 4; ee2++) {
                    int e = ee2*16 + m15;
                    #pragma unroll
                    for (int i = 0; i < 4; i++) {
                        int colp = mf*16 + quad*4 + i;
                        T[e*132 + colp*4 + wv] = f2bf(c3[mf][ee2][i]);
                    }
                }
            }
            __syncthreads();

            // ---- consume pass p: thread (u_loc, nd) walks its node's edges ----
            {
                int lo = (nlo > tbeg) ? nlo : tbeg;
                int hi = (nhi < tend) ? nhi : tend;
                int j  = lo - tbeg;
                int je = hi - tbeg;
                if (j < je) {
                    const int u = p * 32 + u_loc;
                    int j1 = (j + 1 < je) ? j + 1 : j;
                    ushort4 wA = *(const ushort4*)&T[j*132 + u_loc*4];
                    ushort4 yA = *(const ushort4*)(y_pk + ((size_t)srcs_l[j]*128 + u)*4);
                    float4  eA = *(const float4*)&ea_l[j*4];
                    ushort4 wB = *(const ushort4*)&T[j1*132 + u_loc*4];
                    ushort4 yB = *(const ushort4*)(y_pk + ((size_t)srcs_l[j1]*128 + u)*4);
                    float4  eB = *(const float4*)&ea_l[j1*4];
                    for (; j < je; j += 2) {
                        consume1(acc[p], wA, yA, eA);
                        {
                            int jn = (j + 2 < je) ? j + 2 : j;
                            wA = *(const ushort4*)&T[jn*132 + u_loc*4];
                            yA = *(const ushort4*)(y_pk + ((size_t)srcs_l[jn]*128 + u)*4);
                            eA = *(const float4*)&ea_l[jn*4];
                        }
                        if (j + 1 < je) consume1(acc[p], wB, yB, eB);
                        {
                            int jm = (j + 3 < je) ? j + 3 : j;
                            wB = *(const ushort4*)&T[jm*132 + u_loc*4];
                            yB = *(const ushort4*)(y_pk + ((size_t)srcs_l[jm]*128 + u)*4);
                            eB = *(const float4*)&ea_l[jm*4];
                        }
                    }
                }
            }
        };
        do_pass(ic<0>{});
        do_pass(ic<1>{});
        do_pass(ic<2>{});
        do_pass(ic<3>{});
    }

    // ---- epilogue: exclusive stores with scales folded in ----
    const float inv = 0.25f;                   // 1/sqrt(16)
    const float s1c = 0.57735026919f * 0.25f;  // inv/sqrt(3)
    const int n = n0 + nd;
    #pragma unroll
    for (int p = 0; p < 4; p++) {
        int u = p * 32 + u_loc;
        accS[(size_t)n*256 + u]        = acc[p][0] * inv;
        accS[(size_t)n*256 + 128 + u]  = acc[p][1] * s1c;
        accV[((size_t)n*3+0)*256 + u]        = acc[p][2] * inv;
        accV[((size_t)n*3+1)*256 + u]        = acc[p][3] * inv;
        accV[((size_t)n*3+2)*256 + u]        = acc[p][4] * inv;
        accV[((size_t)n*3+0)*256 + 128 + u]  = acc[p][5] * inv;
        accV[((size_t)n*3+1)*256 + 128 + u]  = acc[p][6] * inv;
        accV[((size_t)n*3+2)*256 + 128 + u]  = acc[p][7] * inv;
    }
}

// ---------------- node_out as MFMA GEMM, latency-pipelined ----------------
__global__ __launch_bounds__(256) void node_out_mfma(
    const float* __restrict__ node_feats,
    const float* __restrict__ node_attrs,
    const unsigned short* __restrict__ xvP16,
    const float* __restrict__ accS,
    const float* __restrict__ accV,
    const unsigned short* __restrict__ b_pre,
    float* __restrict__ out)
{
    __shared__ __align__(16) short8x Abuf[2][256];   // 2 x 4 KB double buffer
    const int bid = blockIdx.x;
    const int t = threadIdx.x;
    const int lane = t & 63;
    const int wv = t >> 6;
    const bool is_s = (bid < SO_BLK);

    // this thread's A slot: row r (0..63), k-quad (0..3); slot index == t
    const int r    = ((t >> 6) << 4) + (t & 15);
    const int q8   = ((t >> 4) & 3) * 8;

    const float* px = nullptr;
    const unsigned short* pxv = nullptr;
    const float* pa;
    const float* pat;
    if (is_s) {
        int R = bid * 64 + r;
        int node = (R < N_NODES) ? R : 0;
        px  = node_feats + (size_t)node * 512;
        pa  = accS + (size_t)node * 256;
        pat = node_attrs + node * 10;
    } else {
        int Rg = (bid - SO_BLK) * 64 + r;
        if (Rg >= 3 * N_NODES) Rg = 0;
        int node = Rg / 3;
        pxv = xvP16 + (size_t)Rg * 128;
        pa  = accV + (size_t)Rg * 256;
        pat = node_attrs + node * 10;
    }

    const uint4* bb = (const uint4*)(b_pre) + (is_s ? 0 : 24576);
    const float sc_norm = 0.02795084972f;   // 1/sqrt(1280)
    const float l2 = 0.0625f;               // 1/sqrt(256)

    // ---- preload the 4 sc-part A chunks for this (row, quad) ----
    float xf[4][8];
    S8    xh[4];
    if (is_s) {
        #pragma unroll
        for (int c = 0; c < 4; c++) {
            floatx4 lo = *(const floatx4*)&px[c*32 + q8];
            floatx4 hi = *(const floatx4*)&px[c*32 + q8 + 4];
            #pragma unroll
            for (int i = 0; i < 4; i++) { xf[c][i] = lo[i]; xf[c][4+i] = hi[i]; }
        }
    } else {
        #pragma unroll
        for (int c = 0; c < 4; c++)
            xh[c].q = *(const uint4*)&pxv[c*32 + q8];
    }
    float attC = pat[0] * sc_norm;

    floatx4 acc[4][2];
    #pragma unroll
    for (int af = 0; af < 4; af++) {
        acc[af][0] = (floatx4){0.f, 0.f, 0.f, 0.f};
        acc[af][1] = (floatx4){0.f, 0.f, 0.f, 0.f};
    }

    const int cof0 = (wv*2+0)*64 + lane;
    const int cof1 = (wv*2+1)*64 + lane;

    auto packx = [&](int c_, float att_) -> short8x {
        S8 pk;
        if (is_s) {
            #pragma unroll
            for (int i = 0; i < 8; i++) pk.u[i] = f2bf(xf[c_][i] * att_);
        } else {
            #pragma unroll
            for (int i = 0; i < 8; i++) pk.u[i] = f2bf(bf2f(xh[c_].u[i]) * att_);
        }
        return pk.v;
    };
    auto mstep = [&](int kb, const S8& b0, const S8& b1) {
        __builtin_amdgcn_s_setprio(1);
        #pragma unroll
        for (int af = 0; af < 4; af++) {
            short8x a = Abuf[kb][af*64 + lane];
            acc[af][0] = __builtin_amdgcn_mfma_f32_16x16x32_bf16(a, b0.v, acc[af][0], 0, 0, 0);
            acc[af][1] = __builtin_amdgcn_mfma_f32_16x16x32_bf16(a, b1.v, acc[af][1], 0, 0, 0);
        }
        __builtin_amdgcn_s_setprio(0);
    };
    auto bload = [&](int k2, S8& b0, S8& b1) {
        b0.q = bb[(size_t)k2*512 + cof0];
        b1.q = bb[(size_t)k2*512 + cof1];
    };
    auto barrier_ = [&]() {
        asm volatile("s_waitcnt lgkmcnt(0)" ::: "memory");
        __builtin_amdgcn_s_barrier();
    };

    // B prefetch (depth 2)
    S8 bA0, bA1, bB0, bB1;
    bload(0, bA0, bA1);
    bload(1, bB0, bB1);

    // prologue: A(0) -> buf0
    Abuf[0][t] = packx(0, attC);
    barrier_();

    // ---- main loop: ks = 0..35 (vblk 0..8), A from preloaded chunks ----
    #pragma unroll 1
    for (int vb = 0; vb < 9; vb++) {
        float attN = pat[vb + 1] * sc_norm;
        const int ksb = vb * 4;
        Abuf[1][t] = packx(1, attC); mstep(0, bA0, bA1); bload(ksb+2, bA0, bA1); barrier_();
        Abuf[0][t] = packx(2, attC); mstep(1, bB0, bB1); bload(ksb+3, bB0, bB1); barrier_();
        Abuf[1][t] = packx(3, attC); mstep(0, bA0, bA1); bload(ksb+4, bA0, bA1); barrier_();
        Abuf[0][t] = packx(0, attN); mstep(1, bB0, bB1); bload(ksb+5, bB0, bB1); barrier_();
        attC = attN;
    }

    // ---- ks = 36..47 explicit (attC == pat[9]); tail A from acc (depth-2) ----
    floatx4 aT0[2], aT1[2];
    auto issue0 = [&](int k_) { int j2 = (k_-40)*32 + q8;
        aT0[0] = *(const floatx4*)&pa[j2]; aT0[1] = *(const floatx4*)&pa[j2+4]; };
    auto issue1 = [&](int k_) { int j2 = (k_-40)*32 + q8;
        aT1[0] = *(const floatx4*)&pa[j2]; aT1[1] = *(const floatx4*)&pa[j2+4]; };
    auto packT = [&](const floatx4* a2) -> short8x {
        S8 pk;
        #pragma unroll
        for (int i = 0; i < 4; i++) { pk.u[i] = f2bf(a2[0][i] * l2); pk.u[4+i] = f2bf(a2[1][i] * l2); }
        return pk.v;
    };

    // ks=36
    Abuf[1][t] = packx(1, attC); mstep(0, bA0, bA1); bload(38, bA0, bA1); barrier_();
    // ks=37
    Abuf[0][t] = packx(2, attC); mstep(1, bB0, bB1); bload(39, bB0, bB1); barrier_();
    // ks=38
    issue0(40);
    Abuf[1][t] = packx(3, attC); mstep(0, bA0, bA1); bload(40, bA0, bA1); barrier_();
    // ks=39
    issue1(41);
    Abuf[0][t] = packT(aT0); mstep(1, bB0, bB1); bload(41, bB0, bB1); barrier_();
    // ks=40
    issue0(42);
    Abuf[1][t] = packT(aT1); mstep(0, bA0, bA1); bload(42, bA0, bA1); barrier_();
    // ks=41
    issue1(43);
    Abuf[0][t] = packT(aT0); mstep(1, bB0, bB1); bload(43, bB0, bB1); barrier_();
    // ks=42
    issue0(44);
    Abuf[1][t] = packT(aT1); mstep(0, bA0, bA1); bload(44, bA0, bA1); barrier_();
    // ks=43
    issue1(45);
    Abuf[0][t] = packT(aT0); mstep(1, bB0, bB1); bload(45, bB0, bB1); barrier_();
    // ks=44
    issue0(46);
    Abuf[1][t] = packT(aT1); mstep(0, bA0, bA1); bload(46, bA0, bA1); barrier_();
    // ks=45
    issue1(47);
    Abuf[0][t] = packT(aT0); mstep(1, bB0, bB1); bload(47, bB0, bB1); barrier_();
    // ks=46
    Abuf[1][t] = packT(aT1); mstep(0, bA0, bA1); barrier_();
    // ks=47
    mstep(1, bB0, bB1);

    // ---- epilogue ----
    const int m = lane & 15;
    const int rq = (lane >> 4) * 4;
    if (is_s) {
        const int n0 = bid * 64;
        #pragma unroll
        for (int af = 0; af < 4; af++) {
            #pragma unroll
            for (int i = 0; i < 4; i++) {
                int n = n0 + af*16 + rq + i;
                if (n < N_NODES) {
                    out[(size_t)n*512 + wv*32 + m]      = acc[af][0][i];
                    out[(size_t)n*512 + wv*32 + 16 + m] = acc[af][1][i];
                }
            }
        }
    } else {
        const int r0 = (bid - SO_BLK) * 64;
        #pragma unroll
        for (int af = 0; af < 4; af++) {
            #pragma unroll
            for (int i = 0; i < 4; i++) {
                int Rg = r0 + af*16 + rq + i;
                if (Rg < 3 * N_NODES) {
                    int nn = Rg / 3;
                    int cc = Rg - nn * 3;
                    float* po = out + (size_t)nn*512 + 128 + cc;
                    po[(wv*32 + m)*3]      = acc[af][0][i];
                    po[(wv*32 + 16 + m)*3] = acc[af][1][i];
                }
            }
        }
    }
}

extern "C" void kernel_launch(void* const* d_in, const int* in_sizes, int n_in,
                              void* d_out, int out_size, void* d_ws, size_t ws_size,
                              hipStream_t stream) {
    const float* node_feats = (const float*)d_in[0];
    const float* node_attrs = (const float*)d_in[1];
    const float* edge_feats = (const float*)d_in[2];
    const float* edge_attrs = (const float*)d_in[3];
    const int*   edge_index = (const int*)  d_in[4];
    const float* lin1_ws    = (const float*)d_in[5];
    const float* lin1_wv    = (const float*)d_in[6];
    const float* fc_w0      = (const float*)d_in[7];
    const float* fc_w1      = (const float*)d_in[8];
    const float* fc_w2      = (const float*)d_in[9];
    const float* lin2_ws    = (const float*)d_in[10];
    const float* lin2_wv    = (const float*)d_in[11];
    const float* sc_ws      = (const float*)d_in[12];
    const float* sc_wv      = (const float*)d_in[13];
    float* out = (float*)d_out;

    // workspace layout (w_pk eliminated)
    unsigned short* y_pk  = (unsigned short*)d_ws;            // 5,120,000 us
    float* accS = (float*)(y_pk + (size_t)5120000);           // 2,560,000 f32
    float* accV = accS + (size_t)2560000;                     // 7,680,000 f32
    unsigned short* xvP16 = (unsigned short*)(accV + (size_t)7680000);  // 3,840,000 us
    int* deg       = (int*)(xvP16 + (size_t)3840000);
    int* row_start = deg + 10016;
    int* cursor    = row_start + 10016;
    int* edge_list = cursor + 10016;
    int* srcs      = edge_list + N_EDGES;
    float* ea_sorted = (float*)(srcs + N_EDGES);
    unsigned short* b_pre = (unsigned short*)(ea_sorted + (size_t)N_EDGES * 4);
    unsigned short* w2a   = b_pre + (size_t)2 * 24576 * 8;
    unsigned short* w1a   = w2a + (size_t)4096 * 8;
    unsigned short* b_lin = w1a + (size_t)512 * 8;
    const size_t need = (size_t)5120000 * 2 + (size_t)(2560000 + 7680000) * 4
                      + (size_t)3840000 * 2
                      + (size_t)(10016 * 3 + N_EDGES * 2) * 4
                      + (size_t)N_EDGES * 4 * 4
                      + ((size_t)2 * 24576 * 8 + (size_t)4096 * 8 + (size_t)512 * 8
                         + (size_t)4096 * 8) * 2;
    if (ws_size < need) return;

    hipLaunchKernelGGL(pack_all_kernel, dim3(226), dim3(256), 0, stream,
                       sc_ws, lin2_ws, sc_wv, lin2_wv, fc_w2, fc_w1, lin1_ws, lin1_wv,
                       b_pre, w2a, w1a, b_lin);
    hipLaunchKernelGGL(node_lin1_mfma, dim3(313), dim3(256), 0, stream,
                       node_feats, b_lin, y_pk, xvP16);

    hipMemsetAsync(deg, 0, (size_t)N_NODES * sizeof(int), stream);
    hipLaunchKernelGGL(hist_kernel, dim3(625), dim3(256), 0, stream, edge_index, deg);
    hipLaunchKernelGGL(scan_kernel, dim3(1), dim3(1024), 0, stream, deg, row_start, cursor);
    hipLaunchKernelGGL(scatter_kernel, dim3(625), dim3(256), 0, stream,
                       edge_index, edge_attrs, cursor, edge_list, srcs, ea_sorted);
    hipLaunchKernelGGL(edge_w_fused, dim3(1250), dim3(256), 0, stream,
                       edge_feats, edge_list, srcs, ea_sorted, row_start,
                       fc_w0, w1a, w2a, y_pk, accS, accV);

    hipLaunchKernelGGL(node_out_mfma, dim3(SO_BLK + VO_BLK), dim3(256), 0, stream,
                       node_feats, node_attrs, xvP16, accS, accV, b_pre, out);
}

// Round 10
// 311.601 us; speedup vs baseline: 1.7208x; 1.7208x over previous
//
#include <hip/hip_runtime.h>
#include <hip/hip_bf16.h>
#include <math.h>

#define N_NODES 10000
#define N_EDGES 160000
#define SO_BLK 157          // ceil(10000/64) s-GEMM blocks
#define VO_BLK 469          // ceil(30000/64) v-GEMM blocks
#define E_HALF 80000        // edge split point (1250 edge_w blocks x 64)

typedef __attribute__((ext_vector_type(8))) short short8x;
typedef __attribute__((ext_vector_type(4))) float floatx4;
typedef __attribute__((ext_vector_type(4))) unsigned int uint4x;
typedef __attribute__((ext_vector_type(2))) unsigned int uint2x;

union S8 { short8x v; unsigned short u[8]; uint4 q; uint4x qx; };

__device__ __forceinline__ unsigned short f2bf(float x) {
    unsigned int u = __float_as_uint(x);
    return (unsigned short)((u + 0x7fffu + ((u >> 16) & 1u)) >> 16);
}
__device__ __forceinline__ float bf2f(unsigned short u) {
    return __uint_as_float(((unsigned)u) << 16);
}
__device__ __forceinline__ float silu_c(float x) {
    return 1.679f * x / (1.0f + __expf(-x));
}

// ---------------- pack_all: all weight pre-packs in one launch ----------------
// blocks [0,192): b_pre; [192,208): w2a; [208,210): w1a; [210,226): b_lin
__global__ __launch_bounds__(256) void pack_all_kernel(
    const float* __restrict__ sc_ws, const float* __restrict__ lin2_ws,
    const float* __restrict__ sc_wv, const float* __restrict__ lin2_wv,
    const float* __restrict__ fc_w2, const float* __restrict__ fc_w1,
    const float* __restrict__ lin1_ws, const float* __restrict__ lin1_wv,
    unsigned short* __restrict__ b_pre, unsigned short* __restrict__ w2a,
    unsigned short* __restrict__ w1a, unsigned short* __restrict__ b_lin)
{
    const int bid = blockIdx.x;
    const int t = threadIdx.x;
    if (bid < 192) {
        int id = bid * 256 + t;                  // 0..49151
        int mat = id / 24576;
        int slot = id - mat * 24576;
        int ks = slot >> 9;
        int rr = slot & 511;
        int lane = rr & 63;
        int quad = lane >> 4;
        int n = ((rr >> 6) << 4) + (lane & 15);
        const float* sc  = mat ? sc_wv  : sc_ws;
        const float* lin = mat ? lin2_wv : lin2_ws;
        S8 pk;
        #pragma unroll
        for (int j = 0; j < 8; j++) {
            int k = ks * 32 + quad * 8 + j;
            float w;
            if (k < 1280) {
                int u = k & 127, v = k >> 7;
                w = sc[(u * 10 + v) * 128 + n];
            } else {
                w = lin[(k - 1280) * 128 + n];
            }
            pk.u[j] = f2bf(w);
        }
        *(uint4*)(b_pre + (size_t)id * 8) = pk.q;
    } else if (bid < 208) {
        int id = (bid - 192) * 256 + t;          // 0..4095
        int lane = id & 63;
        int mfg = (id >> 6) & 31;
        int ks = id >> 11;
        int col = mfg * 16 + (lane & 15);
        int k0 = ks * 32 + (lane >> 4) * 8;
        S8 pk;
        #pragma unroll
        for (int j = 0; j < 8; j++)
            pk.u[j] = f2bf(fc_w2[(k0 + j) * 512 + col] * 0.125f);
        *(uint4*)(w2a + (size_t)id * 8) = pk.q;
    } else if (bid < 210) {
        int id = (bid - 208) * 256 + t;          // 0..511
        int lane = id & 63;
        int mf = (id >> 6) & 3;
        int ks = id >> 8;
        int m = mf * 16 + (lane & 15);
        int k0 = ks * 32 + (lane >> 4) * 8;
        S8 pk;
        #pragma unroll
        for (int j = 0; j < 8; j++)
            pk.u[j] = f2bf(fc_w1[(k0 + j) * 64 + m] * 0.125f);
        *(uint4*)(w1a + (size_t)id * 8) = pk.q;
    } else {
        int id = (bid - 210) * 256 + t;          // 0..4095
        int mat = id >> 11;
        int slot = id & 2047;
        int ks = slot >> 9;
        int rr = slot & 511;
        int nf = rr >> 6;
        int lane = rr & 63;
        int n = nf * 16 + (lane & 15);
        int k0 = ks * 32 + (lane >> 4) * 8;
        const float* w = mat ? lin1_wv : lin1_ws;
        const float l1 = 0.0883883476483f;
        S8 pk;
        #pragma unroll
        for (int j = 0; j < 8; j++)
            pk.u[j] = f2bf(w[(k0 + j) * 128 + n] * l1);
        *(uint4*)(b_lin + (size_t)id * 8) = pk.q;
    }
}

// ---------------- Kernel A: lin1 via MFMA -> packed bf16 y + bf16 xvP ----------------
__global__ __launch_bounds__(256) void node_lin1_mfma(
    const float* __restrict__ node_feats,
    const unsigned short* __restrict__ b_lin,
    unsigned short* __restrict__ y_pk,
    unsigned short* __restrict__ xvP16)
{
    __shared__ __align__(16) unsigned char smem[32768];
    short8x* Al = (short8x*)smem;
    unsigned short* Yt = (unsigned short*)smem;

    const int blk = blockIdx.x;   // 313
    const int t = threadIdx.x;
    const int base = blk * 32;
    const int lane = t & 63;
    const int wv = t >> 6;
    const int m15 = lane & 15;
    const int k0q = (lane >> 4) * 8;

    #pragma unroll
    for (int it = 0; it < 8; it++) {
        int g = wv * 8 + it;
        int af = g >> 2;
        int ks = g & 3;
        int m = af * 16 + m15;
        int comp = m >> 5;
        int nloc = m & 31;
        int node = base + nloc;
        int valid = (node < N_NODES);
        if (!valid) node = N_NODES - 1;
        int k0 = ks * 32 + k0q;
        const float* row = node_feats + (size_t)node * 512;
        S8 pk;
        if (comp == 0) {
            float4 a = *(const float4*)&row[k0];
            float4 b = *(const float4*)&row[k0 + 4];
            pk.u[0] = f2bf(a.x); pk.u[1] = f2bf(a.y); pk.u[2] = f2bf(a.z); pk.u[3] = f2bf(a.w);
            pk.u[4] = f2bf(b.x); pk.u[5] = f2bf(b.y); pk.u[6] = f2bf(b.z); pk.u[7] = f2bf(b.w);
        } else {
            int c = comp - 1;
            #pragma unroll
            for (int j = 0; j < 8; j++)
                pk.u[j] = f2bf(row[128 + (k0 + j) * 3 + c]);
            if (valid)
                *(uint4*)&xvP16[((size_t)node * 3 + c) * 128 + k0] = pk.q;
        }
        Al[(ks * 8 + af) * 64 + lane] = pk.v;
    }
    __syncthreads();

    floatx4 c[8][2];
    #pragma unroll
    for (int af = 0; af < 8; af++) {
        c[af][0] = (floatx4){0.f, 0.f, 0.f, 0.f};
        c[af][1] = (floatx4){0.f, 0.f, 0.f, 0.f};
    }

    const uint4* bq = (const uint4*)b_lin;
    #pragma unroll
    for (int ks = 0; ks < 4; ks++) {
        S8 bs0, bs1, bv0, bv1;
        bs0.q = bq[       ks*512 + (wv*2+0)*64 + lane];
        bs1.q = bq[       ks*512 + (wv*2+1)*64 + lane];
        bv0.q = bq[2048 + ks*512 + (wv*2+0)*64 + lane];
        bv1.q = bq[2048 + ks*512 + (wv*2+1)*64 + lane];
        #pragma unroll
        for (int af = 0; af < 8; af++) {
            short8x a = Al[(ks*8 + af)*64 + lane];
            if (af < 2) {
                c[af][0] = __builtin_amdgcn_mfma_f32_16x16x32_bf16(a, bs0.v, c[af][0], 0, 0, 0);
                c[af][1] = __builtin_amdgcn_mfma_f32_16x16x32_bf16(a, bs1.v, c[af][1], 0, 0, 0);
            } else {
                c[af][0] = __builtin_amdgcn_mfma_f32_16x16x32_bf16(a, bv0.v, c[af][0], 0, 0, 0);
                c[af][1] = __builtin_amdgcn_mfma_f32_16x16x32_bf16(a, bv1.v, c[af][1], 0, 0, 0);
            }
        }
    }
    __syncthreads();

    {
        const int rq = (lane >> 4) * 4;
        #pragma unroll
        for (int af = 0; af < 8; af++) {
            #pragma unroll
            for (int nf = 0; nf < 2; nf++) {
                int u = wv * 32 + nf * 16 + m15;
                #pragma unroll
                for (int i = 0; i < 4; i++) {
                    int m = af * 16 + rq + i;
                    int comp = m >> 5, nloc = m & 31;
                    Yt[(nloc * 128 + u) * 4 + comp] = f2bf(c[af][nf][i]);
                }
            }
        }
    }
    __syncthreads();
    {
        unsigned short* dst = y_pk + (size_t)base * 512;
        int nrem = N_NODES - base;
        #pragma unroll
        for (int it = 0; it < 8; it++) {
            int idx = it * 256 + t;
            if ((idx >> 6) < nrem)
                *(uint4*)(dst + (size_t)idx * 8) = *(const uint4*)&Yt[idx * 8];
        }
    }
}

// ---------------- CSR build ----------------
__global__ __launch_bounds__(256) void hist_kernel(const int* __restrict__ edge_index,
                                                   int* __restrict__ deg) {
    int e = blockIdx.x * 256 + threadIdx.x;
    if (e < N_EDGES) atomicAdd(&deg[edge_index[e]], 1);
}

__global__ __launch_bounds__(1024) void scan_kernel(const int* __restrict__ deg,
                                                    int* __restrict__ row_start,
                                                    int* __restrict__ cursor) {
    __shared__ int wsum[16];
    __shared__ int carry_s;
    const int t = threadIdx.x;
    const int lane = t & 63, w = t >> 6;
    if (t == 0) carry_s = 0;
    __syncthreads();
    for (int chunk = 0; chunk < 10; chunk++) {
        int idx = chunk * 1024 + t;
        int v = (idx < N_NODES) ? deg[idx] : 0;
        int x = v;
        #pragma unroll
        for (int off = 1; off < 64; off <<= 1) {
            int yv = __shfl_up(x, off, 64);
            if (lane >= off) x += yv;
        }
        if (lane == 63) wsum[w] = x;
        __syncthreads();
        int wpre = 0;
        for (int i = 0; i < w; i++) wpre += wsum[i];
        int incl = x + wpre + carry_s;
        int excl = incl - v;
        if (idx < N_NODES) { row_start[idx] = excl; cursor[idx] = excl; }
        __syncthreads();
        if (t == 1023) carry_s = incl;
        __syncthreads();
    }
    if (t == 0) row_start[N_NODES] = carry_s;
}

__global__ __launch_bounds__(256) void scatter_kernel(const int* __restrict__ edge_index,
                                                      const float* __restrict__ edge_attrs,
                                                      int* __restrict__ cursor,
                                                      int* __restrict__ edge_list,
                                                      int* __restrict__ srcs,
                                                      float* __restrict__ ea_sorted) {
    int e = blockIdx.x * 256 + threadIdx.x;
    if (e < N_EDGES) {
        int pos = atomicAdd(&cursor[edge_index[e]], 1);
        edge_list[pos] = e;
        srcs[pos] = edge_index[N_EDGES + e];
        float4 ea = *(const float4*)(edge_attrs + (size_t)e * 4);
        *(float4*)(ea_sorted + (size_t)pos * 4) = ea;
    }
}

// ---------------- Kernel B1: edge MLP (sorted order) -> packed bf16 w ----------------
// w_pk[pos][u][4] = bf16{ss, sv, vs, vv}; normal (MALL-allocating) stores.
// Launched in two halves (blk_off 0 / 1250) so each 82 MB half stays
// Infinity-Cache-resident for the gather pass that immediately follows.
__global__ __launch_bounds__(256) void edge_w_mfma(
    const float* __restrict__ edge_feats,
    const int* __restrict__ edge_list,
    const float* __restrict__ fc_w0,
    const unsigned short* __restrict__ w1a,
    const unsigned short* __restrict__ w2a,
    unsigned short* __restrict__ w_pk,
    int blk_off)
{
    __shared__ __align__(16) unsigned char smem[26368];
    float* ef = (float*)smem;                               // [0, 2304)
    unsigned short* h0b = (unsigned short*)(smem + 2304);   // [2304, 11520): 64 x 72
    unsigned short* T   = (unsigned short*)smem;            // [0, 16896): 64 x 132 (epilogue)
    unsigned short* h1b = (unsigned short*)(smem + 16896);  // [16896, 26112): 64 x 72
    int* eids = (int*)(smem + 26112);                       // [26112, 26368)

    const int blk = blockIdx.x + blk_off;   // 2 x 1250
    const int t = threadIdx.x;
    const int eb0 = blk * 64;
    const int lane = t & 63;
    const int wv = t >> 6;
    const int quad = lane >> 4;
    const int m15 = lane & 15;

    if (t < 64) eids[t] = edge_list[eb0 + t];
    __syncthreads();

    #pragma unroll
    for (int r = 0; r < 2; r++) {
        int idx = r * 256 + t;
        int el = idx >> 3;
        int k = idx & 7;
        ef[el * 9 + k] = edge_feats[(size_t)eids[el] * 8 + k];
    }
    __syncthreads();

    // phase 1 (VALU, f32): h0 = silu_c(ef @ w0 / sqrt(8)) -> bf16
    {
        const int e_loc = t >> 2;
        const int c0 = (t & 3) * 16;
        float a0[16];
        #pragma unroll
        for (int i = 0; i < 16; i++) a0[i] = 0.f;
        const float* efr = &ef[e_loc * 9];
        #pragma unroll
        for (int k = 0; k < 8; k++) {
            float ek = efr[k];
            float w[16];
            #pragma unroll
            for (int q4 = 0; q4 < 4; q4++)
                *(float4*)&w[q4*4] = *(const float4*)&fc_w0[k*64 + c0 + q4*4];
            #pragma unroll
            for (int i = 0; i < 16; i++) a0[i] += ek * w[i];
        }
        const float is8 = 0.35355339059f;
        S8 p0, p1;
        #pragma unroll
        for (int i = 0; i < 8; i++) {
            p0.u[i] = f2bf(silu_c(a0[i] * is8));
            p1.u[i] = f2bf(silu_c(a0[8 + i] * is8));
        }
        *(uint4*)&h0b[e_loc * 72 + c0]     = p0.q;
        *(uint4*)&h0b[e_loc * 72 + c0 + 8] = p1.q;
    }
    __syncthreads();

    // phase 2 (MFMA): h1 = silu_c(h0 @ w1 / 8)
    {
        floatx4 c2[4];
        #pragma unroll
        for (int ee = 0; ee < 4; ee++) c2[ee] = (floatx4){0.f, 0.f, 0.f, 0.f};
        const uint4* w1aq = (const uint4*)w1a;
        #pragma unroll
        for (int ks = 0; ks < 2; ks++) {
            S8 afr;
            afr.q = w1aq[(ks*4 + wv)*64 + lane];
            #pragma unroll
            for (int ee = 0; ee < 4; ee++) {
                S8 bfr;
                bfr.q = *(const uint4*)&h0b[(ee*16 + m15) * 72 + ks*32 + quad*8];
                c2[ee] = __builtin_amdgcn_mfma_f32_16x16x32_bf16(afr.v, bfr.v, c2[ee], 0, 0, 0);
            }
        }
        #pragma unroll
        for (int ee = 0; ee < 4; ee++) {
            ushort4 pk = make_ushort4(f2bf(silu_c(c2[ee][0])), f2bf(silu_c(c2[ee][1])),
                                      f2bf(silu_c(c2[ee][2])), f2bf(silu_c(c2[ee][3])));
            *(ushort4*)&h1b[(ee*16 + m15) * 72 + wv*16 + quad*4] = pk;
        }
    }
    __syncthreads();

    // phase 3 (MFMA, 4 passes of 2 m-frags); pass p covers cols p*32..p*32+31 of comp wv
    const uint4* w2aq = (const uint4*)w2a;
    #pragma unroll 1
    for (int p = 0; p < 4; p++) {
        floatx4 c3[2][4];
        #pragma unroll
        for (int mf = 0; mf < 2; mf++)
            #pragma unroll
            for (int ee = 0; ee < 4; ee++)
                c3[mf][ee] = (floatx4){0.f, 0.f, 0.f, 0.f};

        #pragma unroll
        for (int ks = 0; ks < 2; ks++) {
            S8 bfr[4];
            #pragma unroll
            for (int ee = 0; ee < 4; ee++)
                bfr[ee].q = *(const uint4*)&h1b[(ee*16 + m15) * 72 + ks*32 + quad*8];
            #pragma unroll
            for (int mf = 0; mf < 2; mf++) {
                S8 afr;
                afr.q = w2aq[(size_t)(ks*32 + wv*8 + p*2 + mf) * 64 + lane];
                #pragma unroll
                for (int ee = 0; ee < 4; ee++)
                    c3[mf][ee] = __builtin_amdgcn_mfma_f32_16x16x32_bf16(afr.v, bfr[ee].v, c3[mf][ee], 0, 0, 0);
            }
        }

        __syncthreads();   // T region free (prev pass stores done / ef+h0b dead)
        // dump interleaved: T[e*132 + col'*4 + comp], comp = wv
        #pragma unroll
        for (int mf = 0; mf < 2; mf++) {
            #pragma unroll
            for (int ee = 0; ee < 4; ee++) {
                int e = ee*16 + m15;
                #pragma unroll
                for (int i = 0; i < 4; i++) {
                    int colp = mf*16 + quad*4 + i;
                    T[e*132 + colp*4 + wv] = f2bf(c3[mf][ee][i]);
                }
            }
        }
        __syncthreads();

        // coalesced store: uint2 per (e, cu); per e-row 256 B contiguous
        #pragma unroll
        for (int it = 0; it < 8; it++) {
            int idx = it * 256 + t;          // 0..2047
            int e  = idx >> 5;
            int cu = idx & 31;
            uint2x v = *(const uint2x*)&T[e*132 + cu*4];
            unsigned short* dstp = w_pk + ((size_t)(eb0 + e) * 128 + p*32 + cu) * 4;
            *(uint2x*)dstp = v;
        }
    }
}

// ---------------- Kernel B2: wave-per-node gather, phase-split ----------------
// One 64-lane wave per node. pass 0 handles nodes whose ENTIRE edge range lies
// below E_HALF (w half 1 L3-resident); pass 1 handles the rest. Plain (caching)
// w loads so the MALL-resident half is actually hit.
__global__ __launch_bounds__(256) void gather_kernel(
    const int* __restrict__ row_start,
    const int* __restrict__ srcs,
    const float* __restrict__ ea_sorted,
    const unsigned short* __restrict__ w_pk,
    const unsigned short* __restrict__ y_pk,
    float* __restrict__ accS,
    float* __restrict__ accV,
    int pass)
{
    const int t = threadIdx.x;
    const int n = blockIdx.x * 4 + (t >> 6);   // wave-per-node, grid 2500
    const int lane = t & 63;
    const int u0 = lane << 1;                  // u0, u0+1

    const int eb = row_start[n];
    const int ee = row_start[n + 1];

    // phase split: pass 0 <-> ee <= E_HALF; pass 1 <-> ee > E_HALF
    if (pass == 0) { if (ee > E_HALF) return; }
    else           { if (ee <= E_HALF) return; }

    float aS0a=0.f,aS0b=0.f, aS1a=0.f,aS1b=0.f;
    float aV2ax=0.f,aV2ay=0.f,aV2az=0.f, aV2bx=0.f,aV2by=0.f,aV2bz=0.f;
    float aV3ax=0.f,aV3ay=0.f,aV3az=0.f, aV3bx=0.f,aV3by=0.f,aV3bz=0.f;

    auto consume = [&](const S8& w8, const S8& y8, const float4& ea) {
        // u0 slot
        {
            float wss = bf2f(w8.u[0]), wsv = bf2f(w8.u[1]);
            float wvs = bf2f(w8.u[2]), wvv = bf2f(w8.u[3]);
            float qs = bf2f(y8.u[0]), q0 = bf2f(y8.u[1]), q1 = bf2f(y8.u[2]), q2 = bf2f(y8.u[3]);
            aS0a += wss * qs * ea.x;
            aS1a += wvv * (q0*ea.y + q1*ea.z + q2*ea.w);
            float tsv = wsv * qs;
            aV2ax += tsv * ea.y; aV2ay += tsv * ea.z; aV2az += tsv * ea.w;
            float tvs = wvs * ea.x;
            aV3ax += tvs * q0; aV3ay += tvs * q1; aV3az += tvs * q2;
        }
        // u0+1 slot
        {
            float wss = bf2f(w8.u[4]), wsv = bf2f(w8.u[5]);
            float wvs = bf2f(w8.u[6]), wvv = bf2f(w8.u[7]);
            float qs = bf2f(y8.u[4]), q0 = bf2f(y8.u[5]), q1 = bf2f(y8.u[6]), q2 = bf2f(y8.u[7]);
            aS0b += wss * qs * ea.x;
            aS1b += wvv * (q0*ea.y + q1*ea.z + q2*ea.w);
            float tsv = wsv * qs;
            aV2bx += tsv * ea.y; aV2by += tsv * ea.z; aV2bz += tsv * ea.w;
            float tvs = wvs * ea.x;
            aV3bx += tvs * q0; aV3by += tvs * q1; aV3bz += tvs * q2;
        }
    };

    if (eb < ee) {
        const int lastE = ee - 1;
        int j1 = (eb+1 < lastE) ? eb+1 : lastE;
        int sA = srcs[eb];
        int sB = srcs[j1];
        int sP0 = srcs[(eb+2 < lastE) ? eb+2 : lastE];
        int sP1 = srcs[(eb+3 < lastE) ? eb+3 : lastE];

        S8 wA, wB, yA, yB; float4 eaA, eaB;
        wA.q = *(const uint4*)(w_pk + ((size_t)eb * 128 + u0) * 4);
        eaA  = *(const float4*)(ea_sorted + (size_t)eb * 4);
        yA.q = *(const uint4*)(y_pk + ((size_t)sA * 128 + u0) * 4);
        wB.q = *(const uint4*)(w_pk + ((size_t)j1 * 128 + u0) * 4);
        eaB  = *(const float4*)(ea_sorted + (size_t)j1 * 4);
        yB.q = *(const uint4*)(y_pk + ((size_t)sB * 128 + u0) * 4);

        for (int i = eb; i < ee; i += 2) {
            // ---- consume A (edge i, always valid) ----
            consume(wA, yA, eaA);
            // ---- refill A <- edge i+2 (clamped within node) ----
            {
                int jn = (i+2 < lastE) ? i+2 : lastE;
                wA.q = *(const uint4*)(w_pk + ((size_t)jn * 128 + u0) * 4);
                eaA  = *(const float4*)(ea_sorted + (size_t)jn * 4);
                yA.q = *(const uint4*)(y_pk + ((size_t)sP0 * 128 + u0) * 4);
                sP0 = srcs[(i+4 < lastE) ? i+4 : lastE];
            }
            // ---- consume B (edge i+1; wave-uniform guard) ----
            if (i + 1 < ee) consume(wB, yB, eaB);
            // ---- refill B <- edge i+3 (clamped) ----
            {
                int jn = (i+3 < lastE) ? i+3 : lastE;
                wB.q = *(const uint4*)(w_pk + ((size_t)jn * 128 + u0) * 4);
                eaB  = *(const float4*)(ea_sorted + (size_t)jn * 4);
                yB.q = *(const uint4*)(y_pk + ((size_t)sP1 * 128 + u0) * 4);
                sP1 = srcs[(i+5 < lastE) ? i+5 : lastE];
            }
        }
    }

    const float inv = 0.25f;                   // 1/sqrt(16)
    const float s1c = 0.57735026919f * 0.25f;
    *(float2*)(accS + (size_t)n*256 + u0)        = make_float2(aS0a*inv, aS0b*inv);
    *(float2*)(accS + (size_t)n*256 + 128 + u0)  = make_float2(aS1a*s1c, aS1b*s1c);
    *(float2*)(accV + ((size_t)n*3+0)*256 + u0)       = make_float2(aV2ax*inv, aV2bx*inv);
    *(float2*)(accV + ((size_t)n*3+0)*256 + 128 + u0) = make_float2(aV3ax*inv, aV3bx*inv);
    *(float2*)(accV + ((size_t)n*3+1)*256 + u0)       = make_float2(aV2ay*inv, aV2by*inv);
    *(float2*)(accV + ((size_t)n*3+1)*256 + 128 + u0) = make_float2(aV3ay*inv, aV3by*inv);
    *(float2*)(accV + ((size_t)n*3+2)*256 + u0)       = make_float2(aV2az*inv, aV2bz*inv);
    *(float2*)(accV + ((size_t)n*3+2)*256 + 128 + u0) = make_float2(aV3az*inv, aV3bz*inv);
}

// ---------------- node_out as MFMA GEMM, latency-pipelined ----------------
__global__ __launch_bounds__(256) void node_out_mfma(
    const float* __restrict__ node_feats,
    const float* __restrict__ node_attrs,
    const unsigned short* __restrict__ xvP16,
    const float* __restrict__ accS,
    const float* __restrict__ accV,
    const unsigned short* __restrict__ b_pre,
    float* __restrict__ out)
{
    __shared__ __align__(16) short8x Abuf[2][256];   // 2 x 4 KB double buffer
    const int bid = blockIdx.x;
    const int t = threadIdx.x;
    const int lane = t & 63;
    const int wv = t >> 6;
    const bool is_s = (bid < SO_BLK);

    // this thread's A slot: row r (0..63), k-quad (0..3); slot index == t
    const int r    = ((t >> 6) << 4) + (t & 15);
    const int q8   = ((t >> 4) & 3) * 8;

    const float* px = nullptr;
    const unsigned short* pxv = nullptr;
    const float* pa;
    const float* pat;
    if (is_s) {
        int R = bid * 64 + r;
        int node = (R < N_NODES) ? R : 0;
        px  = node_feats + (size_t)node * 512;
        pa  = accS + (size_t)node * 256;
        pat = node_attrs + node * 10;
    } else {
        int Rg = (bid - SO_BLK) * 64 + r;
        if (Rg >= 3 * N_NODES) Rg = 0;
        int node = Rg / 3;
        pxv = xvP16 + (size_t)Rg * 128;
        pa  = accV + (size_t)Rg * 256;
        pat = node_attrs + node * 10;
    }

    const uint4* bb = (const uint4*)(b_pre) + (is_s ? 0 : 24576);
    const float sc_norm = 0.02795084972f;   // 1/sqrt(1280)
    const float l2 = 0.0625f;               // 1/sqrt(256)

    // ---- preload the 4 sc-part A chunks for this (row, quad) ----
    float xf[4][8];
    S8    xh[4];
    if (is_s) {
        #pragma unroll
        for (int c = 0; c < 4; c++) {
            floatx4 lo = *(const floatx4*)&px[c*32 + q8];
            floatx4 hi = *(const floatx4*)&px[c*32 + q8 + 4];
            #pragma unroll
            for (int i = 0; i < 4; i++) { xf[c][i] = lo[i]; xf[c][4+i] = hi[i]; }
        }
    } else {
        #pragma unroll
        for (int c = 0; c < 4; c++)
            xh[c].q = *(const uint4*)&pxv[c*32 + q8];
    }
    float attC = pat[0] * sc_norm;

    floatx4 acc[4][2];
    #pragma unroll
    for (int af = 0; af < 4; af++) {
        acc[af][0] = (floatx4){0.f, 0.f, 0.f, 0.f};
        acc[af][1] = (floatx4){0.f, 0.f, 0.f, 0.f};
    }

    const int cof0 = (wv*2+0)*64 + lane;
    const int cof1 = (wv*2+1)*64 + lane;

    auto packx = [&](int c_, float att_) -> short8x {
        S8 pk;
        if (is_s) {
            #pragma unroll
            for (int i = 0; i < 8; i++) pk.u[i] = f2bf(xf[c_][i] * att_);
        } else {
            #pragma unroll
            for (int i = 0; i < 8; i++) pk.u[i] = f2bf(bf2f(xh[c_].u[i]) * att_);
        }
        return pk.v;
    };
    auto mstep = [&](int kb, const S8& b0, const S8& b1) {
        __builtin_amdgcn_s_setprio(1);
        #pragma unroll
        for (int af = 0; af < 4; af++) {
            short8x a = Abuf[kb][af*64 + lane];
            acc[af][0] = __builtin_amdgcn_mfma_f32_16x16x32_bf16(a, b0.v, acc[af][0], 0, 0, 0);
            acc[af][1] = __builtin_amdgcn_mfma_f32_16x16x32_bf16(a, b1.v, acc[af][1], 0, 0, 0);
        }
        __builtin_amdgcn_s_setprio(0);
    };
    auto bload = [&](int k2, S8& b0, S8& b1) {
        b0.q = bb[(size_t)k2*512 + cof0];
        b1.q = bb[(size_t)k2*512 + cof1];
    };
    auto barrier_ = [&]() {
        asm volatile("s_waitcnt lgkmcnt(0)" ::: "memory");
        __builtin_amdgcn_s_barrier();
    };

    // B prefetch (depth 2)
    S8 bA0, bA1, bB0, bB1;
    bload(0, bA0, bA1);
    bload(1, bB0, bB1);

    // prologue: A(0) -> buf0
    Abuf[0][t] = packx(0, attC);
    barrier_();

    // ---- main loop: ks = 0..35 (vblk 0..8), A from preloaded chunks ----
    #pragma unroll 1
    for (int vb = 0; vb < 9; vb++) {
        float attN = pat[vb + 1] * sc_norm;
        const int ksb = vb * 4;
        Abuf[1][t] = packx(1, attC); mstep(0, bA0, bA1); bload(ksb+2, bA0, bA1); barrier_();
        Abuf[0][t] = packx(2, attC); mstep(1, bB0, bB1); bload(ksb+3, bB0, bB1); barrier_();
        Abuf[1][t] = packx(3, attC); mstep(0, bA0, bA1); bload(ksb+4, bA0, bA1); barrier_();
        Abuf[0][t] = packx(0, attN); mstep(1, bB0, bB1); bload(ksb+5, bB0, bB1); barrier_();
        attC = attN;
    }

    // ---- ks = 36..47 explicit (attC == pat[9]); tail A from acc (depth-2) ----
    floatx4 aT0[2], aT1[2];
    auto issue0 = [&](int k_) { int j2 = (k_-40)*32 + q8;
        aT0[0] = *(const floatx4*)&pa[j2]; aT0[1] = *(const floatx4*)&pa[j2+4]; };
    auto issue1 = [&](int k_) { int j2 = (k_-40)*32 + q8;
        aT1[0] = *(const floatx4*)&pa[j2]; aT1[1] = *(const floatx4*)&pa[j2+4]; };
    auto packT = [&](const floatx4* a2) -> short8x {
        S8 pk;
        #pragma unroll
        for (int i = 0; i < 4; i++) { pk.u[i] = f2bf(a2[0][i] * l2); pk.u[4+i] = f2bf(a2[1][i] * l2); }
        return pk.v;
    };

    // ks=36
    Abuf[1][t] = packx(1, attC); mstep(0, bA0, bA1); bload(38, bA0, bA1); barrier_();
    // ks=37
    Abuf[0][t] = packx(2, attC); mstep(1, bB0, bB1); bload(39, bB0, bB1); barrier_();
    // ks=38
    issue0(40);
    Abuf[1][t] = packx(3, attC); mstep(0, bA0, bA1); bload(40, bA0, bA1); barrier_();
    // ks=39
    issue1(41);
    Abuf[0][t] = packT(aT0); mstep(1, bB0, bB1); bload(41, bB0, bB1); barrier_();
    // ks=40
    issue0(42);
    Abuf[1][t] = packT(aT1); mstep(0, bA0, bA1); bload(42, bA0, bA1); barrier_();
    // ks=41
    issue1(43);
    Abuf[0][t] = packT(aT0); mstep(1, bB0, bB1); bload(43, bB0, bB1); barrier_();
    // ks=42
    issue0(44);
    Abuf[1][t] = packT(aT1); mstep(0, bA0, bA1); bload(44, bA0, bA1); barrier_();
    // ks=43
    issue1(45);
    Abuf[0][t] = packT(aT0); mstep(1, bB0, bB1); bload(45, bB0, bB1); barrier_();
    // ks=44
    issue0(46);
    Abuf[1][t] = packT(aT1); mstep(0, bA0, bA1); bload(46, bA0, bA1); barrier_();
    // ks=45
    issue1(47);
    Abuf[0][t] = packT(aT0); mstep(1, bB0, bB1); bload(47, bB0, bB1); barrier_();
    // ks=46
    Abuf[1][t] = packT(aT1); mstep(0, bA0, bA1); barrier_();
    // ks=47
    mstep(1, bB0, bB1);

    // ---- epilogue ----
    const int m = lane & 15;
    const int rq = (lane >> 4) * 4;
    if (is_s) {
        const int n0 = bid * 64;
        #pragma unroll
        for (int af = 0; af < 4; af++) {
            #pragma unroll
            for (int i = 0; i < 4; i++) {
                int n = n0 + af*16 + rq + i;
                if (n < N_NODES) {
                    out[(size_t)n*512 + wv*32 + m]      = acc[af][0][i];
                    out[(size_t)n*512 + wv*32 + 16 + m] = acc[af][1][i];
                }
            }
        }
    } else {
        const int r0 = (bid - SO_BLK) * 64;
        #pragma unroll
        for (int af = 0; af < 4; af++) {
            #pragma unroll
            for (int i = 0; i < 4; i++) {
                int Rg = r0 + af*16 + rq + i;
                if (Rg < 3 * N_NODES) {
                    int nn = Rg / 3;
                    int cc = Rg - nn * 3;
                    float* po = out + (size_t)nn*512 + 128 + cc;
                    po[(wv*32 + m)*3]      = acc[af][0][i];
                    po[(wv*32 + 16 + m)*3] = acc[af][1][i];
                }
            }
        }
    }
}

extern "C" void kernel_launch(void* const* d_in, const int* in_sizes, int n_in,
                              void* d_out, int out_size, void* d_ws, size_t ws_size,
                              hipStream_t stream) {
    const float* node_feats = (const float*)d_in[0];
    const float* node_attrs = (const float*)d_in[1];
    const float* edge_feats = (const float*)d_in[2];
    const float* edge_attrs = (const float*)d_in[3];
    const int*   edge_index = (const int*)  d_in[4];
    const float* lin1_ws    = (const float*)d_in[5];
    const float* lin1_wv    = (const float*)d_in[6];
    const float* fc_w0      = (const float*)d_in[7];
    const float* fc_w1      = (const float*)d_in[8];
    const float* fc_w2      = (const float*)d_in[9];
    const float* lin2_ws    = (const float*)d_in[10];
    const float* lin2_wv    = (const float*)d_in[11];
    const float* sc_ws      = (const float*)d_in[12];
    const float* sc_wv      = (const float*)d_in[13];
    float* out = (float*)d_out;

    // workspace layout
    unsigned short* y_pk  = (unsigned short*)d_ws;            // 5,120,000 us
    float* accS = (float*)(y_pk + (size_t)5120000);           // 2,560,000 f32
    float* accV = accS + (size_t)2560000;                     // 7,680,000 f32
    unsigned short* xvP16 = (unsigned short*)(accV + (size_t)7680000);  // 3,840,000 us
    unsigned short* w_pk  = xvP16 + (size_t)3840000;          // 81,920,000 us
    int* deg       = (int*)(w_pk + (size_t)81920000);
    int* row_start = deg + 10016;
    int* cursor    = row_start + 10016;
    int* edge_list = cursor + 10016;
    int* srcs      = edge_list + N_EDGES;
    float* ea_sorted = (float*)(srcs + N_EDGES);
    unsigned short* b_pre = (unsigned short*)(ea_sorted + (size_t)N_EDGES * 4);
    unsigned short* w2a   = b_pre + (size_t)2 * 24576 * 8;
    unsigned short* w1a   = w2a + (size_t)4096 * 8;
    unsigned short* b_lin = w1a + (size_t)512 * 8;
    const size_t need = (size_t)5120000 * 2 + (size_t)(2560000 + 7680000) * 4
                      + (size_t)3840000 * 2 + (size_t)81920000 * 2
                      + (size_t)(10016 * 3 + N_EDGES * 2) * 4
                      + (size_t)N_EDGES * 4 * 4
                      + ((size_t)2 * 24576 * 8 + (size_t)4096 * 8 + (size_t)512 * 8
                         + (size_t)4096 * 8) * 2;
    if (ws_size < need) return;

    hipLaunchKernelGGL(pack_all_kernel, dim3(226), dim3(256), 0, stream,
                       sc_ws, lin2_ws, sc_wv, lin2_wv, fc_w2, fc_w1, lin1_ws, lin1_wv,
                       b_pre, w2a, w1a, b_lin);
    hipLaunchKernelGGL(node_lin1_mfma, dim3(313), dim3(256), 0, stream,
                       node_feats, b_lin, y_pk, xvP16);

    hipMemsetAsync(deg, 0, (size_t)N_NODES * sizeof(int), stream);
    hipLaunchKernelGGL(hist_kernel, dim3(625), dim3(256), 0, stream, edge_index, deg);
    hipLaunchKernelGGL(scan_kernel, dim3(1), dim3(1024), 0, stream, deg, row_start, cursor);
    hipLaunchKernelGGL(scatter_kernel, dim3(625), dim3(256), 0, stream,
                       edge_index, edge_attrs, cursor, edge_list, srcs, ea_sorted);

    // phase-split: produce w half 1 -> consume (L3-hot) -> half 2 -> consume
    hipLaunchKernelGGL(edge_w_mfma, dim3(1250), dim3(256), 0, stream,
                       edge_feats, edge_list, fc_w0, w1a, w2a, w_pk, 0);
    hipLaunchKernelGGL(gather_kernel, dim3(2500), dim3(256), 0, stream,
                       row_start, srcs, ea_sorted, w_pk, y_pk, accS, accV, 0);
    hipLaunchKernelGGL(edge_w_mfma, dim3(1250), dim3(256), 0, stream,
                       edge_feats, edge_list, fc_w0, w1a, w2a, w_pk, 1250);
    hipLaunchKernelGGL(gather_kernel, dim3(2500), dim3(256), 0, stream,
                       row_start, srcs, ea_sorted, w_pk, y_pk, accS, accV, 1);

    hipLaunchKernelGGL(node_out_mfma, dim3(SO_BLK + VO_BLK), dim3(256), 0, stream,
                       node_feats, node_attrs, xvP16, accS, accV, b_pre, out);
}

// Round 11
// 286.756 us; speedup vs baseline: 1.8699x; 1.0866x over previous
//
#include <hip/hip_runtime.h>
#include <hip/hip_bf16.h>
#include <math.h>

#define N_NODES 10000
#define N_EDGES 160000
#define SO_BLK 157          // ceil(10000/64) s-GEMM blocks
#define VO_BLK 469          // ceil(30000/64) v-GEMM blocks

typedef __attribute__((ext_vector_type(8))) short short8x;
typedef __attribute__((ext_vector_type(4))) float floatx4;
typedef __attribute__((ext_vector_type(4))) unsigned int uint4x;
typedef __attribute__((ext_vector_type(2))) unsigned int uint2x;

union S8 { short8x v; unsigned short u[8]; uint4 q; uint4x qx; };

__device__ __forceinline__ unsigned short f2bf(float x) {
    unsigned int u = __float_as_uint(x);
    return (unsigned short)((u + 0x7fffu + ((u >> 16) & 1u)) >> 16);
}
__device__ __forceinline__ float bf2f(unsigned short u) {
    return __uint_as_float(((unsigned)u) << 16);
}
__device__ __forceinline__ float silu_c(float x) {
    return 1.679f * x / (1.0f + __expf(-x));
}

// ---------------- pack_all: all weight pre-packs + deg zeroing in one launch ----
// blocks [0,192): b_pre; [192,208): w2a; [208,210): w1a; [210,226): b_lin;
// [226,266): zero deg (saves the hipMemsetAsync dispatch)
__global__ __launch_bounds__(256) void pack_all_kernel(
    const float* __restrict__ sc_ws, const float* __restrict__ lin2_ws,
    const float* __restrict__ sc_wv, const float* __restrict__ lin2_wv,
    const float* __restrict__ fc_w2, const float* __restrict__ fc_w1,
    const float* __restrict__ lin1_ws, const float* __restrict__ lin1_wv,
    unsigned short* __restrict__ b_pre, unsigned short* __restrict__ w2a,
    unsigned short* __restrict__ w1a, unsigned short* __restrict__ b_lin,
    int* __restrict__ deg)
{
    const int bid = blockIdx.x;
    const int t = threadIdx.x;
    if (bid < 192) {
        int id = bid * 256 + t;                  // 0..49151
        int mat = id / 24576;
        int slot = id - mat * 24576;
        int ks = slot >> 9;
        int rr = slot & 511;
        int lane = rr & 63;
        int quad = lane >> 4;
        int n = ((rr >> 6) << 4) + (lane & 15);
        const float* sc  = mat ? sc_wv  : sc_ws;
        const float* lin = mat ? lin2_wv : lin2_ws;
        S8 pk;
        #pragma unroll
        for (int j = 0; j < 8; j++) {
            int k = ks * 32 + quad * 8 + j;
            float w;
            if (k < 1280) {
                int u = k & 127, v = k >> 7;
                w = sc[(u * 10 + v) * 128 + n];
            } else {
                w = lin[(k - 1280) * 128 + n];
            }
            pk.u[j] = f2bf(w);
        }
        *(uint4*)(b_pre + (size_t)id * 8) = pk.q;
    } else if (bid < 208) {
        int id = (bid - 192) * 256 + t;          // 0..4095
        int lane = id & 63;
        int mfg = (id >> 6) & 31;
        int ks = id >> 11;
        int col = mfg * 16 + (lane & 15);
        int k0 = ks * 32 + (lane >> 4) * 8;
        S8 pk;
        #pragma unroll
        for (int j = 0; j < 8; j++)
            pk.u[j] = f2bf(fc_w2[(k0 + j) * 512 + col] * 0.125f);
        *(uint4*)(w2a + (size_t)id * 8) = pk.q;
    } else if (bid < 210) {
        int id = (bid - 208) * 256 + t;          // 0..511
        int lane = id & 63;
        int mf = (id >> 6) & 3;
        int ks = id >> 8;
        int m = mf * 16 + (lane & 15);
        int k0 = ks * 32 + (lane >> 4) * 8;
        S8 pk;
        #pragma unroll
        for (int j = 0; j < 8; j++)
            pk.u[j] = f2bf(fc_w1[(k0 + j) * 64 + m] * 0.125f);
        *(uint4*)(w1a + (size_t)id * 8) = pk.q;
    } else if (bid < 226) {
        int id = (bid - 210) * 256 + t;          // 0..4095
        int mat = id >> 11;
        int slot = id & 2047;
        int ks = slot >> 9;
        int rr = slot & 511;
        int nf = rr >> 6;
        int lane = rr & 63;
        int n = nf * 16 + (lane & 15);
        int k0 = ks * 32 + (lane >> 4) * 8;
        const float* w = mat ? lin1_wv : lin1_ws;
        const float l1 = 0.0883883476483f;
        S8 pk;
        #pragma unroll
        for (int j = 0; j < 8; j++)
            pk.u[j] = f2bf(w[(k0 + j) * 128 + n] * l1);
        *(uint4*)(b_lin + (size_t)id * 8) = pk.q;
    } else {
        int idx = (bid - 226) * 256 + t;         // 0..10239
        if (idx < N_NODES) deg[idx] = 0;
    }
}

// ---------------- Kernel A: lin1 via MFMA -> packed bf16 y + bf16 xvP ----------------
__global__ __launch_bounds__(256) void node_lin1_mfma(
    const float* __restrict__ node_feats,
    const unsigned short* __restrict__ b_lin,
    unsigned short* __restrict__ y_pk,
    unsigned short* __restrict__ xvP16)
{
    __shared__ __align__(16) unsigned char smem[32768];
    short8x* Al = (short8x*)smem;
    unsigned short* Yt = (unsigned short*)smem;

    const int blk = blockIdx.x;   // 313
    const int t = threadIdx.x;
    const int base = blk * 32;
    const int lane = t & 63;
    const int wv = t >> 6;
    const int m15 = lane & 15;
    const int k0q = (lane >> 4) * 8;

    #pragma unroll
    for (int it = 0; it < 8; it++) {
        int g = wv * 8 + it;
        int af = g >> 2;
        int ks = g & 3;
        int m = af * 16 + m15;
        int comp = m >> 5;
        int nloc = m & 31;
        int node = base + nloc;
        int valid = (node < N_NODES);
        if (!valid) node = N_NODES - 1;
        int k0 = ks * 32 + k0q;
        const float* row = node_feats + (size_t)node * 512;
        S8 pk;
        if (comp == 0) {
            float4 a = *(const float4*)&row[k0];
            float4 b = *(const float4*)&row[k0 + 4];
            pk.u[0] = f2bf(a.x); pk.u[1] = f2bf(a.y); pk.u[2] = f2bf(a.z); pk.u[3] = f2bf(a.w);
            pk.u[4] = f2bf(b.x); pk.u[5] = f2bf(b.y); pk.u[6] = f2bf(b.z); pk.u[7] = f2bf(b.w);
        } else {
            int c = comp - 1;
            #pragma unroll
            for (int j = 0; j < 8; j++)
                pk.u[j] = f2bf(row[128 + (k0 + j) * 3 + c]);
            if (valid)
                *(uint4*)&xvP16[((size_t)node * 3 + c) * 128 + k0] = pk.q;
        }
        Al[(ks * 8 + af) * 64 + lane] = pk.v;
    }
    __syncthreads();

    floatx4 c[8][2];
    #pragma unroll
    for (int af = 0; af < 8; af++) {
        c[af][0] = (floatx4){0.f, 0.f, 0.f, 0.f};
        c[af][1] = (floatx4){0.f, 0.f, 0.f, 0.f};
    }

    const uint4* bq = (const uint4*)b_lin;
    #pragma unroll
    for (int ks = 0; ks < 4; ks++) {
        S8 bs0, bs1, bv0, bv1;
        bs0.q = bq[       ks*512 + (wv*2+0)*64 + lane];
        bs1.q = bq[       ks*512 + (wv*2+1)*64 + lane];
        bv0.q = bq[2048 + ks*512 + (wv*2+0)*64 + lane];
        bv1.q = bq[2048 + ks*512 + (wv*2+1)*64 + lane];
        #pragma unroll
        for (int af = 0; af < 8; af++) {
            short8x a = Al[(ks*8 + af)*64 + lane];
            if (af < 2) {
                c[af][0] = __builtin_amdgcn_mfma_f32_16x16x32_bf16(a, bs0.v, c[af][0], 0, 0, 0);
                c[af][1] = __builtin_amdgcn_mfma_f32_16x16x32_bf16(a, bs1.v, c[af][1], 0, 0, 0);
            } else {
                c[af][0] = __builtin_amdgcn_mfma_f32_16x16x32_bf16(a, bv0.v, c[af][0], 0, 0, 0);
                c[af][1] = __builtin_amdgcn_mfma_f32_16x16x32_bf16(a, bv1.v, c[af][1], 0, 0, 0);
            }
        }
    }
    __syncthreads();

    {
        const int rq = (lane >> 4) * 4;
        #pragma unroll
        for (int af = 0; af < 8; af++) {
            #pragma unroll
            for (int nf = 0; nf < 2; nf++) {
                int u = wv * 32 + nf * 16 + m15;
                #pragma unroll
                for (int i = 0; i < 4; i++) {
                    int m = af * 16 + rq + i;
                    int comp = m >> 5, nloc = m & 31;
                    Yt[(nloc * 128 + u) * 4 + comp] = f2bf(c[af][nf][i]);
                }
            }
        }
    }
    __syncthreads();
    {
        unsigned short* dst = y_pk + (size_t)base * 512;
        int nrem = N_NODES - base;
        #pragma unroll
        for (int it = 0; it < 8; it++) {
            int idx = it * 256 + t;
            if ((idx >> 6) < nrem)
                *(uint4*)(dst + (size_t)idx * 8) = *(const uint4*)&Yt[idx * 8];
        }
    }
}

// ---------------- CSR build ----------------
__global__ __launch_bounds__(256) void hist_kernel(const int* __restrict__ edge_index,
                                                   int* __restrict__ deg) {
    int e = blockIdx.x * 256 + threadIdx.x;
    if (e < N_EDGES) atomicAdd(&deg[edge_index[e]], 1);
}

__global__ __launch_bounds__(1024) void scan_kernel(const int* __restrict__ deg,
                                                    int* __restrict__ row_start,
                                                    int* __restrict__ cursor) {
    __shared__ int wsum[16];
    __shared__ int carry_s;
    const int t = threadIdx.x;
    const int lane = t & 63, w = t >> 6;
    if (t == 0) carry_s = 0;
    __syncthreads();
    for (int chunk = 0; chunk < 10; chunk++) {
        int idx = chunk * 1024 + t;
        int v = (idx < N_NODES) ? deg[idx] : 0;
        int x = v;
        #pragma unroll
        for (int off = 1; off < 64; off <<= 1) {
            int yv = __shfl_up(x, off, 64);
            if (lane >= off) x += yv;
        }
        if (lane == 63) wsum[w] = x;
        __syncthreads();
        int wpre = 0;
        for (int i = 0; i < w; i++) wpre += wsum[i];
        int incl = x + wpre + carry_s;
        int excl = incl - v;
        if (idx < N_NODES) { row_start[idx] = excl; cursor[idx] = excl; }
        __syncthreads();
        if (t == 1023) carry_s = incl;
        __syncthreads();
    }
    if (t == 0) row_start[N_NODES] = carry_s;
}

__global__ __launch_bounds__(256) void scatter_kernel(const int* __restrict__ edge_index,
                                                      const float* __restrict__ edge_attrs,
                                                      int* __restrict__ cursor,
                                                      int* __restrict__ edge_list,
                                                      int* __restrict__ srcs,
                                                      float* __restrict__ ea_sorted) {
    int e = blockIdx.x * 256 + threadIdx.x;
    if (e < N_EDGES) {
        int pos = atomicAdd(&cursor[edge_index[e]], 1);
        edge_list[pos] = e;
        srcs[pos] = edge_index[N_EDGES + e];
        float4 ea = *(const float4*)(edge_attrs + (size_t)e * 4);
        *(float4*)(ea_sorted + (size_t)pos * 4) = ea;
    }
}

// ---------------- Kernel B1: edge MLP (sorted order) -> packed bf16 w ----------------
// w_pk[pos][u][4] = bf16{ss, sv, vs, vv}; normal (MALL-allocating) stores.
__global__ __launch_bounds__(256) void edge_w_mfma(
    const float* __restrict__ edge_feats,
    const int* __restrict__ edge_list,
    const float* __restrict__ fc_w0,
    const unsigned short* __restrict__ w1a,
    const unsigned short* __restrict__ w2a,
    unsigned short* __restrict__ w_pk)
{
    __shared__ __align__(16) unsigned char smem[26368];
    float* ef = (float*)smem;                               // [0, 2304)
    unsigned short* h0b = (unsigned short*)(smem + 2304);   // [2304, 11520): 64 x 72
    unsigned short* T   = (unsigned short*)smem;            // [0, 16896): 64 x 132 (epilogue)
    unsigned short* h1b = (unsigned short*)(smem + 16896);  // [16896, 26112): 64 x 72
    int* eids = (int*)(smem + 26112);                       // [26112, 26368)

    const int blk = blockIdx.x;      // 2500
    const int t = threadIdx.x;
    const int eb0 = blk * 64;
    const int lane = t & 63;
    const int wv = t >> 6;
    const int quad = lane >> 4;
    const int m15 = lane & 15;

    if (t < 64) eids[t] = edge_list[eb0 + t];
    __syncthreads();

    #pragma unroll
    for (int r = 0; r < 2; r++) {
        int idx = r * 256 + t;
        int el = idx >> 3;
        int k = idx & 7;
        ef[el * 9 + k] = edge_feats[(size_t)eids[el] * 8 + k];
    }
    __syncthreads();

    // phase 1 (VALU, f32): h0 = silu_c(ef @ w0 / sqrt(8)) -> bf16
    {
        const int e_loc = t >> 2;
        const int c0 = (t & 3) * 16;
        float a0[16];
        #pragma unroll
        for (int i = 0; i < 16; i++) a0[i] = 0.f;
        const float* efr = &ef[e_loc * 9];
        #pragma unroll
        for (int k = 0; k < 8; k++) {
            float ek = efr[k];
            float w[16];
            #pragma unroll
            for (int q4 = 0; q4 < 4; q4++)
                *(float4*)&w[q4*4] = *(const float4*)&fc_w0[k*64 + c0 + q4*4];
            #pragma unroll
            for (int i = 0; i < 16; i++) a0[i] += ek * w[i];
        }
        const float is8 = 0.35355339059f;
        S8 p0, p1;
        #pragma unroll
        for (int i = 0; i < 8; i++) {
            p0.u[i] = f2bf(silu_c(a0[i] * is8));
            p1.u[i] = f2bf(silu_c(a0[8 + i] * is8));
        }
        *(uint4*)&h0b[e_loc * 72 + c0]     = p0.q;
        *(uint4*)&h0b[e_loc * 72 + c0 + 8] = p1.q;
    }
    __syncthreads();

    // phase 2 (MFMA): h1 = silu_c(h0 @ w1 / 8)
    {
        floatx4 c2[4];
        #pragma unroll
        for (int ee = 0; ee < 4; ee++) c2[ee] = (floatx4){0.f, 0.f, 0.f, 0.f};
        const uint4* w1aq = (const uint4*)w1a;
        #pragma unroll
        for (int ks = 0; ks < 2; ks++) {
            S8 afr;
            afr.q = w1aq[(ks*4 + wv)*64 + lane];
            #pragma unroll
            for (int ee = 0; ee < 4; ee++) {
                S8 bfr;
                bfr.q = *(const uint4*)&h0b[(ee*16 + m15) * 72 + ks*32 + quad*8];
                c2[ee] = __builtin_amdgcn_mfma_f32_16x16x32_bf16(afr.v, bfr.v, c2[ee], 0, 0, 0);
            }
        }
        #pragma unroll
        for (int ee = 0; ee < 4; ee++) {
            ushort4 pk = make_ushort4(f2bf(silu_c(c2[ee][0])), f2bf(silu_c(c2[ee][1])),
                                      f2bf(silu_c(c2[ee][2])), f2bf(silu_c(c2[ee][3])));
            *(ushort4*)&h1b[(ee*16 + m15) * 72 + wv*16 + quad*4] = pk;
        }
    }
    __syncthreads();

    // phase 3 (MFMA, 4 passes of 2 m-frags); pass p covers cols p*32..p*32+31 of comp wv
    const uint4* w2aq = (const uint4*)w2a;
    #pragma unroll 1
    for (int p = 0; p < 4; p++) {
        floatx4 c3[2][4];
        #pragma unroll
        for (int mf = 0; mf < 2; mf++)
            #pragma unroll
            for (int ee = 0; ee < 4; ee++)
                c3[mf][ee] = (floatx4){0.f, 0.f, 0.f, 0.f};

        #pragma unroll
        for (int ks = 0; ks < 2; ks++) {
            S8 bfr[4];
            #pragma unroll
            for (int ee = 0; ee < 4; ee++)
                bfr[ee].q = *(const uint4*)&h1b[(ee*16 + m15) * 72 + ks*32 + quad*8];
            #pragma unroll
            for (int mf = 0; mf < 2; mf++) {
                S8 afr;
                afr.q = w2aq[(size_t)(ks*32 + wv*8 + p*2 + mf) * 64 + lane];
                #pragma unroll
                for (int ee = 0; ee < 4; ee++)
                    c3[mf][ee] = __builtin_amdgcn_mfma_f32_16x16x32_bf16(afr.v, bfr[ee].v, c3[mf][ee], 0, 0, 0);
            }
        }

        __syncthreads();   // T region free (prev pass stores done / ef+h0b dead)
        // dump interleaved: T[e*132 + col'*4 + comp], comp = wv
        #pragma unroll
        for (int mf = 0; mf < 2; mf++) {
            #pragma unroll
            for (int ee = 0; ee < 4; ee++) {
                int e = ee*16 + m15;
                #pragma unroll
                for (int i = 0; i < 4; i++) {
                    int colp = mf*16 + quad*4 + i;
                    T[e*132 + colp*4 + wv] = f2bf(c3[mf][ee][i]);
                }
            }
        }
        __syncthreads();

        // coalesced store: uint2 per (e, cu); per e-row 256 B contiguous
        #pragma unroll
        for (int it = 0; it < 8; it++) {
            int idx = it * 256 + t;          // 0..2047
            int e  = idx >> 5;
            int cu = idx & 31;
            uint2x v = *(const uint2x*)&T[e*132 + cu*4];
            unsigned short* dstp = w_pk + ((size_t)(eb0 + e) * 128 + p*32 + cu) * 4;
            *(uint2x*)dstp = v;
        }
    }
}

// ---------------- Kernel B2: wave-per-node gather, depth-4 slot pipeline -------
// One 64-lane wave per node (grid 2500 x 4). Lane owns 2 u-slots (16 B loads).
// Four named slots A..D hold edges i..i+3; each slot is reloaded to edge i+4+k
// immediately after its consume (no register rotation; all indices static).
// 12 loads in flight/wave; issue-to-consume ~ one full 4-edge body.
__global__ __launch_bounds__(256) void gather_kernel(
    const int* __restrict__ row_start,
    const int* __restrict__ srcs,
    const float* __restrict__ ea_sorted,
    const unsigned short* __restrict__ w_pk,
    const unsigned short* __restrict__ y_pk,
    float* __restrict__ accS,
    float* __restrict__ accV)
{
    const int t = threadIdx.x;
    const int n = blockIdx.x * 4 + (t >> 6);   // wave-per-node, grid 2500
    const int lane = t & 63;
    const int u0 = lane << 1;                  // u0, u0+1

    const int eb = row_start[n];
    const int ee = row_start[n + 1];

    float aS0a=0.f,aS0b=0.f, aS1a=0.f,aS1b=0.f;
    float aV2ax=0.f,aV2ay=0.f,aV2az=0.f, aV2bx=0.f,aV2by=0.f,aV2bz=0.f;
    float aV3ax=0.f,aV3ay=0.f,aV3az=0.f, aV3bx=0.f,aV3by=0.f,aV3bz=0.f;

    auto consume = [&](const S8& w8, const S8& y8, const float4& ea) {
        // u0 slot
        {
            float wss = bf2f(w8.u[0]), wsv = bf2f(w8.u[1]);
            float wvs = bf2f(w8.u[2]), wvv = bf2f(w8.u[3]);
            float qs = bf2f(y8.u[0]), q0 = bf2f(y8.u[1]), q1 = bf2f(y8.u[2]), q2 = bf2f(y8.u[3]);
            aS0a += wss * qs * ea.x;
            aS1a += wvv * (q0*ea.y + q1*ea.z + q2*ea.w);
            float tsv = wsv * qs;
            aV2ax += tsv * ea.y; aV2ay += tsv * ea.z; aV2az += tsv * ea.w;
            float tvs = wvs * ea.x;
            aV3ax += tvs * q0; aV3ay += tvs * q1; aV3az += tvs * q2;
        }
        // u0+1 slot
        {
            float wss = bf2f(w8.u[4]), wsv = bf2f(w8.u[5]);
            float wvs = bf2f(w8.u[6]), wvv = bf2f(w8.u[7]);
            float qs = bf2f(y8.u[4]), q0 = bf2f(y8.u[5]), q1 = bf2f(y8.u[6]), q2 = bf2f(y8.u[7]);
            aS0b += wss * qs * ea.x;
            aS1b += wvv * (q0*ea.y + q1*ea.z + q2*ea.w);
            float tsv = wsv * qs;
            aV2bx += tsv * ea.y; aV2by += tsv * ea.z; aV2bz += tsv * ea.w;
            float tvs = wvs * ea.x;
            aV3bx += tvs * q0; aV3by += tvs * q1; aV3bz += tvs * q2;
        }
    };

    if (eb < ee) {
        const int lastE = ee - 1;
        auto cl = [&](int j) { return (j < lastE) ? j : lastE; };
        auto wload = [&](int j, S8& w) {
            w.qx = __builtin_nontemporal_load((const uint4x*)(w_pk + ((size_t)j * 128 + u0) * 4));
        };
        auto yload = [&](int s, S8& y) {
            y.q = *(const uint4*)(y_pk + ((size_t)s * 128 + u0) * 4);
        };
        auto eload = [&](int j) -> float4 {
            return *(const float4*)(ea_sorted + (size_t)j * 4);
        };

        // initial 4-edge window
        S8 wA, wB, wC, wD, yA, yB, yC, yD;
        float4 eA, eB, eC, eD;
        wload(eb, wA);        yload(srcs[eb], yA);        eA = eload(eb);
        wload(cl(eb+1), wB);  yload(srcs[cl(eb+1)], yB);  eB = eload(cl(eb+1));
        wload(cl(eb+2), wC);  yload(srcs[cl(eb+2)], yC);  eC = eload(cl(eb+2));
        wload(cl(eb+3), wD);  yload(srcs[cl(eb+3)], yD);  eD = eload(cl(eb+3));
        // srcs lookahead for the next window (edges i+4..i+7)
        int sE4 = srcs[cl(eb+4)], sE5 = srcs[cl(eb+5)];
        int sE6 = srcs[cl(eb+6)], sE7 = srcs[cl(eb+7)];

        for (int i = eb; i < ee; i += 4) {
            // slot A: consume edge i (always valid), reload to edge i+4
            consume(wA, yA, eA);
            { int j = cl(i+4); wload(j, wA); eA = eload(j); yload(sE4, yA); }
            // slot B: edge i+1 (wave-uniform guard), reload to i+5
            if (i + 1 < ee) consume(wB, yB, eB);
            { int j = cl(i+5); wload(j, wB); eB = eload(j); yload(sE5, yB); }
            // slot C: edge i+2, reload to i+6
            if (i + 2 < ee) consume(wC, yC, eC);
            { int j = cl(i+6); wload(j, wC); eC = eload(j); yload(sE6, yC); }
            // slot D: edge i+3, reload to i+7
            if (i + 3 < ee) consume(wD, yD, eD);
            { int j = cl(i+7); wload(j, wD); eD = eload(j); yload(sE7, yD); }
            // refresh srcs lookahead for edges i+8..i+11 (next window)
            sE4 = srcs[cl(i+8)];  sE5 = srcs[cl(i+9)];
            sE6 = srcs[cl(i+10)]; sE7 = srcs[cl(i+11)];
        }
    }

    const float inv = 0.25f;                   // 1/sqrt(16)
    const float s1c = 0.57735026919f * 0.25f;
    *(float2*)(accS + (size_t)n*256 + u0)        = make_float2(aS0a*inv, aS0b*inv);
    *(float2*)(accS + (size_t)n*256 + 128 + u0)  = make_float2(aS1a*s1c, aS1b*s1c);
    *(float2*)(accV + ((size_t)n*3+0)*256 + u0)       = make_float2(aV2ax*inv, aV2bx*inv);
    *(float2*)(accV + ((size_t)n*3+0)*256 + 128 + u0) = make_float2(aV3ax*inv, aV3bx*inv);
    *(float2*)(accV + ((size_t)n*3+1)*256 + u0)       = make_float2(aV2ay*inv, aV2by*inv);
    *(float2*)(accV + ((size_t)n*3+1)*256 + 128 + u0) = make_float2(aV3ay*inv, aV3by*inv);
    *(float2*)(accV + ((size_t)n*3+2)*256 + u0)       = make_float2(aV2az*inv, aV2bz*inv);
    *(float2*)(accV + ((size_t)n*3+2)*256 + 128 + u0) = make_float2(aV3az*inv, aV3bz*inv);
}

// ---------------- node_out as MFMA GEMM, latency-pipelined ----------------
__global__ __launch_bounds__(256) void node_out_mfma(
    const float* __restrict__ node_feats,
    const float* __restrict__ node_attrs,
    const unsigned short* __restrict__ xvP16,
    const float* __restrict__ accS,
    const float* __restrict__ accV,
    const unsigned short* __restrict__ b_pre,
    float* __restrict__ out)
{
    __shared__ __align__(16) short8x Abuf[2][256];   // 2 x 4 KB double buffer
    const int bid = blockIdx.x;
    const int t = threadIdx.x;
    const int lane = t & 63;
    const int wv = t >> 6;
    const bool is_s = (bid < SO_BLK);

    // this thread's A slot: row r (0..63), k-quad (0..3); slot index == t
    const int r    = ((t >> 6) << 4) + (t & 15);
    const int q8   = ((t >> 4) & 3) * 8;

    const float* px = nullptr;
    const unsigned short* pxv = nullptr;
    const float* pa;
    const float* pat;
    if (is_s) {
        int R = bid * 64 + r;
        int node = (R < N_NODES) ? R : 0;
        px  = node_feats + (size_t)node * 512;
        pa  = accS + (size_t)node * 256;
        pat = node_attrs + node * 10;
    } else {
        int Rg = (bid - SO_BLK) * 64 + r;
        if (Rg >= 3 * N_NODES) Rg = 0;
        int node = Rg / 3;
        pxv = xvP16 + (size_t)Rg * 128;
        pa  = accV + (size_t)Rg * 256;
        pat = node_attrs + node * 10;
    }

    const uint4* bb = (const uint4*)(b_pre) + (is_s ? 0 : 24576);
    const float sc_norm = 0.02795084972f;   // 1/sqrt(1280)
    const float l2 = 0.0625f;               // 1/sqrt(256)

    // ---- preload the 4 sc-part A chunks for this (row, quad) ----
    float xf[4][8];
    S8    xh[4];
    if (is_s) {
        #pragma unroll
        for (int c = 0; c < 4; c++) {
            floatx4 lo = *(const floatx4*)&px[c*32 + q8];
            floatx4 hi = *(const floatx4*)&px[c*32 + q8 + 4];
            #pragma unroll
            for (int i = 0; i < 4; i++) { xf[c][i] = lo[i]; xf[c][4+i] = hi[i]; }
        }
    } else {
        #pragma unroll
        for (int c = 0; c < 4; c++)
            xh[c].q = *(const uint4*)&pxv[c*32 + q8];
    }
    float attC = pat[0] * sc_norm;

    floatx4 acc[4][2];
    #pragma unroll
    for (int af = 0; af < 4; af++) {
        acc[af][0] = (floatx4){0.f, 0.f, 0.f, 0.f};
        acc[af][1] = (floatx4){0.f, 0.f, 0.f, 0.f};
    }

    const int cof0 = (wv*2+0)*64 + lane;
    const int cof1 = (wv*2+1)*64 + lane;

    auto packx = [&](int c_, float att_) -> short8x {
        S8 pk;
        if (is_s) {
            #pragma unroll
            for (int i = 0; i < 8; i++) pk.u[i] = f2bf(xf[c_][i] * att_);
        } else {
            #pragma unroll
            for (int i = 0; i < 8; i++) pk.u[i] = f2bf(bf2f(xh[c_].u[i]) * att_);
        }
        return pk.v;
    };
    auto mstep = [&](int kb, const S8& b0, const S8& b1) {
        __builtin_amdgcn_s_setprio(1);
        #pragma unroll
        for (int af = 0; af < 4; af++) {
            short8x a = Abuf[kb][af*64 + lane];
            acc[af][0] = __builtin_amdgcn_mfma_f32_16x16x32_bf16(a, b0.v, acc[af][0], 0, 0, 0);
            acc[af][1] = __builtin_amdgcn_mfma_f32_16x16x32_bf16(a, b1.v, acc[af][1], 0, 0, 0);
        }
        __builtin_amdgcn_s_setprio(0);
    };
    auto bload = [&](int k2, S8& b0, S8& b1) {
        b0.q = bb[(size_t)k2*512 + cof0];
        b1.q = bb[(size_t)k2*512 + cof1];
    };
    auto barrier_ = [&]() {
        asm volatile("s_waitcnt lgkmcnt(0)" ::: "memory");
        __builtin_amdgcn_s_barrier();
    };

    // B prefetch (depth 2)
    S8 bA0, bA1, bB0, bB1;
    bload(0, bA0, bA1);
    bload(1, bB0, bB1);

    // prologue: A(0) -> buf0
    Abuf[0][t] = packx(0, attC);
    barrier_();

    // ---- main loop: ks = 0..35 (vblk 0..8), A from preloaded chunks ----
    #pragma unroll 1
    for (int vb = 0; vb < 9; vb++) {
        float attN = pat[vb + 1] * sc_norm;
        const int ksb = vb * 4;
        Abuf[1][t] = packx(1, attC); mstep(0, bA0, bA1); bload(ksb+2, bA0, bA1); barrier_();
        Abuf[0][t] = packx(2, attC); mstep(1, bB0, bB1); bload(ksb+3, bB0, bB1); barrier_();
        Abuf[1][t] = packx(3, attC); mstep(0, bA0, bA1); bload(ksb+4, bA0, bA1); barrier_();
        Abuf[0][t] = packx(0, attN); mstep(1, bB0, bB1); bload(ksb+5, bB0, bB1); barrier_();
        attC = attN;
    }

    // ---- ks = 36..47 explicit (attC == pat[9]); tail A from acc (depth-2) ----
    floatx4 aT0[2], aT1[2];
    auto issue0 = [&](int k_) { int j2 = (k_-40)*32 + q8;
        aT0[0] = *(const floatx4*)&pa[j2]; aT0[1] = *(const floatx4*)&pa[j2+4]; };
    auto issue1 = [&](int k_) { int j2 = (k_-40)*32 + q8;
        aT1[0] = *(const floatx4*)&pa[j2]; aT1[1] = *(const floatx4*)&pa[j2+4]; };
    auto packT = [&](const floatx4* a2) -> short8x {
        S8 pk;
        #pragma unroll
        for (int i = 0; i < 4; i++) { pk.u[i] = f2bf(a2[0][i] * l2); pk.u[4+i] = f2bf(a2[1][i] * l2); }
        return pk.v;
    };

    // ks=36
    Abuf[1][t] = packx(1, attC); mstep(0, bA0, bA1); bload(38, bA0, bA1); barrier_();
    // ks=37
    Abuf[0][t] = packx(2, attC); mstep(1, bB0, bB1); bload(39, bB0, bB1); barrier_();
    // ks=38
    issue0(40);
    Abuf[1][t] = packx(3, attC); mstep(0, bA0, bA1); bload(40, bA0, bA1); barrier_();
    // ks=39
    issue1(41);
    Abuf[0][t] = packT(aT0); mstep(1, bB0, bB1); bload(41, bB0, bB1); barrier_();
    // ks=40
    issue0(42);
    Abuf[1][t] = packT(aT1); mstep(0, bA0, bA1); bload(42, bA0, bA1); barrier_();
    // ks=41
    issue1(43);
    Abuf[0][t] = packT(aT0); mstep(1, bB0, bB1); bload(43, bB0, bB1); barrier_();
    // ks=42
    issue0(44);
    Abuf[1][t] = packT(aT1); mstep(0, bA0, bA1); bload(44, bA0, bA1); barrier_();
    // ks=43
    issue1(45);
    Abuf[0][t] = packT(aT0); mstep(1, bB0, bB1); bload(45, bB0, bB1); barrier_();
    // ks=44
    issue0(46);
    Abuf[1][t] = packT(aT1); mstep(0, bA0, bA1); bload(46, bA0, bA1); barrier_();
    // ks=45
    issue1(47);
    Abuf[0][t] = packT(aT0); mstep(1, bB0, bB1); bload(47, bB0, bB1); barrier_();
    // ks=46
    Abuf[1][t] = packT(aT1); mstep(0, bA0, bA1); barrier_();
    // ks=47
    mstep(1, bB0, bB1);

    // ---- epilogue ----
    const int m = lane & 15;
    const int rq = (lane >> 4) * 4;
    if (is_s) {
        const int n0 = bid * 64;
        #pragma unroll
        for (int af = 0; af < 4; af++) {
            #pragma unroll
            for (int i = 0; i < 4; i++) {
                int n = n0 + af*16 + rq + i;
                if (n < N_NODES) {
                    out[(size_t)n*512 + wv*32 + m]      = acc[af][0][i];
                    out[(size_t)n*512 + wv*32 + 16 + m] = acc[af][1][i];
                }
            }
        }
    } else {
        const int r0 = (bid - SO_BLK) * 64;
        #pragma unroll
        for (int af = 0; af < 4; af++) {
            #pragma unroll
            for (int i = 0; i < 4; i++) {
                int Rg = r0 + af*16 + rq + i;
                if (Rg < 3 * N_NODES) {
                    int nn = Rg / 3;
                    int cc = Rg - nn * 3;
                    float* po = out + (size_t)nn*512 + 128 + cc;
                    po[(wv*32 + m)*3]      = acc[af][0][i];
                    po[(wv*32 + 16 + m)*3] = acc[af][1][i];
                }
            }
        }
    }
}

extern "C" void kernel_launch(void* const* d_in, const int* in_sizes, int n_in,
                              void* d_out, int out_size, void* d_ws, size_t ws_size,
                              hipStream_t stream) {
    const float* node_feats = (const float*)d_in[0];
    const float* node_attrs = (const float*)d_in[1];
    const float* edge_feats = (const float*)d_in[2];
    const float* edge_attrs = (const float*)d_in[3];
    const int*   edge_index = (const int*)  d_in[4];
    const float* lin1_ws    = (const float*)d_in[5];
    const float* lin1_wv    = (const float*)d_in[6];
    const float* fc_w0      = (const float*)d_in[7];
    const float* fc_w1      = (const float*)d_in[8];
    const float* fc_w2      = (const float*)d_in[9];
    const float* lin2_ws    = (const float*)d_in[10];
    const float* lin2_wv    = (const float*)d_in[11];
    const float* sc_ws      = (const float*)d_in[12];
    const float* sc_wv      = (const float*)d_in[13];
    float* out = (float*)d_out;

    // workspace layout
    unsigned short* y_pk  = (unsigned short*)d_ws;            // 5,120,000 us
    float* accS = (float*)(y_pk + (size_t)5120000);           // 2,560,000 f32
    float* accV = accS + (size_t)2560000;                     // 7,680,000 f32
    unsigned short* xvP16 = (unsigned short*)(accV + (size_t)7680000);  // 3,840,000 us
    unsigned short* w_pk  = xvP16 + (size_t)3840000;          // 81,920,000 us
    int* deg       = (int*)(w_pk + (size_t)81920000);
    int* row_start = deg + 10016;
    int* cursor    = row_start + 10016;
    int* edge_list = cursor + 10016;
    int* srcs      = edge_list + N_EDGES;
    float* ea_sorted = (float*)(srcs + N_EDGES);
    unsigned short* b_pre = (unsigned short*)(ea_sorted + (size_t)N_EDGES * 4);
    unsigned short* w2a   = b_pre + (size_t)2 * 24576 * 8;
    unsigned short* w1a   = w2a + (size_t)4096 * 8;
    unsigned short* b_lin = w1a + (size_t)512 * 8;
    const size_t need = (size_t)5120000 * 2 + (size_t)(2560000 + 7680000) * 4
                      + (size_t)3840000 * 2 + (size_t)81920000 * 2
                      + (size_t)(10016 * 3 + N_EDGES * 2) * 4
                      + (size_t)N_EDGES * 4 * 4
                      + ((size_t)2 * 24576 * 8 + (size_t)4096 * 8 + (size_t)512 * 8
                         + (size_t)4096 * 8) * 2;
    if (ws_size < need) return;

    hipLaunchKernelGGL(pack_all_kernel, dim3(266), dim3(256), 0, stream,
                       sc_ws, lin2_ws, sc_wv, lin2_wv, fc_w2, fc_w1, lin1_ws, lin1_wv,
                       b_pre, w2a, w1a, b_lin, deg);
    hipLaunchKernelGGL(node_lin1_mfma, dim3(313), dim3(256), 0, stream,
                       node_feats, b_lin, y_pk, xvP16);

    hipLaunchKernelGGL(hist_kernel, dim3(625), dim3(256), 0, stream, edge_index, deg);
    hipLaunchKernelGGL(scan_kernel, dim3(1), dim3(1024), 0, stream, deg, row_start, cursor);
    hipLaunchKernelGGL(scatter_kernel, dim3(625), dim3(256), 0, stream,
                       edge_index, edge_attrs, cursor, edge_list, srcs, ea_sorted);
    hipLaunchKernelGGL(edge_w_mfma, dim3(2500), dim3(256), 0, stream,
                       edge_feats, edge_list, fc_w0, w1a, w2a, w_pk);
    hipLaunchKernelGGL(gather_kernel, dim3(2500), dim3(256), 0, stream,
                       row_start, srcs, ea_sorted, w_pk, y_pk, accS, accV);

    hipLaunchKernelGGL(node_out_mfma, dim3(SO_BLK + VO_BLK), dim3(256), 0, stream,
                       node_feats, node_attrs, xvP16, accS, accV, b_pre, out);
}

// Round 12
// 281.211 us; speedup vs baseline: 1.9068x; 1.0197x over previous
//
#include <hip/hip_runtime.h>
#include <hip/hip_bf16.h>
#include <math.h>

#define N_NODES 10000
#define N_EDGES 160000
#define SO_BLK 157          // ceil(10000/64) s-GEMM blocks
#define VO_BLK 469          // ceil(30000/64) v-GEMM blocks

typedef __attribute__((ext_vector_type(8))) short short8x;
typedef __attribute__((ext_vector_type(4))) float floatx4;
typedef __attribute__((ext_vector_type(4))) unsigned int uint4x;
typedef __attribute__((ext_vector_type(2))) unsigned int uint2x;

union S8 { short8x v; unsigned short u[8]; uint4 q; uint4x qx; };
union U2 { uint2x v; unsigned short us[4]; };

__device__ __forceinline__ unsigned short f2bf(float x) {
    unsigned int u = __float_as_uint(x);
    return (unsigned short)((u + 0x7fffu + ((u >> 16) & 1u)) >> 16);
}
__device__ __forceinline__ float bf2f(unsigned short u) {
    return __uint_as_float(((unsigned)u) << 16);
}
__device__ __forceinline__ float silu_c(float x) {
    return 1.679f * x / (1.0f + __expf(-x));
}

// ---------------- pack_all: all weight pre-packs in one launch ----------------
// blocks [0,192): b_pre; [192,208): w2a; [208,210): w1a; [210,226): b_lin
__global__ __launch_bounds__(256) void pack_all_kernel(
    const float* __restrict__ sc_ws, const float* __restrict__ lin2_ws,
    const float* __restrict__ sc_wv, const float* __restrict__ lin2_wv,
    const float* __restrict__ fc_w2, const float* __restrict__ fc_w1,
    const float* __restrict__ lin1_ws, const float* __restrict__ lin1_wv,
    unsigned short* __restrict__ b_pre, unsigned short* __restrict__ w2a,
    unsigned short* __restrict__ w1a, unsigned short* __restrict__ b_lin)
{
    const int bid = blockIdx.x;
    const int t = threadIdx.x;
    if (bid < 192) {
        int id = bid * 256 + t;                  // 0..49151
        int mat = id / 24576;
        int slot = id - mat * 24576;
        int ks = slot >> 9;
        int rr = slot & 511;
        int lane = rr & 63;
        int quad = lane >> 4;
        int n = ((rr >> 6) << 4) + (lane & 15);
        const float* sc  = mat ? sc_wv  : sc_ws;
        const float* lin = mat ? lin2_wv : lin2_ws;
        S8 pk;
        #pragma unroll
        for (int j = 0; j < 8; j++) {
            int k = ks * 32 + quad * 8 + j;
            float w;
            if (k < 1280) {
                int u = k & 127, v = k >> 7;
                w = sc[(u * 10 + v) * 128 + n];
            } else {
                w = lin[(k - 1280) * 128 + n];
            }
            pk.u[j] = f2bf(w);
        }
        *(uint4*)(b_pre + (size_t)id * 8) = pk.q;
    } else if (bid < 208) {
        int id = (bid - 192) * 256 + t;          // 0..4095
        int lane = id & 63;
        int mfg = (id >> 6) & 31;
        int ks = id >> 11;
        int col = mfg * 16 + (lane & 15);
        int k0 = ks * 32 + (lane >> 4) * 8;
        S8 pk;
        #pragma unroll
        for (int j = 0; j < 8; j++)
            pk.u[j] = f2bf(fc_w2[(k0 + j) * 512 + col] * 0.125f);
        *(uint4*)(w2a + (size_t)id * 8) = pk.q;
    } else if (bid < 210) {
        int id = (bid - 208) * 256 + t;          // 0..511
        int lane = id & 63;
        int mf = (id >> 6) & 3;
        int ks = id >> 8;
        int m = mf * 16 + (lane & 15);
        int k0 = ks * 32 + (lane >> 4) * 8;
        S8 pk;
        #pragma unroll
        for (int j = 0; j < 8; j++)
            pk.u[j] = f2bf(fc_w1[(k0 + j) * 64 + m] * 0.125f);
        *(uint4*)(w1a + (size_t)id * 8) = pk.q;
    } else {
        int id = (bid - 210) * 256 + t;          // 0..4095
        int mat = id >> 11;
        int slot = id & 2047;
        int ks = slot >> 9;
        int rr = slot & 511;
        int nf = rr >> 6;
        int lane = rr & 63;
        int n = nf * 16 + (lane & 15);
        int k0 = ks * 32 + (lane >> 4) * 8;
        const float* w = mat ? lin1_wv : lin1_ws;
        const float l1 = 0.0883883476483f;
        S8 pk;
        #pragma unroll
        for (int j = 0; j < 8; j++)
            pk.u[j] = f2bf(w[(k0 + j) * 128 + n] * l1);
        *(uint4*)(b_lin + (size_t)id * 8) = pk.q;
    }
}

// ---------------- Kernel A: lin1 via MFMA -> packed bf16 y + bf16 xvP ----------------
// 16 nodes/block (M=64 rows: comp = af), grid 625 = 2.4 blocks/CU, LDS 16 KB.
__global__ __launch_bounds__(256) void node_lin1_mfma(
    const float* __restrict__ node_feats,
    const unsigned short* __restrict__ b_lin,
    unsigned short* __restrict__ y_pk,
    unsigned short* __restrict__ xvP16)
{
    __shared__ __align__(16) unsigned char smem[16384];
    short8x* Al = (short8x*)smem;
    unsigned short* Yt = (unsigned short*)smem;

    const int blk = blockIdx.x;   // 625
    const int t = threadIdx.x;
    const int base = blk * 16;
    const int lane = t & 63;
    const int wv = t >> 6;
    const int m15 = lane & 15;
    const int k0q = (lane >> 4) * 8;

    #pragma unroll
    for (int it = 0; it < 4; it++) {
        int g = wv * 4 + it;          // 0..15
        int af = g >> 2;              // 0..3  (== comp)
        int ks = g & 3;               // 0..3
        int node = base + m15;
        int valid = (node < N_NODES);
        if (!valid) node = N_NODES - 1;
        int k0 = ks * 32 + k0q;
        const float* row = node_feats + (size_t)node * 512;
        S8 pk;
        if (af == 0) {
            float4 a = *(const float4*)&row[k0];
            float4 b = *(const float4*)&row[k0 + 4];
            pk.u[0] = f2bf(a.x); pk.u[1] = f2bf(a.y); pk.u[2] = f2bf(a.z); pk.u[3] = f2bf(a.w);
            pk.u[4] = f2bf(b.x); pk.u[5] = f2bf(b.y); pk.u[6] = f2bf(b.z); pk.u[7] = f2bf(b.w);
        } else {
            int c = af - 1;
            #pragma unroll
            for (int j = 0; j < 8; j++)
                pk.u[j] = f2bf(row[128 + (k0 + j) * 3 + c]);
            if (valid)
                *(uint4*)&xvP16[((size_t)node * 3 + c) * 128 + k0] = pk.q;
        }
        Al[(ks * 4 + af) * 64 + lane] = pk.v;
    }
    __syncthreads();

    floatx4 c[4][2];
    #pragma unroll
    for (int af = 0; af < 4; af++) {
        c[af][0] = (floatx4){0.f, 0.f, 0.f, 0.f};
        c[af][1] = (floatx4){0.f, 0.f, 0.f, 0.f};
    }

    const uint4* bq = (const uint4*)b_lin;
    #pragma unroll
    for (int ks = 0; ks < 4; ks++) {
        S8 bs0, bs1, bv0, bv1;
        bs0.q = bq[       ks*512 + (wv*2+0)*64 + lane];
        bs1.q = bq[       ks*512 + (wv*2+1)*64 + lane];
        bv0.q = bq[2048 + ks*512 + (wv*2+0)*64 + lane];
        bv1.q = bq[2048 + ks*512 + (wv*2+1)*64 + lane];
        #pragma unroll
        for (int af = 0; af < 4; af++) {
            short8x a = Al[(ks*4 + af)*64 + lane];
            if (af == 0) {
                c[af][0] = __builtin_amdgcn_mfma_f32_16x16x32_bf16(a, bs0.v, c[af][0], 0, 0, 0);
                c[af][1] = __builtin_amdgcn_mfma_f32_16x16x32_bf16(a, bs1.v, c[af][1], 0, 0, 0);
            } else {
                c[af][0] = __builtin_amdgcn_mfma_f32_16x16x32_bf16(a, bv0.v, c[af][0], 0, 0, 0);
                c[af][1] = __builtin_amdgcn_mfma_f32_16x16x32_bf16(a, bv1.v, c[af][1], 0, 0, 0);
            }
        }
    }
    __syncthreads();

    {
        const int rq = (lane >> 4) * 4;
        #pragma unroll
        for (int af = 0; af < 4; af++) {
            #pragma unroll
            for (int nf = 0; nf < 2; nf++) {
                int u = wv * 32 + nf * 16 + m15;
                #pragma unroll
                for (int i = 0; i < 4; i++) {
                    int nloc = rq + i;           // row m = af*16 + nloc; comp = af
                    Yt[(nloc * 128 + u) * 4 + af] = f2bf(c[af][nf][i]);
                }
            }
        }
    }
    __syncthreads();
    {
        unsigned short* dst = y_pk + (size_t)base * 512;
        int nrem = N_NODES - base;
        #pragma unroll
        for (int it = 0; it < 4; it++) {
            int idx = it * 256 + t;              // 0..1023 (16 nodes x 64 groups)
            if ((idx >> 6) < nrem)
                *(uint4*)(dst + (size_t)idx * 8) = *(const uint4*)&Yt[idx * 8];
        }
    }
}

// ---------------- CSR build ----------------
__global__ __launch_bounds__(256) void hist_kernel(const int* __restrict__ edge_index,
                                                   int* __restrict__ deg) {
    int e = blockIdx.x * 256 + threadIdx.x;
    if (e < N_EDGES) atomicAdd(&deg[edge_index[e]], 1);
}

__global__ __launch_bounds__(1024) void scan_kernel(const int* __restrict__ deg,
                                                    int* __restrict__ row_start,
                                                    int* __restrict__ cursor) {
    __shared__ int wsum[16];
    __shared__ int carry_s;
    const int t = threadIdx.x;
    const int lane = t & 63, w = t >> 6;
    if (t == 0) carry_s = 0;
    __syncthreads();
    for (int chunk = 0; chunk < 10; chunk++) {
        int idx = chunk * 1024 + t;
        int v = (idx < N_NODES) ? deg[idx] : 0;
        int x = v;
        #pragma unroll
        for (int off = 1; off < 64; off <<= 1) {
            int yv = __shfl_up(x, off, 64);
            if (lane >= off) x += yv;
        }
        if (lane == 63) wsum[w] = x;
        __syncthreads();
        int wpre = 0;
        for (int i = 0; i < w; i++) wpre += wsum[i];
        int incl = x + wpre + carry_s;
        int excl = incl - v;
        if (idx < N_NODES) { row_start[idx] = excl; cursor[idx] = excl; }
        __syncthreads();
        if (t == 1023) carry_s = incl;
        __syncthreads();
    }
    if (t == 0) row_start[N_NODES] = carry_s;
}

__global__ __launch_bounds__(256) void scatter_kernel(const int* __restrict__ edge_index,
                                                      const float* __restrict__ edge_attrs,
                                                      int* __restrict__ cursor,
                                                      int* __restrict__ edge_list,
                                                      int* __restrict__ srcs,
                                                      float* __restrict__ ea_sorted) {
    int e = blockIdx.x * 256 + threadIdx.x;
    if (e < N_EDGES) {
        int pos = atomicAdd(&cursor[edge_index[e]], 1);
        edge_list[pos] = e;
        srcs[pos] = edge_index[N_EDGES + e];
        float4 ea = *(const float4*)(edge_attrs + (size_t)e * 4);
        *(float4*)(ea_sorted + (size_t)pos * 4) = ea;
    }
}

// ---------------- Kernel B1: edge MLP (sorted order) -> packed bf16 w ----------------
// w_pk[pos][u][4] = bf16{ss, sv, vs, vv}; normal (MALL-allocating) stores.
__global__ __launch_bounds__(256) void edge_w_mfma(
    const float* __restrict__ edge_feats,
    const int* __restrict__ edge_list,
    const float* __restrict__ fc_w0,
    const unsigned short* __restrict__ w1a,
    const unsigned short* __restrict__ w2a,
    unsigned short* __restrict__ w_pk)
{
    __shared__ __align__(16) unsigned char smem[26368];
    float* ef = (float*)smem;                               // [0, 2304)
    unsigned short* h0b = (unsigned short*)(smem + 2304);   // [2304, 11520): 64 x 72
    unsigned short* T   = (unsigned short*)smem;            // [0, 16896): 64 x 132 (epilogue)
    unsigned short* h1b = (unsigned short*)(smem + 16896);  // [16896, 26112): 64 x 72
    int* eids = (int*)(smem + 26112);                       // [26112, 26368)

    const int blk = blockIdx.x;      // 2500
    const int t = threadIdx.x;
    const int eb0 = blk * 64;
    const int lane = t & 63;
    const int wv = t >> 6;
    const int quad = lane >> 4;
    const int m15 = lane & 15;

    if (t < 64) eids[t] = edge_list[eb0 + t];
    __syncthreads();

    #pragma unroll
    for (int r = 0; r < 2; r++) {
        int idx = r * 256 + t;
        int el = idx >> 3;
        int k = idx & 7;
        ef[el * 9 + k] = edge_feats[(size_t)eids[el] * 8 + k];
    }
    __syncthreads();

    // phase 1 (VALU, f32): h0 = silu_c(ef @ w0 / sqrt(8)) -> bf16
    {
        const int e_loc = t >> 2;
        const int c0 = (t & 3) * 16;
        float a0[16];
        #pragma unroll
        for (int i = 0; i < 16; i++) a0[i] = 0.f;
        const float* efr = &ef[e_loc * 9];
        #pragma unroll
        for (int k = 0; k < 8; k++) {
            float ek = efr[k];
            float w[16];
            #pragma unroll
            for (int q4 = 0; q4 < 4; q4++)
                *(float4*)&w[q4*4] = *(const float4*)&fc_w0[k*64 + c0 + q4*4];
            #pragma unroll
            for (int i = 0; i < 16; i++) a0[i] += ek * w[i];
        }
        const float is8 = 0.35355339059f;
        S8 p0, p1;
        #pragma unroll
        for (int i = 0; i < 8; i++) {
            p0.u[i] = f2bf(silu_c(a0[i] * is8));
            p1.u[i] = f2bf(silu_c(a0[8 + i] * is8));
        }
        *(uint4*)&h0b[e_loc * 72 + c0]     = p0.q;
        *(uint4*)&h0b[e_loc * 72 + c0 + 8] = p1.q;
    }
    __syncthreads();

    // phase 2 (MFMA): h1 = silu_c(h0 @ w1 / 8)
    {
        floatx4 c2[4];
        #pragma unroll
        for (int ee = 0; ee < 4; ee++) c2[ee] = (floatx4){0.f, 0.f, 0.f, 0.f};
        const uint4* w1aq = (const uint4*)w1a;
        #pragma unroll
        for (int ks = 0; ks < 2; ks++) {
            S8 afr;
            afr.q = w1aq[(ks*4 + wv)*64 + lane];
            #pragma unroll
            for (int ee = 0; ee < 4; ee++) {
                S8 bfr;
                bfr.q = *(const uint4*)&h0b[(ee*16 + m15) * 72 + ks*32 + quad*8];
                c2[ee] = __builtin_amdgcn_mfma_f32_16x16x32_bf16(afr.v, bfr.v, c2[ee], 0, 0, 0);
            }
        }
        #pragma unroll
        for (int ee = 0; ee < 4; ee++) {
            ushort4 pk = make_ushort4(f2bf(silu_c(c2[ee][0])), f2bf(silu_c(c2[ee][1])),
                                      f2bf(silu_c(c2[ee][2])), f2bf(silu_c(c2[ee][3])));
            *(ushort4*)&h1b[(ee*16 + m15) * 72 + wv*16 + quad*4] = pk;
        }
    }
    __syncthreads();

    // phase 3 (MFMA, 4 passes of 2 m-frags); pass p covers cols p*32..p*32+31 of comp wv
    const uint4* w2aq = (const uint4*)w2a;
    #pragma unroll 1
    for (int p = 0; p < 4; p++) {
        floatx4 c3[2][4];
        #pragma unroll
        for (int mf = 0; mf < 2; mf++)
            #pragma unroll
            for (int ee = 0; ee < 4; ee++)
                c3[mf][ee] = (floatx4){0.f, 0.f, 0.f, 0.f};

        #pragma unroll
        for (int ks = 0; ks < 2; ks++) {
            S8 bfr[4];
            #pragma unroll
            for (int ee = 0; ee < 4; ee++)
                bfr[ee].q = *(const uint4*)&h1b[(ee*16 + m15) * 72 + ks*32 + quad*8];
            #pragma unroll
            for (int mf = 0; mf < 2; mf++) {
                S8 afr;
                afr.q = w2aq[(size_t)(ks*32 + wv*8 + p*2 + mf) * 64 + lane];
                #pragma unroll
                for (int ee = 0; ee < 4; ee++)
                    c3[mf][ee] = __builtin_amdgcn_mfma_f32_16x16x32_bf16(afr.v, bfr[ee].v, c3[mf][ee], 0, 0, 0);
            }
        }

        __syncthreads();   // T region free (prev pass stores done / ef+h0b dead)
        // dump interleaved: T[e*132 + col'*4 + comp], comp = wv
        #pragma unroll
        for (int mf = 0; mf < 2; mf++) {
            #pragma unroll
            for (int ee = 0; ee < 4; ee++) {
                int e = ee*16 + m15;
                #pragma unroll
                for (int i = 0; i < 4; i++) {
                    int colp = mf*16 + quad*4 + i;
                    T[e*132 + colp*4 + wv] = f2bf(c3[mf][ee][i]);
                }
            }
        }
        __syncthreads();

        // coalesced store: uint2 per (e, cu); per e-row 256 B contiguous
        #pragma unroll
        for (int it = 0; it < 8; it++) {
            int idx = it * 256 + t;          // 0..2047
            int e  = idx >> 5;
            int cu = idx & 31;
            uint2x v = *(const uint2x*)&T[e*132 + cu*4];
            unsigned short* dstp = w_pk + ((size_t)(eb0 + e) * 128 + p*32 + cu) * 4;
            *(uint2x*)dstp = v;
        }
    }
}

// ---------------- Kernel B2: wave-per-node gather (R5 depth-2, best measured) --
__global__ __launch_bounds__(256) void gather_kernel(
    const int* __restrict__ row_start,
    const int* __restrict__ srcs,
    const float* __restrict__ ea_sorted,
    const unsigned short* __restrict__ w_pk,
    const unsigned short* __restrict__ y_pk,
    float* __restrict__ accS,
    float* __restrict__ accV)
{
    const int t = threadIdx.x;
    const int n = blockIdx.x * 4 + (t >> 6);   // wave-per-node, grid 2500
    const int lane = t & 63;
    const int u0 = lane << 1;                  // u0, u0+1

    const int eb = row_start[n];
    const int ee = row_start[n + 1];

    float aS0a=0.f,aS0b=0.f, aS1a=0.f,aS1b=0.f;
    float aV2ax=0.f,aV2ay=0.f,aV2az=0.f, aV2bx=0.f,aV2by=0.f,aV2bz=0.f;
    float aV3ax=0.f,aV3ay=0.f,aV3az=0.f, aV3bx=0.f,aV3by=0.f,aV3bz=0.f;

    auto consume = [&](const S8& w8, const S8& y8, const float4& ea) {
        // u0 slot
        {
            float wss = bf2f(w8.u[0]), wsv = bf2f(w8.u[1]);
            float wvs = bf2f(w8.u[2]), wvv = bf2f(w8.u[3]);
            float qs = bf2f(y8.u[0]), q0 = bf2f(y8.u[1]), q1 = bf2f(y8.u[2]), q2 = bf2f(y8.u[3]);
            aS0a += wss * qs * ea.x;
            aS1a += wvv * (q0*ea.y + q1*ea.z + q2*ea.w);
            float tsv = wsv * qs;
            aV2ax += tsv * ea.y; aV2ay += tsv * ea.z; aV2az += tsv * ea.w;
            float tvs = wvs * ea.x;
            aV3ax += tvs * q0; aV3ay += tvs * q1; aV3az += tvs * q2;
        }
        // u0+1 slot
        {
            float wss = bf2f(w8.u[4]), wsv = bf2f(w8.u[5]);
            float wvs = bf2f(w8.u[6]), wvv = bf2f(w8.u[7]);
            float qs = bf2f(y8.u[4]), q0 = bf2f(y8.u[5]), q1 = bf2f(y8.u[6]), q2 = bf2f(y8.u[7]);
            aS0b += wss * qs * ea.x;
            aS1b += wvv * (q0*ea.y + q1*ea.z + q2*ea.w);
            float tsv = wsv * qs;
            aV2bx += tsv * ea.y; aV2by += tsv * ea.z; aV2bz += tsv * ea.w;
            float tvs = wvs * ea.x;
            aV3bx += tvs * q0; aV3by += tvs * q1; aV3bz += tvs * q2;
        }
    };

    if (eb < ee) {
        const int lastE = ee - 1;
        int j1 = (eb+1 < lastE) ? eb+1 : lastE;
        int sA = srcs[eb];
        int sB = srcs[j1];
        int sP0 = srcs[(eb+2 < lastE) ? eb+2 : lastE];
        int sP1 = srcs[(eb+3 < lastE) ? eb+3 : lastE];

        S8 wA, wB, yA, yB; float4 eaA, eaB;
        wA.qx = __builtin_nontemporal_load((const uint4x*)(w_pk + ((size_t)eb * 128 + u0) * 4));
        eaA   = *(const float4*)(ea_sorted + (size_t)eb * 4);
        yA.q  = *(const uint4*)(y_pk + ((size_t)sA * 128 + u0) * 4);
        wB.qx = __builtin_nontemporal_load((const uint4x*)(w_pk + ((size_t)j1 * 128 + u0) * 4));
        eaB   = *(const float4*)(ea_sorted + (size_t)j1 * 4);
        yB.q  = *(const uint4*)(y_pk + ((size_t)sB * 128 + u0) * 4);

        for (int i = eb; i < ee; i += 2) {
            // ---- consume A (edge i, always valid) ----
            consume(wA, yA, eaA);
            // ---- refill A <- edge i+2 (clamped within node; never consumed if invalid) ----
            {
                int jn = (i+2 < lastE) ? i+2 : lastE;
                wA.qx = __builtin_nontemporal_load((const uint4x*)(w_pk + ((size_t)jn * 128 + u0) * 4));
                eaA   = *(const float4*)(ea_sorted + (size_t)jn * 4);
                yA.q  = *(const uint4*)(y_pk + ((size_t)sP0 * 128 + u0) * 4);
                sP0 = srcs[(i+4 < lastE) ? i+4 : lastE];
            }
            // ---- consume B (edge i+1; wave-uniform guard) ----
            if (i + 1 < ee) consume(wB, yB, eaB);
            // ---- refill B <- edge i+3 (clamped) ----
            {
                int jn = (i+3 < lastE) ? i+3 : lastE;
                wB.qx = __builtin_nontemporal_load((const uint4x*)(w_pk + ((size_t)jn * 128 + u0) * 4));
                eaB   = *(const float4*)(ea_sorted + (size_t)jn * 4);
                yB.q  = *(const uint4*)(y_pk + ((size_t)sP1 * 128 + u0) * 4);
                sP1 = srcs[(i+5 < lastE) ? i+5 : lastE];
            }
        }
    }

    const float inv = 0.25f;                   // 1/sqrt(16)
    const float s1c = 0.57735026919f * 0.25f;
    *(float2*)(accS + (size_t)n*256 + u0)        = make_float2(aS0a*inv, aS0b*inv);
    *(float2*)(accS + (size_t)n*256 + 128 + u0)  = make_float2(aS1a*s1c, aS1b*s1c);
    *(float2*)(accV + ((size_t)n*3+0)*256 + u0)       = make_float2(aV2ax*inv, aV2bx*inv);
    *(float2*)(accV + ((size_t)n*3+0)*256 + 128 + u0) = make_float2(aV3ax*inv, aV3bx*inv);
    *(float2*)(accV + ((size_t)n*3+1)*256 + u0)       = make_float2(aV2ay*inv, aV2by*inv);
    *(float2*)(accV + ((size_t)n*3+1)*256 + 128 + u0) = make_float2(aV3ay*inv, aV3by*inv);
    *(float2*)(accV + ((size_t)n*3+2)*256 + u0)       = make_float2(aV2az*inv, aV2bz*inv);
    *(float2*)(accV + ((size_t)n*3+2)*256 + 128 + u0) = make_float2(aV3az*inv, aV3bz*inv);
}

// ---------------- node_out as MFMA GEMM, latency-pipelined ----------------
__global__ __launch_bounds__(256) void node_out_mfma(
    const float* __restrict__ node_feats,
    const float* __restrict__ node_attrs,
    const unsigned short* __restrict__ xvP16,
    const float* __restrict__ accS,
    const float* __restrict__ accV,
    const unsigned short* __restrict__ b_pre,
    float* __restrict__ out)
{
    __shared__ __align__(16) short8x Abuf[2][256];   // 2 x 4 KB double buffer
    const int bid = blockIdx.x;
    const int t = threadIdx.x;
    const int lane = t & 63;
    const int wv = t >> 6;
    const bool is_s = (bid < SO_BLK);

    // this thread's A slot: row r (0..63), k-quad (0..3); slot index == t
    const int r    = ((t >> 6) << 4) + (t & 15);
    const int q8   = ((t >> 4) & 3) * 8;

    const float* px = nullptr;
    const unsigned short* pxv = nullptr;
    const float* pa;
    const float* pat;
    if (is_s) {
        int R = bid * 64 + r;
        int node = (R < N_NODES) ? R : 0;
        px  = node_feats + (size_t)node * 512;
        pa  = accS + (size_t)node * 256;
        pat = node_attrs + node * 10;
    } else {
        int Rg = (bid - SO_BLK) * 64 + r;
        if (Rg >= 3 * N_NODES) Rg = 0;
        int node = Rg / 3;
        pxv = xvP16 + (size_t)Rg * 128;
        pa  = accV + (size_t)Rg * 256;
        pat = node_attrs + node * 10;
    }

    const uint4* bb = (const uint4*)(b_pre) + (is_s ? 0 : 24576);
    const float sc_norm = 0.02795084972f;   // 1/sqrt(1280)
    const float l2 = 0.0625f;               // 1/sqrt(256)

    // ---- preload the 4 sc-part A chunks for this (row, quad) ----
    float xf[4][8];
    S8    xh[4];
    if (is_s) {
        #pragma unroll
        for (int c = 0; c < 4; c++) {
            floatx4 lo = *(const floatx4*)&px[c*32 + q8];
            floatx4 hi = *(const floatx4*)&px[c*32 + q8 + 4];
            #pragma unroll
            for (int i = 0; i < 4; i++) { xf[c][i] = lo[i]; xf[c][4+i] = hi[i]; }
        }
    } else {
        #pragma unroll
        for (int c = 0; c < 4; c++)
            xh[c].q = *(const uint4*)&pxv[c*32 + q8];
    }
    float attC = pat[0] * sc_norm;

    floatx4 acc[4][2];
    #pragma unroll
    for (int af = 0; af < 4; af++) {
        acc[af][0] = (floatx4){0.f, 0.f, 0.f, 0.f};
        acc[af][1] = (floatx4){0.f, 0.f, 0.f, 0.f};
    }

    const int cof0 = (wv*2+0)*64 + lane;
    const int cof1 = (wv*2+1)*64 + lane;

    auto packx = [&](int c_, float att_) -> short8x {
        S8 pk;
        if (is_s) {
            #pragma unroll
            for (int i = 0; i < 8; i++) pk.u[i] = f2bf(xf[c_][i] * att_);
        } else {
            #pragma unroll
            for (int i = 0; i < 8; i++) pk.u[i] = f2bf(bf2f(xh[c_].u[i]) * att_);
        }
        return pk.v;
    };
    auto mstep = [&](int kb, const S8& b0, const S8& b1) {
        __builtin_amdgcn_s_setprio(1);
        #pragma unroll
        for (int af = 0; af < 4; af++) {
            short8x a = Abuf[kb][af*64 + lane];
            acc[af][0] = __builtin_amdgcn_mfma_f32_16x16x32_bf16(a, b0.v, acc[af][0], 0, 0, 0);
            acc[af][1] = __builtin_amdgcn_mfma_f32_16x16x32_bf16(a, b1.v, acc[af][1], 0, 0, 0);
        }
        __builtin_amdgcn_s_setprio(0);
    };
    auto bload = [&](int k2, S8& b0, S8& b1) {
        b0.q = bb[(size_t)k2*512 + cof0];
        b1.q = bb[(size_t)k2*512 + cof1];
    };
    auto barrier_ = [&]() {
        asm volatile("s_waitcnt lgkmcnt(0)" ::: "memory");
        __builtin_amdgcn_s_barrier();
    };

    // B prefetch (depth 2)
    S8 bA0, bA1, bB0, bB1;
    bload(0, bA0, bA1);
    bload(1, bB0, bB1);

    // prologue: A(0) -> buf0
    Abuf[0][t] = packx(0, attC);
    barrier_();

    // ---- main loop: ks = 0..35 (vblk 0..8), A from preloaded chunks ----
    #pragma unroll 1
    for (int vb = 0; vb < 9; vb++) {
        float attN = pat[vb + 1] * sc_norm;
        const int ksb = vb * 4;
        Abuf[1][t] = packx(1, attC); mstep(0, bA0, bA1); bload(ksb+2, bA0, bA1); barrier_();
        Abuf[0][t] = packx(2, attC); mstep(1, bB0, bB1); bload(ksb+3, bB0, bB1); barrier_();
        Abuf[1][t] = packx(3, attC); mstep(0, bA0, bA1); bload(ksb+4, bA0, bA1); barrier_();
        Abuf[0][t] = packx(0, attN); mstep(1, bB0, bB1); bload(ksb+5, bB0, bB1); barrier_();
        attC = attN;
    }

    // ---- ks = 36..47 explicit (attC == pat[9]); tail A from acc (depth-2) ----
    floatx4 aT0[2], aT1[2];
    auto issue0 = [&](int k_) { int j2 = (k_-40)*32 + q8;
        aT0[0] = *(const floatx4*)&pa[j2]; aT0[1] = *(const floatx4*)&pa[j2+4]; };
    auto issue1 = [&](int k_) { int j2 = (k_-40)*32 + q8;
        aT1[0] = *(const floatx4*)&pa[j2]; aT1[1] = *(const floatx4*)&pa[j2+4]; };
    auto packT = [&](const floatx4* a2) -> short8x {
        S8 pk;
        #pragma unroll
        for (int i = 0; i < 4; i++) { pk.u[i] = f2bf(a2[0][i] * l2); pk.u[4+i] = f2bf(a2[1][i] * l2); }
        return pk.v;
    };

    // ks=36
    Abuf[1][t] = packx(1, attC); mstep(0, bA0, bA1); bload(38, bA0, bA1); barrier_();
    // ks=37
    Abuf[0][t] = packx(2, attC); mstep(1, bB0, bB1); bload(39, bB0, bB1); barrier_();
    // ks=38
    issue0(40);
    Abuf[1][t] = packx(3, attC); mstep(0, bA0, bA1); bload(40, bA0, bA1); barrier_();
    // ks=39
    issue1(41);
    Abuf[0][t] = packT(aT0); mstep(1, bB0, bB1); bload(41, bB0, bB1); barrier_();
    // ks=40
    issue0(42);
    Abuf[1][t] = packT(aT1); mstep(0, bA0, bA1); bload(42, bA0, bA1); barrier_();
    // ks=41
    issue1(43);
    Abuf[0][t] = packT(aT0); mstep(1, bB0, bB1); bload(43, bB0, bB1); barrier_();
    // ks=42
    issue0(44);
    Abuf[1][t] = packT(aT1); mstep(0, bA0, bA1); bload(44, bA0, bA1); barrier_();
    // ks=43
    issue1(45);
    Abuf[0][t] = packT(aT0); mstep(1, bB0, bB1); bload(45, bB0, bB1); barrier_();
    // ks=44
    issue0(46);
    Abuf[1][t] = packT(aT1); mstep(0, bA0, bA1); bload(46, bA0, bA1); barrier_();
    // ks=45
    issue1(47);
    Abuf[0][t] = packT(aT0); mstep(1, bB0, bB1); bload(47, bB0, bB1); barrier_();
    // ks=46
    Abuf[1][t] = packT(aT1); mstep(0, bA0, bA1); barrier_();
    // ks=47
    mstep(1, bB0, bB1);

    // ---- epilogue ----
    const int m = lane & 15;
    const int rq = (lane >> 4) * 4;
    if (is_s) {
        const int n0 = bid * 64;
        #pragma unroll
        for (int af = 0; af < 4; af++) {
            #pragma unroll
            for (int i = 0; i < 4; i++) {
                int n = n0 + af*16 + rq + i;
                if (n < N_NODES) {
                    out[(size_t)n*512 + wv*32 + m]      = acc[af][0][i];
                    out[(size_t)n*512 + wv*32 + 16 + m] = acc[af][1][i];
                }
            }
        }
    } else {
        const int r0 = (bid - SO_BLK) * 64;
        #pragma unroll
        for (int af = 0; af < 4; af++) {
            #pragma unroll
            for (int i = 0; i < 4; i++) {
                int Rg = r0 + af*16 + rq + i;
                if (Rg < 3 * N_NODES) {
                    int nn = Rg / 3;
                    int cc = Rg - nn * 3;
                    float* po = out + (size_t)nn*512 + 128 + cc;
                    po[(wv*32 + m)*3]      = acc[af][0][i];
                    po[(wv*32 + 16 + m)*3] = acc[af][1][i];
                }
            }
        }
    }
}

extern "C" void kernel_launch(void* const* d_in, const int* in_sizes, int n_in,
                              void* d_out, int out_size, void* d_ws, size_t ws_size,
                              hipStream_t stream) {
    const float* node_feats = (const float*)d_in[0];
    const float* node_attrs = (const float*)d_in[1];
    const float* edge_feats = (const float*)d_in[2];
    const float* edge_attrs = (const float*)d_in[3];
    const int*   edge_index = (const int*)  d_in[4];
    const float* lin1_ws    = (const float*)d_in[5];
    const float* lin1_wv    = (const float*)d_in[6];
    const float* fc_w0      = (const float*)d_in[7];
    const float* fc_w1      = (const float*)d_in[8];
    const float* fc_w2      = (const float*)d_in[9];
    const float* lin2_ws    = (const float*)d_in[10];
    const float* lin2_wv    = (const float*)d_in[11];
    const float* sc_ws      = (const float*)d_in[12];
    const float* sc_wv      = (const float*)d_in[13];
    float* out = (float*)d_out;

    // workspace layout
    unsigned short* y_pk  = (unsigned short*)d_ws;            // 5,120,000 us
    float* accS = (float*)(y_pk + (size_t)5120000);           // 2,560,000 f32
    float* accV = accS + (size_t)2560000;                     // 7,680,000 f32
    unsigned short* xvP16 = (unsigned short*)(accV + (size_t)7680000);  // 3,840,000 us
    unsigned short* w_pk  = xvP16 + (size_t)3840000;          // 81,920,000 us
    int* deg       = (int*)(w_pk + (size_t)81920000);
    int* row_start = deg + 10016;
    int* cursor    = row_start + 10016;
    int* edge_list = cursor + 10016;
    int* srcs      = edge_list + N_EDGES;
    float* ea_sorted = (float*)(srcs + N_EDGES);
    unsigned short* b_pre = (unsigned short*)(ea_sorted + (size_t)N_EDGES * 4);
    unsigned short* w2a   = b_pre + (size_t)2 * 24576 * 8;
    unsigned short* w1a   = w2a + (size_t)4096 * 8;
    unsigned short* b_lin = w1a + (size_t)512 * 8;
    const size_t need = (size_t)5120000 * 2 + (size_t)(2560000 + 7680000) * 4
                      + (size_t)3840000 * 2 + (size_t)81920000 * 2
                      + (size_t)(10016 * 3 + N_EDGES * 2) * 4
                      + (size_t)N_EDGES * 4 * 4
                      + ((size_t)2 * 24576 * 8 + (size_t)4096 * 8 + (size_t)512 * 8
                         + (size_t)4096 * 8) * 2;
    if (ws_size < need) return;

    hipLaunchKernelGGL(pack_all_kernel, dim3(226), dim3(256), 0, stream,
                       sc_ws, lin2_ws, sc_wv, lin2_wv, fc_w2, fc_w1, lin1_ws, lin1_wv,
                       b_pre, w2a, w1a, b_lin);
    hipLaunchKernelGGL(node_lin1_mfma, dim3(625), dim3(256), 0, stream,
                       node_feats, b_lin, y_pk, xvP16);

    hipMemsetAsync(deg, 0, (size_t)N_NODES * sizeof(int), stream);
    hipLaunchKernelGGL(hist_kernel, dim3(625), dim3(256), 0, stream, edge_index, deg);
    hipLaunchKernelGGL(scan_kernel, dim3(1), dim3(1024), 0, stream, deg, row_start, cursor);
    hipLaunchKernelGGL(scatter_kernel, dim3(625), dim3(256), 0, stream,
                       edge_index, edge_attrs, cursor, edge_list, srcs, ea_sorted);
    hipLaunchKernelGGL(edge_w_mfma, dim3(2500), dim3(256), 0, stream,
                       edge_feats, edge_list, fc_w0, w1a, w2a, w_pk);
    hipLaunchKernelGGL(gather_kernel, dim3(2500), dim3(256), 0, stream,
                       row_start, srcs, ea_sorted, w_pk, y_pk, accS, accV);

    hipLaunchKernelGGL(node_out_mfma, dim3(SO_BLK + VO_BLK), dim3(256), 0, stream,
                       node_feats, node_attrs, xvP16, accS, accV, b_pre, out);
}

// Round 14
// 280.252 us; speedup vs baseline: 1.9133x; 1.0034x over previous
//
#include <hip/hip_runtime.h>
#include <hip/hip_bf16.h>
#include <math.h>

#define N_NODES 10000
#define N_EDGES 160000
#define SO_BLK 157          // ceil(10000/64) s-GEMM blocks
#define VO_BLK 469          // ceil(30000/64) v-GEMM blocks

typedef __attribute__((ext_vector_type(8))) short short8x;
typedef __attribute__((ext_vector_type(4))) float floatx4;
typedef __attribute__((ext_vector_type(4))) unsigned int uint4x;
typedef __attribute__((ext_vector_type(2))) unsigned int uint2x;

union S8 { short8x v; unsigned short u[8]; uint4 q; uint4x qx; };
union U2 { uint2x v; unsigned short us[4]; };

__device__ __forceinline__ unsigned short f2bf(float x) {
    unsigned int u = __float_as_uint(x);
    return (unsigned short)((u + 0x7fffu + ((u >> 16) & 1u)) >> 16);
}
__device__ __forceinline__ float bf2f(unsigned short u) {
    return __uint_as_float(((unsigned)u) << 16);
}
__device__ __forceinline__ float silu_c(float x) {
    return 1.679f * x / (1.0f + __expf(-x));
}

// ---------------- pack_all: all weight pre-packs in one launch ----------------
// blocks [0,192): b_pre; [192,208): w2a; [208,210): w1a; [210,226): b_lin
__global__ __launch_bounds__(256) void pack_all_kernel(
    const float* __restrict__ sc_ws, const float* __restrict__ lin2_ws,
    const float* __restrict__ sc_wv, const float* __restrict__ lin2_wv,
    const float* __restrict__ fc_w2, const float* __restrict__ fc_w1,
    const float* __restrict__ lin1_ws, const float* __restrict__ lin1_wv,
    unsigned short* __restrict__ b_pre, unsigned short* __restrict__ w2a,
    unsigned short* __restrict__ w1a, unsigned short* __restrict__ b_lin)
{
    const int bid = blockIdx.x;
    const int t = threadIdx.x;
    if (bid < 192) {
        int id = bid * 256 + t;                  // 0..49151
        int mat = id / 24576;
        int slot = id - mat * 24576;
        int ks = slot >> 9;
        int rr = slot & 511;
        int lane = rr & 63;
        int quad = lane >> 4;
        int n = ((rr >> 6) << 4) + (lane & 15);
        const float* sc  = mat ? sc_wv  : sc_ws;
        const float* lin = mat ? lin2_wv : lin2_ws;
        S8 pk;
        #pragma unroll
        for (int j = 0; j < 8; j++) {
            int k = ks * 32 + quad * 8 + j;
            float w;
            if (k < 1280) {
                int u = k & 127, v = k >> 7;
                w = sc[(u * 10 + v) * 128 + n];
            } else {
                w = lin[(k - 1280) * 128 + n];
            }
            pk.u[j] = f2bf(w);
        }
        *(uint4*)(b_pre + (size_t)id * 8) = pk.q;
    } else if (bid < 208) {
        int id = (bid - 192) * 256 + t;          // 0..4095
        int lane = id & 63;
        int mfg = (id >> 6) & 31;
        int ks = id >> 11;
        int col = mfg * 16 + (lane & 15);
        int k0 = ks * 32 + (lane >> 4) * 8;
        S8 pk;
        #pragma unroll
        for (int j = 0; j < 8; j++)
            pk.u[j] = f2bf(fc_w2[(k0 + j) * 512 + col] * 0.125f);
        *(uint4*)(w2a + (size_t)id * 8) = pk.q;
    } else if (bid < 210) {
        int id = (bid - 208) * 256 + t;          // 0..511
        int lane = id & 63;
        int mf = (id >> 6) & 3;
        int ks = id >> 8;
        int m = mf * 16 + (lane & 15);
        int k0 = ks * 32 + (lane >> 4) * 8;
        S8 pk;
        #pragma unroll
        for (int j = 0; j < 8; j++)
            pk.u[j] = f2bf(fc_w1[(k0 + j) * 64 + m] * 0.125f);
        *(uint4*)(w1a + (size_t)id * 8) = pk.q;
    } else {
        int id = (bid - 210) * 256 + t;          // 0..4095
        int mat = id >> 11;
        int slot = id & 2047;
        int ks = slot >> 9;
        int rr = slot & 511;
        int nf = rr >> 6;
        int lane = rr & 63;
        int n = nf * 16 + (lane & 15);
        int k0 = ks * 32 + (lane >> 4) * 8;
        const float* w = mat ? lin1_wv : lin1_ws;
        const float l1 = 0.0883883476483f;
        S8 pk;
        #pragma unroll
        for (int j = 0; j < 8; j++)
            pk.u[j] = f2bf(w[(k0 + j) * 128 + n] * l1);
        *(uint4*)(b_lin + (size_t)id * 8) = pk.q;
    }
}

// ---------------- Kernel A: lin1 via MFMA -> packed bf16 y + bf16 xvP ----------------
// 16 nodes/block (M=64 rows: comp = af), grid 625 = 2.4 blocks/CU, LDS 16 KB.
__global__ __launch_bounds__(256) void node_lin1_mfma(
    const float* __restrict__ node_feats,
    const unsigned short* __restrict__ b_lin,
    unsigned short* __restrict__ y_pk,
    unsigned short* __restrict__ xvP16)
{
    __shared__ __align__(16) unsigned char smem[16384];
    short8x* Al = (short8x*)smem;
    unsigned short* Yt = (unsigned short*)smem;

    const int blk = blockIdx.x;   // 625
    const int t = threadIdx.x;
    const int base = blk * 16;
    const int lane = t & 63;
    const int wv = t >> 6;
    const int m15 = lane & 15;
    const int k0q = (lane >> 4) * 8;

    #pragma unroll
    for (int it = 0; it < 4; it++) {
        int g = wv * 4 + it;          // 0..15
        int af = g >> 2;              // 0..3  (== comp)
        int ks = g & 3;               // 0..3
        int node = base + m15;
        int valid = (node < N_NODES);
        if (!valid) node = N_NODES - 1;
        int k0 = ks * 32 + k0q;
        const float* row = node_feats + (size_t)node * 512;
        S8 pk;
        if (af == 0) {
            float4 a = *(const float4*)&row[k0];
            float4 b = *(const float4*)&row[k0 + 4];
            pk.u[0] = f2bf(a.x); pk.u[1] = f2bf(a.y); pk.u[2] = f2bf(a.z); pk.u[3] = f2bf(a.w);
            pk.u[4] = f2bf(b.x); pk.u[5] = f2bf(b.y); pk.u[6] = f2bf(b.z); pk.u[7] = f2bf(b.w);
        } else {
            int c = af - 1;
            #pragma unroll
            for (int j = 0; j < 8; j++)
                pk.u[j] = f2bf(row[128 + (k0 + j) * 3 + c]);
            if (valid)
                *(uint4*)&xvP16[((size_t)node * 3 + c) * 128 + k0] = pk.q;
        }
        Al[(ks * 4 + af) * 64 + lane] = pk.v;
    }
    __syncthreads();

    floatx4 c[4][2];
    #pragma unroll
    for (int af = 0; af < 4; af++) {
        c[af][0] = (floatx4){0.f, 0.f, 0.f, 0.f};
        c[af][1] = (floatx4){0.f, 0.f, 0.f, 0.f};
    }

    const uint4* bq = (const uint4*)b_lin;
    #pragma unroll
    for (int ks = 0; ks < 4; ks++) {
        S8 bs0, bs1, bv0, bv1;
        bs0.q = bq[       ks*512 + (wv*2+0)*64 + lane];
        bs1.q = bq[       ks*512 + (wv*2+1)*64 + lane];
        bv0.q = bq[2048 + ks*512 + (wv*2+0)*64 + lane];
        bv1.q = bq[2048 + ks*512 + (wv*2+1)*64 + lane];
        #pragma unroll
        for (int af = 0; af < 4; af++) {
            short8x a = Al[(ks*4 + af)*64 + lane];
            if (af == 0) {
                c[af][0] = __builtin_amdgcn_mfma_f32_16x16x32_bf16(a, bs0.v, c[af][0], 0, 0, 0);
                c[af][1] = __builtin_amdgcn_mfma_f32_16x16x32_bf16(a, bs1.v, c[af][1], 0, 0, 0);
            } else {
                c[af][0] = __builtin_amdgcn_mfma_f32_16x16x32_bf16(a, bv0.v, c[af][0], 0, 0, 0);
                c[af][1] = __builtin_amdgcn_mfma_f32_16x16x32_bf16(a, bv1.v, c[af][1], 0, 0, 0);
            }
        }
    }
    __syncthreads();

    {
        const int rq = (lane >> 4) * 4;
        #pragma unroll
        for (int af = 0; af < 4; af++) {
            #pragma unroll
            for (int nf = 0; nf < 2; nf++) {
                int u = wv * 32 + nf * 16 + m15;
                #pragma unroll
                for (int i = 0; i < 4; i++) {
                    int nloc = rq + i;           // row m = af*16 + nloc; comp = af
                    Yt[(nloc * 128 + u) * 4 + af] = f2bf(c[af][nf][i]);
                }
            }
        }
    }
    __syncthreads();
    {
        unsigned short* dst = y_pk + (size_t)base * 512;
        int nrem = N_NODES - base;
        #pragma unroll
        for (int it = 0; it < 4; it++) {
            int idx = it * 256 + t;              // 0..1023 (16 nodes x 64 groups)
            if ((idx >> 6) < nrem)
                *(uint4*)(dst + (size_t)idx * 8) = *(const uint4*)&Yt[idx * 8];
        }
    }
}

// ---------------- CSR build ----------------
__global__ __launch_bounds__(256) void hist_kernel(const int* __restrict__ edge_index,
                                                   int* __restrict__ deg) {
    int e = blockIdx.x * 256 + threadIdx.x;
    if (e < N_EDGES) atomicAdd(&deg[edge_index[e]], 1);
}

__global__ __launch_bounds__(1024) void scan_kernel(const int* __restrict__ deg,
                                                    int* __restrict__ row_start,
                                                    int* __restrict__ cursor) {
    __shared__ int wsum[16];
    __shared__ int carry_s;
    const int t = threadIdx.x;
    const int lane = t & 63, w = t >> 6;
    if (t == 0) carry_s = 0;
    __syncthreads();
    for (int chunk = 0; chunk < 10; chunk++) {
        int idx = chunk * 1024 + t;
        int v = (idx < N_NODES) ? deg[idx] : 0;
        int x = v;
        #pragma unroll
        for (int off = 1; off < 64; off <<= 1) {
            int yv = __shfl_up(x, off, 64);
            if (lane >= off) x += yv;
        }
        if (lane == 63) wsum[w] = x;
        __syncthreads();
        int wpre = 0;
        for (int i = 0; i < w; i++) wpre += wsum[i];
        int incl = x + wpre + carry_s;
        int excl = incl - v;
        if (idx < N_NODES) { row_start[idx] = excl; cursor[idx] = excl; }
        __syncthreads();
        if (t == 1023) carry_s = incl;
        __syncthreads();
    }
    if (t == 0) row_start[N_NODES] = carry_s;
}

__global__ __launch_bounds__(256) void scatter_kernel(const int* __restrict__ edge_index,
                                                      const float* __restrict__ edge_attrs,
                                                      int* __restrict__ cursor,
                                                      int* __restrict__ edge_list,
                                                      int* __restrict__ srcs,
                                                      float* __restrict__ ea_sorted) {
    int e = blockIdx.x * 256 + threadIdx.x;
    if (e < N_EDGES) {
        int pos = atomicAdd(&cursor[edge_index[e]], 1);
        edge_list[pos] = e;
        srcs[pos] = edge_index[N_EDGES + e];
        float4 ea = *(const float4*)(edge_attrs + (size_t)e * 4);
        *(float4*)(ea_sorted + (size_t)pos * 4) = ea;
    }
}

// ---------------- Kernel B1: edge MLP (sorted order) -> packed bf16 w ----------------
// w_pk[pos][u][4] = bf16{ss, sv, vs, vv}; normal (MALL-allocating) stores.
// h0b/h1b columns XOR-swizzled (c ^ ((row&7)<<3), 8-ushort granularity) to break
// the 36-word row-stride bank pattern (was ~8-way conflicts on ds_read_b128).
__global__ __launch_bounds__(256) void edge_w_mfma(
    const float* __restrict__ edge_feats,
    const int* __restrict__ edge_list,
    const float* __restrict__ fc_w0,
    const unsigned short* __restrict__ w1a,
    const unsigned short* __restrict__ w2a,
    unsigned short* __restrict__ w_pk)
{
    __shared__ __align__(16) unsigned char smem[26368];
    float* ef = (float*)smem;                               // [0, 2304)
    unsigned short* h0b = (unsigned short*)(smem + 2304);   // [2304, 11520): 64 x 72
    unsigned short* T   = (unsigned short*)smem;            // [0, 16896): 64 x 132 (epilogue)
    unsigned short* h1b = (unsigned short*)(smem + 16896);  // [16896, 26112): 64 x 72
    int* eids = (int*)(smem + 26112);                       // [26112, 26368)

    const int blk = blockIdx.x;      // 2500
    const int t = threadIdx.x;
    const int eb0 = blk * 64;
    const int lane = t & 63;
    const int wv = t >> 6;
    const int quad = lane >> 4;
    const int m15 = lane & 15;

    #define SWZ(row, col) ((col) ^ (((row) & 7) << 3))

    if (t < 64) eids[t] = edge_list[eb0 + t];
    __syncthreads();

    #pragma unroll
    for (int r = 0; r < 2; r++) {
        int idx = r * 256 + t;
        int el = idx >> 3;
        int k = idx & 7;
        ef[el * 9 + k] = edge_feats[(size_t)eids[el] * 8 + k];
    }
    __syncthreads();

    // phase 1 (VALU, f32): h0 = silu_c(ef @ w0 / sqrt(8)) -> bf16
    {
        const int e_loc = t >> 2;
        const int c0 = (t & 3) * 16;
        float a0[16];
        #pragma unroll
        for (int i = 0; i < 16; i++) a0[i] = 0.f;
        const float* efr = &ef[e_loc * 9];
        #pragma unroll
        for (int k = 0; k < 8; k++) {
            float ek = efr[k];
            float w[16];
            #pragma unroll
            for (int q4 = 0; q4 < 4; q4++)
                *(float4*)&w[q4*4] = *(const float4*)&fc_w0[k*64 + c0 + q4*4];
            #pragma unroll
            for (int i = 0; i < 16; i++) a0[i] += ek * w[i];
        }
        const float is8 = 0.35355339059f;
        S8 p0, p1;
        #pragma unroll
        for (int i = 0; i < 8; i++) {
            p0.u[i] = f2bf(silu_c(a0[i] * is8));
            p1.u[i] = f2bf(silu_c(a0[8 + i] * is8));
        }
        *(uint4*)&h0b[e_loc * 72 + SWZ(e_loc, c0)]     = p0.q;
        *(uint4*)&h0b[e_loc * 72 + SWZ(e_loc, c0 + 8)] = p1.q;
    }
    __syncthreads();

    // phase 2 (MFMA): h1 = silu_c(h0 @ w1 / 8)
    {
        floatx4 c2[4];
        #pragma unroll
        for (int ee = 0; ee < 4; ee++) c2[ee] = (floatx4){0.f, 0.f, 0.f, 0.f};
        const uint4* w1aq = (const uint4*)w1a;
        #pragma unroll
        for (int ks = 0; ks < 2; ks++) {
            S8 afr;
            afr.q = w1aq[(ks*4 + wv)*64 + lane];
            #pragma unroll
            for (int ee = 0; ee < 4; ee++) {
                S8 bfr;
                int rw = ee*16 + m15;
                bfr.q = *(const uint4*)&h0b[rw * 72 + SWZ(rw, ks*32 + quad*8)];
                c2[ee] = __builtin_amdgcn_mfma_f32_16x16x32_bf16(afr.v, bfr.v, c2[ee], 0, 0, 0);
            }
        }
        #pragma unroll
        for (int ee = 0; ee < 4; ee++) {
            ushort4 pk = make_ushort4(f2bf(silu_c(c2[ee][0])), f2bf(silu_c(c2[ee][1])),
                                      f2bf(silu_c(c2[ee][2])), f2bf(silu_c(c2[ee][3])));
            int rw = ee*16 + m15;
            *(ushort4*)&h1b[rw * 72 + SWZ(rw, wv*16 + quad*4)] = pk;
        }
    }
    __syncthreads();

    // phase 3 (MFMA, 4 passes of 2 m-frags); pass p covers cols p*32..p*32+31 of comp wv
    const uint4* w2aq = (const uint4*)w2a;
    #pragma unroll 1
    for (int p = 0; p < 4; p++) {
        floatx4 c3[2][4];
        #pragma unroll
        for (int mf = 0; mf < 2; mf++)
            #pragma unroll
            for (int ee = 0; ee < 4; ee++)
                c3[mf][ee] = (floatx4){0.f, 0.f, 0.f, 0.f};

        #pragma unroll
        for (int ks = 0; ks < 2; ks++) {
            S8 bfr[4];
            #pragma unroll
            for (int ee = 0; ee < 4; ee++) {
                int rw = ee*16 + m15;
                bfr[ee].q = *(const uint4*)&h1b[rw * 72 + SWZ(rw, ks*32 + quad*8)];
            }
            #pragma unroll
            for (int mf = 0; mf < 2; mf++) {
                S8 afr;
                afr.q = w2aq[(size_t)(ks*32 + wv*8 + p*2 + mf) * 64 + lane];
                #pragma unroll
                for (int ee = 0; ee < 4; ee++)
                    c3[mf][ee] = __builtin_amdgcn_mfma_f32_16x16x32_bf16(afr.v, bfr[ee].v, c3[mf][ee], 0, 0, 0);
            }
        }

        __syncthreads();   // T region free (prev pass stores done / ef+h0b dead)
        // dump interleaved: T[e*132 + col'*4 + comp], comp = wv
        #pragma unroll
        for (int mf = 0; mf < 2; mf++) {
            #pragma unroll
            for (int ee = 0; ee < 4; ee++) {
                int e = ee*16 + m15;
                #pragma unroll
                for (int i = 0; i < 4; i++) {
                    int colp = mf*16 + quad*4 + i;
                    T[e*132 + colp*4 + wv] = f2bf(c3[mf][ee][i]);
                }
            }
        }
        __syncthreads();

        // coalesced store: uint2 per (e, cu); per e-row 256 B contiguous
        #pragma unroll
        for (int it = 0; it < 8; it++) {
            int idx = it * 256 + t;          // 0..2047
            int e  = idx >> 5;
            int cu = idx & 31;
            uint2x v = *(const uint2x*)&T[e*132 + cu*4];
            unsigned short* dstp = w_pk + ((size_t)(eb0 + e) * 128 + p*32 + cu) * 4;
            *(uint2x*)dstp = v;
        }
    }
    #undef SWZ
}

// ---------------- Kernel B2: wave-per-node gather (R5 depth-2, best measured) --
__global__ __launch_bounds__(256) void gather_kernel(
    const int* __restrict__ row_start,
    const int* __restrict__ srcs,
    const float* __restrict__ ea_sorted,
    const unsigned short* __restrict__ w_pk,
    const unsigned short* __restrict__ y_pk,
    float* __restrict__ accS,
    float* __restrict__ accV)
{
    const int t = threadIdx.x;
    const int n = blockIdx.x * 4 + (t >> 6);   // wave-per-node, grid 2500
    const int lane = t & 63;
    const int u0 = lane << 1;                  // u0, u0+1

    const int eb = row_start[n];
    const int ee = row_start[n + 1];

    float aS0a=0.f,aS0b=0.f, aS1a=0.f,aS1b=0.f;
    float aV2ax=0.f,aV2ay=0.f,aV2az=0.f, aV2bx=0.f,aV2by=0.f,aV2bz=0.f;
    float aV3ax=0.f,aV3ay=0.f,aV3az=0.f, aV3bx=0.f,aV3by=0.f,aV3bz=0.f;

    auto consume = [&](const S8& w8, const S8& y8, const float4& ea) {
        // u0 slot
        {
            float wss = bf2f(w8.u[0]), wsv = bf2f(w8.u[1]);
            float wvs = bf2f(w8.u[2]), wvv = bf2f(w8.u[3]);
            float qs = bf2f(y8.u[0]), q0 = bf2f(y8.u[1]), q1 = bf2f(y8.u[2]), q2 = bf2f(y8.u[3]);
            aS0a += wss * qs * ea.x;
            aS1a += wvv * (q0*ea.y + q1*ea.z + q2*ea.w);
            float tsv = wsv * qs;
            aV2ax += tsv * ea.y; aV2ay += tsv * ea.z; aV2az += tsv * ea.w;
            float tvs = wvs * ea.x;
            aV3ax += tvs * q0; aV3ay += tvs * q1; aV3az += tvs * q2;
        }
        // u0+1 slot
        {
            float wss = bf2f(w8.u[4]), wsv = bf2f(w8.u[5]);
            float wvs = bf2f(w8.u[6]), wvv = bf2f(w8.u[7]);
            float qs = bf2f(y8.u[4]), q0 = bf2f(y8.u[5]), q1 = bf2f(y8.u[6]), q2 = bf2f(y8.u[7]);
            aS0b += wss * qs * ea.x;
            aS1b += wvv * (q0*ea.y + q1*ea.z + q2*ea.w);
            float tsv = wsv * qs;
            aV2bx += tsv * ea.y; aV2by += tsv * ea.z; aV2bz += tsv * ea.w;
            float tvs = wvs * ea.x;
            aV3bx += tvs * q0; aV3by += tvs * q1; aV3bz += tvs * q2;
        }
    };

    if (eb < ee) {
        const int lastE = ee - 1;
        int j1 = (eb+1 < lastE) ? eb+1 : lastE;
        int sA = srcs[eb];
        int sB = srcs[j1];
        int sP0 = srcs[(eb+2 < lastE) ? eb+2 : lastE];
        int sP1 = srcs[(eb+3 < lastE) ? eb+3 : lastE];

        S8 wA, wB, yA, yB; float4 eaA, eaB;
        wA.qx = __builtin_nontemporal_load((const uint4x*)(w_pk + ((size_t)eb * 128 + u0) * 4));
        eaA   = *(const float4*)(ea_sorted + (size_t)eb * 4);
        yA.q  = *(const uint4*)(y_pk + ((size_t)sA * 128 + u0) * 4);
        wB.qx = __builtin_nontemporal_load((const uint4x*)(w_pk + ((size_t)j1 * 128 + u0) * 4));
        eaB   = *(const float4*)(ea_sorted + (size_t)j1 * 4);
        yB.q  = *(const uint4*)(y_pk + ((size_t)sB * 128 + u0) * 4);

        for (int i = eb; i < ee; i += 2) {
            // ---- consume A (edge i, always valid) ----
            consume(wA, yA, eaA);
            // ---- refill A <- edge i+2 (clamped within node; never consumed if invalid) ----
            {
                int jn = (i+2 < lastE) ? i+2 : lastE;
                wA.qx = __builtin_nontemporal_load((const uint4x*)(w_pk + ((size_t)jn * 128 + u0) * 4));
                eaA   = *(const float4*)(ea_sorted + (size_t)jn * 4);
                yA.q  = *(const uint4*)(y_pk + ((size_t)sP0 * 128 + u0) * 4);
                sP0 = srcs[(i+4 < lastE) ? i+4 : lastE];
            }
            // ---- consume B (edge i+1; wave-uniform guard) ----
            if (i + 1 < ee) consume(wB, yB, eaB);
            // ---- refill B <- edge i+3 (clamped) ----
            {
                int jn = (i+3 < lastE) ? i+3 : lastE;
                wB.qx = __builtin_nontemporal_load((const uint4x*)(w_pk + ((size_t)jn * 128 + u0) * 4));
                eaB   = *(const float4*)(ea_sorted + (size_t)jn * 4);
                yB.q  = *(const uint4*)(y_pk + ((size_t)sP1 * 128 + u0) * 4);
                sP1 = srcs[(i+5 < lastE) ? i+5 : lastE];
            }
        }
    }

    const float inv = 0.25f;                   // 1/sqrt(16)
    const float s1c = 0.57735026919f * 0.25f;
    *(float2*)(accS + (size_t)n*256 + u0)        = make_float2(aS0a*inv, aS0b*inv);
    *(float2*)(accS + (size_t)n*256 + 128 + u0)  = make_float2(aS1a*s1c, aS1b*s1c);
    *(float2*)(accV + ((size_t)n*3+0)*256 + u0)       = make_float2(aV2ax*inv, aV2bx*inv);
    *(float2*)(accV + ((size_t)n*3+0)*256 + 128 + u0) = make_float2(aV3ax*inv, aV3bx*inv);
    *(float2*)(accV + ((size_t)n*3+1)*256 + u0)       = make_float2(aV2ay*inv, aV2by*inv);
    *(float2*)(accV + ((size_t)n*3+1)*256 + 128 + u0) = make_float2(aV3ay*inv, aV3by*inv);
    *(float2*)(accV + ((size_t)n*3+2)*256 + u0)       = make_float2(aV2az*inv, aV2bz*inv);
    *(float2*)(accV + ((size_t)n*3+2)*256 + 128 + u0) = make_float2(aV3az*inv, aV3bz*inv);
}

// ---------------- node_out as MFMA GEMM, latency-pipelined ----------------
__global__ __launch_bounds__(256) void node_out_mfma(
    const float* __restrict__ node_feats,
    const float* __restrict__ node_attrs,
    const unsigned short* __restrict__ xvP16,
    const float* __restrict__ accS,
    const float* __restrict__ accV,
    const unsigned short* __restrict__ b_pre,
    float* __restrict__ out)
{
    __shared__ __align__(16) short8x Abuf[2][256];   // 2 x 4 KB double buffer
    const int bid = blockIdx.x;
    const int t = threadIdx.x;
    const int lane = t & 63;
    const int wv = t >> 6;
    const bool is_s = (bid < SO_BLK);

    // this thread's A slot: row r (0..63), k-quad (0..3); slot index == t
    const int r    = ((t >> 6) << 4) + (t & 15);
    const int q8   = ((t >> 4) & 3) * 8;

    const float* px = nullptr;
    const unsigned short* pxv = nullptr;
    const float* pa;
    const float* pat;
    if (is_s) {
        int R = bid * 64 + r;
        int node = (R < N_NODES) ? R : 0;
        px  = node_feats + (size_t)node * 512;
        pa  = accS + (size_t)node * 256;
        pat = node_attrs + node * 10;
    } else {
        int Rg = (bid - SO_BLK) * 64 + r;
        if (Rg >= 3 * N_NODES) Rg = 0;
        int node = Rg / 3;
        pxv = xvP16 + (size_t)Rg * 128;
        pa  = accV + (size_t)Rg * 256;
        pat = node_attrs + node * 10;
    }

    const uint4* bb = (const uint4*)(b_pre) + (is_s ? 0 : 24576);
    const float sc_norm = 0.02795084972f;   // 1/sqrt(1280)
    const float l2 = 0.0625f;               // 1/sqrt(256)

    // ---- preload the 4 sc-part A chunks for this (row, quad) ----
    float xf[4][8];
    S8    xh[4];
    if (is_s) {
        #pragma unroll
        for (int c = 0; c < 4; c++) {
            floatx4 lo = *(const floatx4*)&px[c*32 + q8];
            floatx4 hi = *(const floatx4*)&px[c*32 + q8 + 4];
            #pragma unroll
            for (int i = 0; i < 4; i++) { xf[c][i] = lo[i]; xf[c][4+i] = hi[i]; }
        }
    } else {
        #pragma unroll
        for (int c = 0; c < 4; c++)
            xh[c].q = *(const uint4*)&pxv[c*32 + q8];
    }
    float attC = pat[0] * sc_norm;

    floatx4 acc[4][2];
    #pragma unroll
    for (int af = 0; af < 4; af++) {
        acc[af][0] = (floatx4){0.f, 0.f, 0.f, 0.f};
        acc[af][1] = (floatx4){0.f, 0.f, 0.f, 0.f};
    }

    const int cof0 = (wv*2+0)*64 + lane;
    const int cof1 = (wv*2+1)*64 + lane;

    auto packx = [&](int c_, float att_) -> short8x {
        S8 pk;
        if (is_s) {
            #pragma unroll
            for (int i = 0; i < 8; i++) pk.u[i] = f2bf(xf[c_][i] * att_);
        } else {
            #pragma unroll
            for (int i = 0; i < 8; i++) pk.u[i] = f2bf(bf2f(xh[c_].u[i]) * att_);
        }
        return pk.v;
    };
    auto mstep = [&](int kb, const S8& b0, const S8& b1) {
        __builtin_amdgcn_s_setprio(1);
        #pragma unroll
        for (int af = 0; af < 4; af++) {
            short8x a = Abuf[kb][af*64 + lane];
            acc[af][0] = __builtin_amdgcn_mfma_f32_16x16x32_bf16(a, b0.v, acc[af][0], 0, 0, 0);
            acc[af][1] = __builtin_amdgcn_mfma_f32_16x16x32_bf16(a, b1.v, acc[af][1], 0, 0, 0);
        }
        __builtin_amdgcn_s_setprio(0);
    };
    auto bload = [&](int k2, S8& b0, S8& b1) {
        b0.q = bb[(size_t)k2*512 + cof0];
        b1.q = bb[(size_t)k2*512 + cof1];
    };
    auto barrier_ = [&]() {
        asm volatile("s_waitcnt lgkmcnt(0)" ::: "memory");
        __builtin_amdgcn_s_barrier();
    };

    // B prefetch (depth 2)
    S8 bA0, bA1, bB0, bB1;
    bload(0, bA0, bA1);
    bload(1, bB0, bB1);

    // prologue: A(0) -> buf0
    Abuf[0][t] = packx(0, attC);
    barrier_();

    // ---- main loop: ks = 0..35 (vblk 0..8), A from preloaded chunks ----
    #pragma unroll 1
    for (int vb = 0; vb < 9; vb++) {
        float attN = pat[vb + 1] * sc_norm;
        const int ksb = vb * 4;
        Abuf[1][t] = packx(1, attC); mstep(0, bA0, bA1); bload(ksb+2, bA0, bA1); barrier_();
        Abuf[0][t] = packx(2, attC); mstep(1, bB0, bB1); bload(ksb+3, bB0, bB1); barrier_();
        Abuf[1][t] = packx(3, attC); mstep(0, bA0, bA1); bload(ksb+4, bA0, bA1); barrier_();
        Abuf[0][t] = packx(0, attN); mstep(1, bB0, bB1); bload(ksb+5, bB0, bB1); barrier_();
        attC = attN;
    }

    // ---- ks = 36..47 explicit (attC == pat[9]); tail A from acc (depth-2) ----
    floatx4 aT0[2], aT1[2];
    auto issue0 = [&](int k_) { int j2 = (k_-40)*32 + q8;
        aT0[0] = *(const floatx4*)&pa[j2]; aT0[1] = *(const floatx4*)&pa[j2+4]; };
    auto issue1 = [&](int k_) { int j2 = (k_-40)*32 + q8;
        aT1[0] = *(const floatx4*)&pa[j2]; aT1[1] = *(const floatx4*)&pa[j2+4]; };
    auto packT = [&](const floatx4* a2) -> short8x {
        S8 pk;
        #pragma unroll
        for (int i = 0; i < 4; i++) { pk.u[i] = f2bf(a2[0][i] * l2); pk.u[4+i] = f2bf(a2[1][i] * l2); }
        return pk.v;
    };

    // ks=36
    Abuf[1][t] = packx(1, attC); mstep(0, bA0, bA1); bload(38, bA0, bA1); barrier_();
    // ks=37
    Abuf[0][t] = packx(2, attC); mstep(1, bB0, bB1); bload(39, bB0, bB1); barrier_();
    // ks=38
    issue0(40);
    Abuf[1][t] = packx(3, attC); mstep(0, bA0, bA1); bload(40, bA0, bA1); barrier_();
    // ks=39
    issue1(41);
    Abuf[0][t] = packT(aT0); mstep(1, bB0, bB1); bload(41, bB0, bB1); barrier_();
    // ks=40
    issue0(42);
    Abuf[1][t] = packT(aT1); mstep(0, bA0, bA1); bload(42, bA0, bA1); barrier_();
    // ks=41
    issue1(43);
    Abuf[0][t] = packT(aT0); mstep(1, bB0, bB1); bload(43, bB0, bB1); barrier_();
    // ks=42
    issue0(44);
    Abuf[1][t] = packT(aT1); mstep(0, bA0, bA1); bload(44, bA0, bA1); barrier_();
    // ks=43
    issue1(45);
    Abuf[0][t] = packT(aT0); mstep(1, bB0, bB1); bload(45, bB0, bB1); barrier_();
    // ks=44
    issue0(46);
    Abuf[1][t] = packT(aT1); mstep(0, bA0, bA1); bload(46, bA0, bA1); barrier_();
    // ks=45
    issue1(47);
    Abuf[0][t] = packT(aT0); mstep(1, bB0, bB1); bload(47, bB0, bB1); barrier_();
    // ks=46
    Abuf[1][t] = packT(aT1); mstep(0, bA0, bA1); barrier_();
    // ks=47
    mstep(1, bB0, bB1);

    // ---- epilogue ----
    const int m = lane & 15;
    const int rq = (lane >> 4) * 4;
    if (is_s) {
        const int n0 = bid * 64;
        #pragma unroll
        for (int af = 0; af < 4; af++) {
            #pragma unroll
            for (int i = 0; i < 4; i++) {
                int n = n0 + af*16 + rq + i;
                if (n < N_NODES) {
                    out[(size_t)n*512 + wv*32 + m]      = acc[af][0][i];
                    out[(size_t)n*512 + wv*32 + 16 + m] = acc[af][1][i];
                }
            }
        }
    } else {
        const int r0 = (bid - SO_BLK) * 64;
        #pragma unroll
        for (int af = 0; af < 4; af++) {
            #pragma unroll
            for (int i = 0; i < 4; i++) {
                int Rg = r0 + af*16 + rq + i;
                if (Rg < 3 * N_NODES) {
                    int nn = Rg / 3;
                    int cc = Rg - nn * 3;
                    float* po = out + (size_t)nn*512 + 128 + cc;
                    po[(wv*32 + m)*3]      = acc[af][0][i];
                    po[(wv*32 + 16 + m)*3] = acc[af][1][i];
                }
            }
        }
    }
}

extern "C" void kernel_launch(void* const* d_in, const int* in_sizes, int n_in,
                              void* d_out, int out_size, void* d_ws, size_t ws_size,
                              hipStream_t stream) {
    const float* node_feats = (const float*)d_in[0];
    const float* node_attrs = (const float*)d_in[1];
    const float* edge_feats = (const float*)d_in[2];
    const float* edge_attrs = (const float*)d_in[3];
    const int*   edge_index = (const int*)  d_in[4];
    const float* lin1_ws    = (const float*)d_in[5];
    const float* lin1_wv    = (const float*)d_in[6];
    const float* fc_w0      = (const float*)d_in[7];
    const float* fc_w1      = (const float*)d_in[8];
    const float* fc_w2      = (const float*)d_in[9];
    const float* lin2_ws    = (const float*)d_in[10];
    const float* lin2_wv    = (const float*)d_in[11];
    const float* sc_ws      = (const float*)d_in[12];
    const float* sc_wv      = (const float*)d_in[13];
    float* out = (float*)d_out;

    // workspace layout
    unsigned short* y_pk  = (unsigned short*)d_ws;            // 5,120,000 us
    float* accS = (float*)(y_pk + (size_t)5120000);           // 2,560,000 f32
    float* accV = accS + (size_t)2560000;                     // 7,680,000 f32
    unsigned short* xvP16 = (unsigned short*)(accV + (size_t)7680000);  // 3,840,000 us
    unsigned short* w_pk  = xvP16 + (size_t)3840000;          // 81,920,000 us
    int* deg       = (int*)(w_pk + (size_t)81920000);
    int* row_start = deg + 10016;
    int* cursor    = row_start + 10016;
    int* edge_list = cursor + 10016;
    int* srcs      = edge_list + N_EDGES;
    float* ea_sorted = (float*)(srcs + N_EDGES);
    unsigned short* b_pre = (unsigned short*)(ea_sorted + (size_t)N_EDGES * 4);
    unsigned short* w2a   = b_pre + (size_t)2 * 24576 * 8;
    unsigned short* w1a   = w2a + (size_t)4096 * 8;
    unsigned short* b_lin = w1a + (size_t)512 * 8;
    const size_t need = (size_t)5120000 * 2 + (size_t)(2560000 + 7680000) * 4
                      + (size_t)3840000 * 2 + (size_t)81920000 * 2
                      + (size_t)(10016 * 3 + N_EDGES * 2) * 4
                      + (size_t)N_EDGES * 4 * 4
                      + ((size_t)2 * 24576 * 8 + (size_t)4096 * 8 + (size_t)512 * 8
                         + (size_t)4096 * 8) * 2;
    if (ws_size < need) return;

    hipLaunchKernelGGL(pack_all_kernel, dim3(226), dim3(256), 0, stream,
                       sc_ws, lin2_ws, sc_wv, lin2_wv, fc_w2, fc_w1, lin1_ws, lin1_wv,
                       b_pre, w2a, w1a, b_lin);
    hipLaunchKernelGGL(node_lin1_mfma, dim3(625), dim3(256), 0, stream,
                       node_feats, b_lin, y_pk, xvP16);

    hipMemsetAsync(deg, 0, (size_t)N_NODES * sizeof(int), stream);
    hipLaunchKernelGGL(hist_kernel, dim3(625), dim3(256), 0, stream, edge_index, deg);
    hipLaunchKernelGGL(scan_kernel, dim3(1), dim3(1024), 0, stream, deg, row_start, cursor);
    hipLaunchKernelGGL(scatter_kernel, dim3(625), dim3(256), 0, stream,
                       edge_index, edge_attrs, cursor, edge_list, srcs, ea_sorted);
    hipLaunchKernelGGL(edge_w_mfma, dim3(2500), dim3(256), 0, stream,
                       edge_feats, edge_list, fc_w0, w1a, w2a, w_pk);
    hipLaunchKernelGGL(gather_kernel, dim3(2500), dim3(256), 0, stream,
                       row_start, srcs, ea_sorted, w_pk, y_pk, accS, accV);

    hipLaunchKernelGGL(node_out_mfma, dim3(SO_BLK + VO_BLK), dim3(256), 0, stream,
                       node_feats, node_attrs, xvP16, accS, accV, b_pre, out);
}

// Round 15
// 279.300 us; speedup vs baseline: 1.9198x; 1.0034x over previous
//
#include <hip/hip_runtime.h>
#include <hip/hip_bf16.h>
#include <math.h>

#define N_NODES 10000
#define N_EDGES 160000
#define SO_BLK 157          // ceil(10000/64) s-GEMM blocks
#define VO_BLK 469          // ceil(30000/64) v-GEMM blocks

typedef __attribute__((ext_vector_type(8))) short short8x;
typedef __attribute__((ext_vector_type(4))) float floatx4;
typedef __attribute__((ext_vector_type(4))) unsigned int uint4x;
typedef __attribute__((ext_vector_type(2))) unsigned int uint2x;

union S8 { short8x v; unsigned short u[8]; uint4 q; uint4x qx; };
union U2 { uint2x v; unsigned short us[4]; };

__device__ __forceinline__ unsigned short f2bf(float x) {
    unsigned int u = __float_as_uint(x);
    return (unsigned short)((u + 0x7fffu + ((u >> 16) & 1u)) >> 16);
}
__device__ __forceinline__ float bf2f(unsigned short u) {
    return __uint_as_float(((unsigned)u) << 16);
}
__device__ __forceinline__ float silu_c(float x) {
    return 1.679f * x / (1.0f + __expf(-x));
}

// ---------------- pack_all: weight pre-packs + edge histogram in one launch ----
// blocks [0,192): b_pre; [192,208): w2a; [208,210): w1a; [210,226): b_lin;
// [226,851): hist (deg atomicAdd; deg zeroed by the preceding memset dispatch)
__global__ __launch_bounds__(256) void pack_all_kernel(
    const float* __restrict__ sc_ws, const float* __restrict__ lin2_ws,
    const float* __restrict__ sc_wv, const float* __restrict__ lin2_wv,
    const float* __restrict__ fc_w2, const float* __restrict__ fc_w1,
    const float* __restrict__ lin1_ws, const float* __restrict__ lin1_wv,
    const int* __restrict__ edge_index,
    unsigned short* __restrict__ b_pre, unsigned short* __restrict__ w2a,
    unsigned short* __restrict__ w1a, unsigned short* __restrict__ b_lin,
    int* __restrict__ deg)
{
    const int bid = blockIdx.x;
    const int t = threadIdx.x;
    if (bid < 192) {
        int id = bid * 256 + t;                  // 0..49151
        int mat = id / 24576;
        int slot = id - mat * 24576;
        int ks = slot >> 9;
        int rr = slot & 511;
        int lane = rr & 63;
        int quad = lane >> 4;
        int n = ((rr >> 6) << 4) + (lane & 15);
        const float* sc  = mat ? sc_wv  : sc_ws;
        const float* lin = mat ? lin2_wv : lin2_ws;
        S8 pk;
        #pragma unroll
        for (int j = 0; j < 8; j++) {
            int k = ks * 32 + quad * 8 + j;
            float w;
            if (k < 1280) {
                int u = k & 127, v = k >> 7;
                w = sc[(u * 10 + v) * 128 + n];
            } else {
                w = lin[(k - 1280) * 128 + n];
            }
            pk.u[j] = f2bf(w);
        }
        *(uint4*)(b_pre + (size_t)id * 8) = pk.q;
    } else if (bid < 208) {
        int id = (bid - 192) * 256 + t;          // 0..4095
        int lane = id & 63;
        int mfg = (id >> 6) & 31;
        int ks = id >> 11;
        int col = mfg * 16 + (lane & 15);
        int k0 = ks * 32 + (lane >> 4) * 8;
        S8 pk;
        #pragma unroll
        for (int j = 0; j < 8; j++)
            pk.u[j] = f2bf(fc_w2[(k0 + j) * 512 + col] * 0.125f);
        *(uint4*)(w2a + (size_t)id * 8) = pk.q;
    } else if (bid < 210) {
        int id = (bid - 208) * 256 + t;          // 0..511
        int lane = id & 63;
        int mf = (id >> 6) & 3;
        int ks = id >> 8;
        int m = mf * 16 + (lane & 15);
        int k0 = ks * 32 + (lane >> 4) * 8;
        S8 pk;
        #pragma unroll
        for (int j = 0; j < 8; j++)
            pk.u[j] = f2bf(fc_w1[(k0 + j) * 64 + m] * 0.125f);
        *(uint4*)(w1a + (size_t)id * 8) = pk.q;
    } else if (bid < 226) {
        int id = (bid - 210) * 256 + t;          // 0..4095
        int mat = id >> 11;
        int slot = id & 2047;
        int ks = slot >> 9;
        int rr = slot & 511;
        int nf = rr >> 6;
        int lane = rr & 63;
        int n = nf * 16 + (lane & 15);
        int k0 = ks * 32 + (lane >> 4) * 8;
        const float* w = mat ? lin1_wv : lin1_ws;
        const float l1 = 0.0883883476483f;
        S8 pk;
        #pragma unroll
        for (int j = 0; j < 8; j++)
            pk.u[j] = f2bf(w[(k0 + j) * 128 + n] * l1);
        *(uint4*)(b_lin + (size_t)id * 8) = pk.q;
    } else {
        int e = (bid - 226) * 256 + t;           // 0..159999 exactly (625 blocks)
        if (e < N_EDGES) atomicAdd(&deg[edge_index[e]], 1);
    }
}

// ---------------- Kernel A: lin1 via MFMA -> packed bf16 y + bf16 xvP ----------------
// 16 nodes/block (M=64 rows: comp = af), grid 625 = 2.4 blocks/CU, LDS 16 KB.
__global__ __launch_bounds__(256) void node_lin1_mfma(
    const float* __restrict__ node_feats,
    const unsigned short* __restrict__ b_lin,
    unsigned short* __restrict__ y_pk,
    unsigned short* __restrict__ xvP16)
{
    __shared__ __align__(16) unsigned char smem[16384];
    short8x* Al = (short8x*)smem;
    unsigned short* Yt = (unsigned short*)smem;

    const int blk = blockIdx.x;   // 625
    const int t = threadIdx.x;
    const int base = blk * 16;
    const int lane = t & 63;
    const int wv = t >> 6;
    const int m15 = lane & 15;
    const int k0q = (lane >> 4) * 8;

    #pragma unroll
    for (int it = 0; it < 4; it++) {
        int g = wv * 4 + it;          // 0..15
        int af = g >> 2;              // 0..3  (== comp)
        int ks = g & 3;               // 0..3
        int node = base + m15;
        int valid = (node < N_NODES);
        if (!valid) node = N_NODES - 1;
        int k0 = ks * 32 + k0q;
        const float* row = node_feats + (size_t)node * 512;
        S8 pk;
        if (af == 0) {
            float4 a = *(const float4*)&row[k0];
            float4 b = *(const float4*)&row[k0 + 4];
            pk.u[0] = f2bf(a.x); pk.u[1] = f2bf(a.y); pk.u[2] = f2bf(a.z); pk.u[3] = f2bf(a.w);
            pk.u[4] = f2bf(b.x); pk.u[5] = f2bf(b.y); pk.u[6] = f2bf(b.z); pk.u[7] = f2bf(b.w);
        } else {
            int c = af - 1;
            #pragma unroll
            for (int j = 0; j < 8; j++)
                pk.u[j] = f2bf(row[128 + (k0 + j) * 3 + c]);
            if (valid)
                *(uint4*)&xvP16[((size_t)node * 3 + c) * 128 + k0] = pk.q;
        }
        Al[(ks * 4 + af) * 64 + lane] = pk.v;
    }
    __syncthreads();

    floatx4 c[4][2];
    #pragma unroll
    for (int af = 0; af < 4; af++) {
        c[af][0] = (floatx4){0.f, 0.f, 0.f, 0.f};
        c[af][1] = (floatx4){0.f, 0.f, 0.f, 0.f};
    }

    const uint4* bq = (const uint4*)b_lin;
    #pragma unroll
    for (int ks = 0; ks < 4; ks++) {
        S8 bs0, bs1, bv0, bv1;
        bs0.q = bq[       ks*512 + (wv*2+0)*64 + lane];
        bs1.q = bq[       ks*512 + (wv*2+1)*64 + lane];
        bv0.q = bq[2048 + ks*512 + (wv*2+0)*64 + lane];
        bv1.q = bq[2048 + ks*512 + (wv*2+1)*64 + lane];
        #pragma unroll
        for (int af = 0; af < 4; af++) {
            short8x a = Al[(ks*4 + af)*64 + lane];
            if (af == 0) {
                c[af][0] = __builtin_amdgcn_mfma_f32_16x16x32_bf16(a, bs0.v, c[af][0], 0, 0, 0);
                c[af][1] = __builtin_amdgcn_mfma_f32_16x16x32_bf16(a, bs1.v, c[af][1], 0, 0, 0);
            } else {
                c[af][0] = __builtin_amdgcn_mfma_f32_16x16x32_bf16(a, bv0.v, c[af][0], 0, 0, 0);
                c[af][1] = __builtin_amdgcn_mfma_f32_16x16x32_bf16(a, bv1.v, c[af][1], 0, 0, 0);
            }
        }
    }
    __syncthreads();

    {
        const int rq = (lane >> 4) * 4;
        #pragma unroll
        for (int af = 0; af < 4; af++) {
            #pragma unroll
            for (int nf = 0; nf < 2; nf++) {
                int u = wv * 32 + nf * 16 + m15;
                #pragma unroll
                for (int i = 0; i < 4; i++) {
                    int nloc = rq + i;           // row m = af*16 + nloc; comp = af
                    Yt[(nloc * 128 + u) * 4 + af] = f2bf(c[af][nf][i]);
                }
            }
        }
    }
    __syncthreads();
    {
        unsigned short* dst = y_pk + (size_t)base * 512;
        int nrem = N_NODES - base;
        #pragma unroll
        for (int it = 0; it < 4; it++) {
            int idx = it * 256 + t;              // 0..1023 (16 nodes x 64 groups)
            if ((idx >> 6) < nrem)
                *(uint4*)(dst + (size_t)idx * 8) = *(const uint4*)&Yt[idx * 8];
        }
    }
}

// ---------------- CSR build ----------------
__global__ __launch_bounds__(1024) void scan_kernel(const int* __restrict__ deg,
                                                    int* __restrict__ row_start,
                                                    int* __restrict__ cursor) {
    __shared__ int wsum[16];
    __shared__ int carry_s;
    const int t = threadIdx.x;
    const int lane = t & 63, w = t >> 6;
    if (t == 0) carry_s = 0;
    __syncthreads();
    for (int chunk = 0; chunk < 10; chunk++) {
        int idx = chunk * 1024 + t;
        int v = (idx < N_NODES) ? deg[idx] : 0;
        int x = v;
        #pragma unroll
        for (int off = 1; off < 64; off <<= 1) {
            int yv = __shfl_up(x, off, 64);
            if (lane >= off) x += yv;
        }
        if (lane == 63) wsum[w] = x;
        __syncthreads();
        int wpre = 0;
        for (int i = 0; i < w; i++) wpre += wsum[i];
        int incl = x + wpre + carry_s;
        int excl = incl - v;
        if (idx < N_NODES) { row_start[idx] = excl; cursor[idx] = excl; }
        __syncthreads();
        if (t == 1023) carry_s = incl;
        __syncthreads();
    }
    if (t == 0) row_start[N_NODES] = carry_s;
}

__global__ __launch_bounds__(256) void scatter_kernel(const int* __restrict__ edge_index,
                                                      const float* __restrict__ edge_attrs,
                                                      int* __restrict__ cursor,
                                                      int* __restrict__ edge_list,
                                                      int* __restrict__ srcs,
                                                      float* __restrict__ ea_sorted) {
    int e = blockIdx.x * 256 + threadIdx.x;
    if (e < N_EDGES) {
        int pos = atomicAdd(&cursor[edge_index[e]], 1);
        edge_list[pos] = e;
        srcs[pos] = edge_index[N_EDGES + e];
        float4 ea = *(const float4*)(edge_attrs + (size_t)e * 4);
        *(float4*)(ea_sorted + (size_t)pos * 4) = ea;
    }
}

// ---------------- Kernel B1: edge MLP (sorted order) -> packed bf16 w ----------------
// w_pk[pos][u][4] = bf16{ss, sv, vs, vv}; normal (MALL-allocating) stores.
__global__ __launch_bounds__(256) void edge_w_mfma(
    const float* __restrict__ edge_feats,
    const int* __restrict__ edge_list,
    const float* __restrict__ fc_w0,
    const unsigned short* __restrict__ w1a,
    const unsigned short* __restrict__ w2a,
    unsigned short* __restrict__ w_pk)
{
    __shared__ __align__(16) unsigned char smem[26368];
    float* ef = (float*)smem;                               // [0, 2304)
    unsigned short* h0b = (unsigned short*)(smem + 2304);   // [2304, 11520): 64 x 72
    unsigned short* T   = (unsigned short*)smem;            // [0, 16896): 64 x 132 (epilogue)
    unsigned short* h1b = (unsigned short*)(smem + 16896);  // [16896, 26112): 64 x 72
    int* eids = (int*)(smem + 26112);                       // [26112, 26368)

    const int blk = blockIdx.x;      // 2500
    const int t = threadIdx.x;
    const int eb0 = blk * 64;
    const int lane = t & 63;
    const int wv = t >> 6;
    const int quad = lane >> 4;
    const int m15 = lane & 15;

    #define SWZ(row, col) ((col) ^ (((row) & 7) << 3))

    if (t < 64) eids[t] = edge_list[eb0 + t];
    __syncthreads();

    #pragma unroll
    for (int r = 0; r < 2; r++) {
        int idx = r * 256 + t;
        int el = idx >> 3;
        int k = idx & 7;
        ef[el * 9 + k] = edge_feats[(size_t)eids[el] * 8 + k];
    }
    __syncthreads();

    // phase 1 (VALU, f32): h0 = silu_c(ef @ w0 / sqrt(8)) -> bf16
    {
        const int e_loc = t >> 2;
        const int c0 = (t & 3) * 16;
        float a0[16];
        #pragma unroll
        for (int i = 0; i < 16; i++) a0[i] = 0.f;
        const float* efr = &ef[e_loc * 9];
        #pragma unroll
        for (int k = 0; k < 8; k++) {
            float ek = efr[k];
            float w[16];
            #pragma unroll
            for (int q4 = 0; q4 < 4; q4++)
                *(float4*)&w[q4*4] = *(const float4*)&fc_w0[k*64 + c0 + q4*4];
            #pragma unroll
            for (int i = 0; i < 16; i++) a0[i] += ek * w[i];
        }
        const float is8 = 0.35355339059f;
        S8 p0, p1;
        #pragma unroll
        for (int i = 0; i < 8; i++) {
            p0.u[i] = f2bf(silu_c(a0[i] * is8));
            p1.u[i] = f2bf(silu_c(a0[8 + i] * is8));
        }
        *(uint4*)&h0b[e_loc * 72 + SWZ(e_loc, c0)]     = p0.q;
        *(uint4*)&h0b[e_loc * 72 + SWZ(e_loc, c0 + 8)] = p1.q;
    }
    __syncthreads();

    // phase 2 (MFMA): h1 = silu_c(h0 @ w1 / 8)
    {
        floatx4 c2[4];
        #pragma unroll
        for (int ee = 0; ee < 4; ee++) c2[ee] = (floatx4){0.f, 0.f, 0.f, 0.f};
        const uint4* w1aq = (const uint4*)w1a;
        #pragma unroll
        for (int ks = 0; ks < 2; ks++) {
            S8 afr;
            afr.q = w1aq[(ks*4 + wv)*64 + lane];
            #pragma unroll
            for (int ee = 0; ee < 4; ee++) {
                S8 bfr;
                int rw = ee*16 + m15;
                bfr.q = *(const uint4*)&h0b[rw * 72 + SWZ(rw, ks*32 + quad*8)];
                c2[ee] = __builtin_amdgcn_mfma_f32_16x16x32_bf16(afr.v, bfr.v, c2[ee], 0, 0, 0);
            }
        }
        #pragma unroll
        for (int ee = 0; ee < 4; ee++) {
            ushort4 pk = make_ushort4(f2bf(silu_c(c2[ee][0])), f2bf(silu_c(c2[ee][1])),
                                      f2bf(silu_c(c2[ee][2])), f2bf(silu_c(c2[ee][3])));
            int rw = ee*16 + m15;
            *(ushort4*)&h1b[rw * 72 + SWZ(rw, wv*16 + quad*4)] = pk;
        }
    }
    __syncthreads();

    // phase 3 (MFMA, 4 passes of 2 m-frags); pass p covers cols p*32..p*32+31 of comp wv
    const uint4* w2aq = (const uint4*)w2a;
    #pragma unroll 1
    for (int p = 0; p < 4; p++) {
        floatx4 c3[2][4];
        #pragma unroll
        for (int mf = 0; mf < 2; mf++)
            #pragma unroll
            for (int ee = 0; ee < 4; ee++)
                c3[mf][ee] = (floatx4){0.f, 0.f, 0.f, 0.f};

        #pragma unroll
        for (int ks = 0; ks < 2; ks++) {
            S8 bfr[4];
            #pragma unroll
            for (int ee = 0; ee < 4; ee++) {
                int rw = ee*16 + m15;
                bfr[ee].q = *(const uint4*)&h1b[rw * 72 + SWZ(rw, ks*32 + quad*8)];
            }
            #pragma unroll
            for (int mf = 0; mf < 2; mf++) {
                S8 afr;
                afr.q = w2aq[(size_t)(ks*32 + wv*8 + p*2 + mf) * 64 + lane];
                #pragma unroll
                for (int ee = 0; ee < 4; ee++)
                    c3[mf][ee] = __builtin_amdgcn_mfma_f32_16x16x32_bf16(afr.v, bfr[ee].v, c3[mf][ee], 0, 0, 0);
            }
        }

        __syncthreads();   // T region free (prev pass stores done / ef+h0b dead)
        // dump interleaved: T[e*132 + col'*4 + comp], comp = wv
        #pragma unroll
        for (int mf = 0; mf < 2; mf++) {
            #pragma unroll
            for (int ee = 0; ee < 4; ee++) {
                int e = ee*16 + m15;
                #pragma unroll
                for (int i = 0; i < 4; i++) {
                    int colp = mf*16 + quad*4 + i;
                    T[e*132 + colp*4 + wv] = f2bf(c3[mf][ee][i]);
                }
            }
        }
        __syncthreads();

        // coalesced store: uint2 per (e, cu); per e-row 256 B contiguous
        #pragma unroll
        for (int it = 0; it < 8; it++) {
            int idx = it * 256 + t;          // 0..2047
            int e  = idx >> 5;
            int cu = idx & 31;
            uint2x v = *(const uint2x*)&T[e*132 + cu*4];
            unsigned short* dstp = w_pk + ((size_t)(eb0 + e) * 128 + p*32 + cu) * 4;
            *(uint2x*)dstp = v;
        }
    }
    #undef SWZ
}

// ---------------- Kernel B2: wave-per-node gather (R5 depth-2, best measured) --
__global__ __launch_bounds__(256) void gather_kernel(
    const int* __restrict__ row_start,
    const int* __restrict__ srcs,
    const float* __restrict__ ea_sorted,
    const unsigned short* __restrict__ w_pk,
    const unsigned short* __restrict__ y_pk,
    float* __restrict__ accS,
    float* __restrict__ accV)
{
    const int t = threadIdx.x;
    const int n = blockIdx.x * 4 + (t >> 6);   // wave-per-node, grid 2500
    const int lane = t & 63;
    const int u0 = lane << 1;                  // u0, u0+1

    const int eb = row_start[n];
    const int ee = row_start[n + 1];

    float aS0a=0.f,aS0b=0.f, aS1a=0.f,aS1b=0.f;
    float aV2ax=0.f,aV2ay=0.f,aV2az=0.f, aV2bx=0.f,aV2by=0.f,aV2bz=0.f;
    float aV3ax=0.f,aV3ay=0.f,aV3az=0.f, aV3bx=0.f,aV3by=0.f,aV3bz=0.f;

    auto consume = [&](const S8& w8, const S8& y8, const float4& ea) {
        // u0 slot
        {
            float wss = bf2f(w8.u[0]), wsv = bf2f(w8.u[1]);
            float wvs = bf2f(w8.u[2]), wvv = bf2f(w8.u[3]);
            float qs = bf2f(y8.u[0]), q0 = bf2f(y8.u[1]), q1 = bf2f(y8.u[2]), q2 = bf2f(y8.u[3]);
            aS0a += wss * qs * ea.x;
            aS1a += wvv * (q0*ea.y + q1*ea.z + q2*ea.w);
            float tsv = wsv * qs;
            aV2ax += tsv * ea.y; aV2ay += tsv * ea.z; aV2az += tsv * ea.w;
            float tvs = wvs * ea.x;
            aV3ax += tvs * q0; aV3ay += tvs * q1; aV3az += tvs * q2;
        }
        // u0+1 slot
        {
            float wss = bf2f(w8.u[4]), wsv = bf2f(w8.u[5]);
            float wvs = bf2f(w8.u[6]), wvv = bf2f(w8.u[7]);
            float qs = bf2f(y8.u[4]), q0 = bf2f(y8.u[5]), q1 = bf2f(y8.u[6]), q2 = bf2f(y8.u[7]);
            aS0b += wss * qs * ea.x;
            aS1b += wvv * (q0*ea.y + q1*ea.z + q2*ea.w);
            float tsv = wsv * qs;
            aV2bx += tsv * ea.y; aV2by += tsv * ea.z; aV2bz += tsv * ea.w;
            float tvs = wvs * ea.x;
            aV3bx += tvs * q0; aV3by += tvs * q1; aV3bz += tvs * q2;
        }
    };

    if (eb < ee) {
        const int lastE = ee - 1;
        int j1 = (eb+1 < lastE) ? eb+1 : lastE;
        int sA = srcs[eb];
        int sB = srcs[j1];
        int sP0 = srcs[(eb+2 < lastE) ? eb+2 : lastE];
        int sP1 = srcs[(eb+3 < lastE) ? eb+3 : lastE];

        S8 wA, wB, yA, yB; float4 eaA, eaB;
        wA.qx = __builtin_nontemporal_load((const uint4x*)(w_pk + ((size_t)eb * 128 + u0) * 4));
        eaA   = *(const float4*)(ea_sorted + (size_t)eb * 4);
        yA.q  = *(const uint4*)(y_pk + ((size_t)sA * 128 + u0) * 4);
        wB.qx = __builtin_nontemporal_load((const uint4x*)(w_pk + ((size_t)j1 * 128 + u0) * 4));
        eaB   = *(const float4*)(ea_sorted + (size_t)j1 * 4);
        yB.q  = *(const uint4*)(y_pk + ((size_t)sB * 128 + u0) * 4);

        for (int i = eb; i < ee; i += 2) {
            // ---- consume A (edge i, always valid) ----
            consume(wA, yA, eaA);
            // ---- refill A <- edge i+2 (clamped within node; never consumed if invalid) ----
            {
                int jn = (i+2 < lastE) ? i+2 : lastE;
                wA.qx = __builtin_nontemporal_load((const uint4x*)(w_pk + ((size_t)jn * 128 + u0) * 4));
                eaA   = *(const float4*)(ea_sorted + (size_t)jn * 4);
                yA.q  = *(const uint4*)(y_pk + ((size_t)sP0 * 128 + u0) * 4);
                sP0 = srcs[(i+4 < lastE) ? i+4 : lastE];
            }
            // ---- consume B (edge i+1; wave-uniform guard) ----
            if (i + 1 < ee) consume(wB, yB, eaB);
            // ---- refill B <- edge i+3 (clamped) ----
            {
                int jn = (i+3 < lastE) ? i+3 : lastE;
                wB.qx = __builtin_nontemporal_load((const uint4x*)(w_pk + ((size_t)jn * 128 + u0) * 4));
                eaB   = *(const float4*)(ea_sorted + (size_t)jn * 4);
                yB.q  = *(const uint4*)(y_pk + ((size_t)sP1 * 128 + u0) * 4);
                sP1 = srcs[(i+5 < lastE) ? i+5 : lastE];
            }
        }
    }

    const float inv = 0.25f;                   // 1/sqrt(16)
    const float s1c = 0.57735026919f * 0.25f;
    *(float2*)(accS + (size_t)n*256 + u0)        = make_float2(aS0a*inv, aS0b*inv);
    *(float2*)(accS + (size_t)n*256 + 128 + u0)  = make_float2(aS1a*s1c, aS1b*s1c);
    *(float2*)(accV + ((size_t)n*3+0)*256 + u0)       = make_float2(aV2ax*inv, aV2bx*inv);
    *(float2*)(accV + ((size_t)n*3+0)*256 + 128 + u0) = make_float2(aV3ax*inv, aV3bx*inv);
    *(float2*)(accV + ((size_t)n*3+1)*256 + u0)       = make_float2(aV2ay*inv, aV2by*inv);
    *(float2*)(accV + ((size_t)n*3+1)*256 + 128 + u0) = make_float2(aV3ay*inv, aV3by*inv);
    *(float2*)(accV + ((size_t)n*3+2)*256 + u0)       = make_float2(aV2az*inv, aV2bz*inv);
    *(float2*)(accV + ((size_t)n*3+2)*256 + 128 + u0) = make_float2(aV3az*inv, aV3bz*inv);
}

// ---------------- node_out as MFMA GEMM, latency-pipelined ----------------
__global__ __launch_bounds__(256) void node_out_mfma(
    const float* __restrict__ node_feats,
    const float* __restrict__ node_attrs,
    const unsigned short* __restrict__ xvP16,
    const float* __restrict__ accS,
    const float* __restrict__ accV,
    const unsigned short* __restrict__ b_pre,
    float* __restrict__ out)
{
    __shared__ __align__(16) short8x Abuf[2][256];   // 2 x 4 KB double buffer
    const int bid = blockIdx.x;
    const int t = threadIdx.x;
    const int lane = t & 63;
    const int wv = t >> 6;
    const bool is_s = (bid < SO_BLK);

    // this thread's A slot: row r (0..63), k-quad (0..3); slot index == t
    const int r    = ((t >> 6) << 4) + (t & 15);
    const int q8   = ((t >> 4) & 3) * 8;

    const float* px = nullptr;
    const unsigned short* pxv = nullptr;
    const float* pa;
    const float* pat;
    if (is_s) {
        int R = bid * 64 + r;
        int node = (R < N_NODES) ? R : 0;
        px  = node_feats + (size_t)node * 512;
        pa  = accS + (size_t)node * 256;
        pat = node_attrs + node * 10;
    } else {
        int Rg = (bid - SO_BLK) * 64 + r;
        if (Rg >= 3 * N_NODES) Rg = 0;
        int node = Rg / 3;
        pxv = xvP16 + (size_t)Rg * 128;
        pa  = accV + (size_t)Rg * 256;
        pat = node_attrs + node * 10;
    }

    const uint4* bb = (const uint4*)(b_pre) + (is_s ? 0 : 24576);
    const float sc_norm = 0.02795084972f;   // 1/sqrt(1280)
    const float l2 = 0.0625f;               // 1/sqrt(256)

    // ---- preload the 4 sc-part A chunks for this (row, quad) ----
    float xf[4][8];
    S8    xh[4];
    if (is_s) {
        #pragma unroll
        for (int c = 0; c < 4; c++) {
            floatx4 lo = *(const floatx4*)&px[c*32 + q8];
            floatx4 hi = *(const floatx4*)&px[c*32 + q8 + 4];
            #pragma unroll
            for (int i = 0; i < 4; i++) { xf[c][i] = lo[i]; xf[c][4+i] = hi[i]; }
        }
    } else {
        #pragma unroll
        for (int c = 0; c < 4; c++)
            xh[c].q = *(const uint4*)&pxv[c*32 + q8];
    }
    float attC = pat[0] * sc_norm;

    floatx4 acc[4][2];
    #pragma unroll
    for (int af = 0; af < 4; af++) {
        acc[af][0] = (floatx4){0.f, 0.f, 0.f, 0.f};
        acc[af][1] = (floatx4){0.f, 0.f, 0.f, 0.f};
    }

    const int cof0 = (wv*2+0)*64 + lane;
    const int cof1 = (wv*2+1)*64 + lane;

    auto packx = [&](int c_, float att_) -> short8x {
        S8 pk;
        if (is_s) {
            #pragma unroll
            for (int i = 0; i < 8; i++) pk.u[i] = f2bf(xf[c_][i] * att_);
        } else {
            #pragma unroll
            for (int i = 0; i < 8; i++) pk.u[i] = f2bf(bf2f(xh[c_].u[i]) * att_);
        }
        return pk.v;
    };
    auto mstep = [&](int kb, const S8& b0, const S8& b1) {
        __builtin_amdgcn_s_setprio(1);
        #pragma unroll
        for (int af = 0; af < 4; af++) {
            short8x a = Abuf[kb][af*64 + lane];
            acc[af][0] = __builtin_amdgcn_mfma_f32_16x16x32_bf16(a, b0.v, acc[af][0], 0, 0, 0);
            acc[af][1] = __builtin_amdgcn_mfma_f32_16x16x32_bf16(a, b1.v, acc[af][1], 0, 0, 0);
        }
        __builtin_amdgcn_s_setprio(0);
    };
    auto bload = [&](int k2, S8& b0, S8& b1) {
        b0.q = bb[(size_t)k2*512 + cof0];
        b1.q = bb[(size_t)k2*512 + cof1];
    };
    auto barrier_ = [&]() {
        asm volatile("s_waitcnt lgkmcnt(0)" ::: "memory");
        __builtin_amdgcn_s_barrier();
    };

    // B prefetch (depth 2)
    S8 bA0, bA1, bB0, bB1;
    bload(0, bA0, bA1);
    bload(1, bB0, bB1);

    // prologue: A(0) -> buf0
    Abuf[0][t] = packx(0, attC);
    barrier_();

    // ---- main loop: ks = 0..35 (vblk 0..8), A from preloaded chunks ----
    #pragma unroll 1
    for (int vb = 0; vb < 9; vb++) {
        float attN = pat[vb + 1] * sc_norm;
        const int ksb = vb * 4;
        Abuf[1][t] = packx(1, attC); mstep(0, bA0, bA1); bload(ksb+2, bA0, bA1); barrier_();
        Abuf[0][t] = packx(2, attC); mstep(1, bB0, bB1); bload(ksb+3, bB0, bB1); barrier_();
        Abuf[1][t] = packx(3, attC); mstep(0, bA0, bA1); bload(ksb+4, bA0, bA1); barrier_();
        Abuf[0][t] = packx(0, attN); mstep(1, bB0, bB1); bload(ksb+5, bB0, bB1); barrier_();
        attC = attN;
    }

    // ---- ks = 36..47 explicit (attC == pat[9]); tail A from acc (depth-2) ----
    floatx4 aT0[2], aT1[2];
    auto issue0 = [&](int k_) { int j2 = (k_-40)*32 + q8;
        aT0[0] = *(const floatx4*)&pa[j2]; aT0[1] = *(const floatx4*)&pa[j2+4]; };
    auto issue1 = [&](int k_) { int j2 = (k_-40)*32 + q8;
        aT1[0] = *(const floatx4*)&pa[j2]; aT1[1] = *(const floatx4*)&pa[j2+4]; };
    auto packT = [&](const floatx4* a2) -> short8x {
        S8 pk;
        #pragma unroll
        for (int i = 0; i < 4; i++) { pk.u[i] = f2bf(a2[0][i] * l2); pk.u[4+i] = f2bf(a2[1][i] * l2); }
        return pk.v;
    };

    // ks=36
    Abuf[1][t] = packx(1, attC); mstep(0, bA0, bA1); bload(38, bA0, bA1); barrier_();
    // ks=37
    Abuf[0][t] = packx(2, attC); mstep(1, bB0, bB1); bload(39, bB0, bB1); barrier_();
    // ks=38
    issue0(40);
    Abuf[1][t] = packx(3, attC); mstep(0, bA0, bA1); bload(40, bA0, bA1); barrier_();
    // ks=39
    issue1(41);
    Abuf[0][t] = packT(aT0); mstep(1, bB0, bB1); bload(41, bB0, bB1); barrier_();
    // ks=40
    issue0(42);
    Abuf[1][t] = packT(aT1); mstep(0, bA0, bA1); bload(42, bA0, bA1); barrier_();
    // ks=41
    issue1(43);
    Abuf[0][t] = packT(aT0); mstep(1, bB0, bB1); bload(43, bB0, bB1); barrier_();
    // ks=42
    issue0(44);
    Abuf[1][t] = packT(aT1); mstep(0, bA0, bA1); bload(44, bA0, bA1); barrier_();
    // ks=43
    issue1(45);
    Abuf[0][t] = packT(aT0); mstep(1, bB0, bB1); bload(45, bB0, bB1); barrier_();
    // ks=44
    issue0(46);
    Abuf[1][t] = packT(aT1); mstep(0, bA0, bA1); bload(46, bA0, bA1); barrier_();
    // ks=45
    issue1(47);
    Abuf[0][t] = packT(aT0); mstep(1, bB0, bB1); bload(47, bB0, bB1); barrier_();
    // ks=46
    Abuf[1][t] = packT(aT1); mstep(0, bA0, bA1); barrier_();
    // ks=47
    mstep(1, bB0, bB1);

    // ---- epilogue ----
    const int m = lane & 15;
    const int rq = (lane >> 4) * 4;
    if (is_s) {
        const int n0 = bid * 64;
        #pragma unroll
        for (int af = 0; af < 4; af++) {
            #pragma unroll
            for (int i = 0; i < 4; i++) {
                int n = n0 + af*16 + rq + i;
                if (n < N_NODES) {
                    out[(size_t)n*512 + wv*32 + m]      = acc[af][0][i];
                    out[(size_t)n*512 + wv*32 + 16 + m] = acc[af][1][i];
                }
            }
        }
    } else {
        const int r0 = (bid - SO_BLK) * 64;
        #pragma unroll
        for (int af = 0; af < 4; af++) {
            #pragma unroll
            for (int i = 0; i < 4; i++) {
                int Rg = r0 + af*16 + rq + i;
                if (Rg < 3 * N_NODES) {
                    int nn = Rg / 3;
                    int cc = Rg - nn * 3;
                    float* po = out + (size_t)nn*512 + 128 + cc;
                    po[(wv*32 + m)*3]      = acc[af][0][i];
                    po[(wv*32 + 16 + m)*3] = acc[af][1][i];
                }
            }
        }
    }
}

extern "C" void kernel_launch(void* const* d_in, const int* in_sizes, int n_in,
                              void* d_out, int out_size, void* d_ws, size_t ws_size,
                              hipStream_t stream) {
    const float* node_feats = (const float*)d_in[0];
    const float* node_attrs = (const float*)d_in[1];
    const float* edge_feats = (const float*)d_in[2];
    const float* edge_attrs = (const float*)d_in[3];
    const int*   edge_index = (const int*)  d_in[4];
    const float* lin1_ws    = (const float*)d_in[5];
    const float* lin1_wv    = (const float*)d_in[6];
    const float* fc_w0      = (const float*)d_in[7];
    const float* fc_w1      = (const float*)d_in[8];
    const float* fc_w2      = (const float*)d_in[9];
    const float* lin2_ws    = (const float*)d_in[10];
    const float* lin2_wv    = (const float*)d_in[11];
    const float* sc_ws      = (const float*)d_in[12];
    const float* sc_wv      = (const float*)d_in[13];
    float* out = (float*)d_out;

    // workspace layout
    unsigned short* y_pk  = (unsigned short*)d_ws;            // 5,120,000 us
    float* accS = (float*)(y_pk + (size_t)5120000);           // 2,560,000 f32
    float* accV = accS + (size_t)2560000;                     // 7,680,000 f32
    unsigned short* xvP16 = (unsigned short*)(accV + (size_t)7680000);  // 3,840,000 us
    unsigned short* w_pk  = xvP16 + (size_t)3840000;          // 81,920,000 us
    int* deg       = (int*)(w_pk + (size_t)81920000);
    int* row_start = deg + 10016;
    int* cursor    = row_start + 10016;
    int* edge_list = cursor + 10016;
    int* srcs      = edge_list + N_EDGES;
    float* ea_sorted = (float*)(srcs + N_EDGES);
    unsigned short* b_pre = (unsigned short*)(ea_sorted + (size_t)N_EDGES * 4);
    unsigned short* w2a   = b_pre + (size_t)2 * 24576 * 8;
    unsigned short* w1a   = w2a + (size_t)4096 * 8;
    unsigned short* b_lin = w1a + (size_t)512 * 8;
    const size_t need = (size_t)5120000 * 2 + (size_t)(2560000 + 7680000) * 4
                      + (size_t)3840000 * 2 + (size_t)81920000 * 2
                      + (size_t)(10016 * 3 + N_EDGES * 2) * 4
                      + (size_t)N_EDGES * 4 * 4
                      + ((size_t)2 * 24576 * 8 + (size_t)4096 * 8 + (size_t)512 * 8
                         + (size_t)4096 * 8) * 2;
    if (ws_size < need) return;

    // deg must be zero before pack_all's hist blocks run (stream-ordered)
    hipMemsetAsync(deg, 0, (size_t)N_NODES * sizeof(int), stream);
    hipLaunchKernelGGL(pack_all_kernel, dim3(851), dim3(256), 0, stream,
                       sc_ws, lin2_ws, sc_wv, lin2_wv, fc_w2, fc_w1, lin1_ws, lin1_wv,
                       edge_index, b_pre, w2a, w1a, b_lin, deg);
    hipLaunchKernelGGL(node_lin1_mfma, dim3(625), dim3(256), 0, stream,
                       node_feats, b_lin, y_pk, xvP16);

    hipLaunchKernelGGL(scan_kernel, dim3(1), dim3(1024), 0, stream, deg, row_start, cursor);
    hipLaunchKernelGGL(scatter_kernel, dim3(625), dim3(256), 0, stream,
                       edge_index, edge_attrs, cursor, edge_list, srcs, ea_sorted);
    hipLaunchKernelGGL(edge_w_mfma, dim3(2500), dim3(256), 0, stream,
                       edge_feats, edge_list, fc_w0, w1a, w2a, w_pk);
    hipLaunchKernelGGL(gather_kernel, dim3(2500), dim3(256), 0, stream,
                       row_start, srcs, ea_sorted, w_pk, y_pk, accS, accV);

    hipLaunchKernelGGL(node_out_mfma, dim3(SO_BLK + VO_BLK), dim3(256), 0, stream,
                       node_feats, node_attrs, xvP16, accS, accV, b_pre, out);
}